// Round 3
// baseline (1226.905 us; speedup 1.0000x reference)
//
#include <hip/hip_runtime.h>

#define NFULL 8192
#define BATCH 4

typedef unsigned long long u64;
typedef unsigned int u32;

// Total-order bias: monotone map fp32 -> u32 (handles negatives correctly).
__device__ __forceinline__ u32 fbias(float f) {
  u32 u = __float_as_uint(f);
  return (u & 0x80000000u) ? ~u : (u | 0x80000000u);
}
__device__ __forceinline__ float funbias(u32 b) {
  u32 u = (b & 0x80000000u) ? (b & 0x7fffffffu) : ~b;
  return __uint_as_float(u);
}

// ---------------------------------------------------------------- kNN ------
// Wave-per-query. Lanes split refs 64 ways; each lane keeps a sorted local
// top-K of u64 keys (biased-d2 << 32 | idx) => lexicographic (d2, idx) order
// exactly matches jax.lax.top_k stable tie-break.
//
// R3: wave-global cull threshold tau = wave-min over lanes of lane-local max
// (16th-best) biased d2. The minimizing lane holds K keys <= tau, so the
// global Kth-smallest <= tau; candidates with db > tau can never make the
// final top-K (u64 keys are unique, and we only cull on strict d2-word
// inequality, preserving index tie-breaks). tau only decreases => stale tau
// is conservative. Unfilled lists carry ~0ull sentinels => tau stays inf
// until every lane has K entries (warm-up is automatically unfiltered).
// __ballot makes the insert path a wave-uniform skip; tau is refreshed only
// on steps where some lane inserted.
template<int K, int KOUT, int QPB>
__global__ __launch_bounds__(64 * QPB) void knn_kernel(
    const float* __restrict__ pos, int Nref, int Mq,
    int* __restrict__ oidx, float* __restrict__ od2) {
  const int TILE = 256;
  __shared__ float4 sRef[TILE];
  int b = blockIdx.y;
  int w = threadIdx.x >> 6, lane = threadIdx.x & 63;
  int q = blockIdx.x * QPB + w;  // all Mq are multiples of QPB
  const float* pb = pos + (size_t)b * NFULL * 3;
  float qx = pb[q * 3 + 0], qy = pb[q * 3 + 1], qz = pb[q * 3 + 2];
  float qq = qx * qx + qy * qy + qz * qz;

  u64 key[K];
#pragma unroll
  for (int i = 0; i < K; ++i) key[i] = ~0ull;
  u32 tau = 0xFFFFFFFFu;

  for (int t0 = 0; t0 < Nref; t0 += TILE) {
    int cnt = min(TILE, Nref - t0);
    __syncthreads();
    for (int j = threadIdx.x; j < cnt; j += 64 * QPB) {
      float rx = pb[(t0 + j) * 3 + 0];
      float ry = pb[(t0 + j) * 3 + 1];
      float rz = pb[(t0 + j) * 3 + 2];
      sRef[j] = make_float4(rx, ry, rz, rx * rx + ry * ry + rz * rz);
    }
    __syncthreads();
#pragma unroll
    for (int c = 0; c < TILE / 64; ++c) {
      int j = lane + 64 * c;
      // cnt is always a multiple of 64 here (all Nref are), so this branch
      // and the __ballot below are wave-uniform.
      if (j < cnt) {
        float4 r = sRef[j];
        float d2 = qq + r.w - 2.0f * (qx * r.x + qy * r.y + qz * r.z);
        u32 db = fbias(d2);
        bool pass = db <= tau;  // cull only strictly-greater d2 words
        if (__ballot(pass)) {
          u64 ck = ((u64)db << 32) | (u32)(t0 + j);
          if (pass && ck < key[K - 1]) {
            key[K - 1] = ck;
#pragma unroll
            for (int s = K - 1; s > 0; --s) {
              if (key[s] < key[s - 1]) {
                u64 t = key[s]; key[s] = key[s - 1]; key[s - 1] = t;
              }
            }
          }
          // refresh tau = wave-min of lane maxes (u32 d2 word)
          u32 lmax = (u32)(key[K - 1] >> 32);
#pragma unroll
          for (int s = 32; s >= 1; s >>= 1) {
            u32 o = (u32)__shfl_xor((int)lmax, s, 64);
            lmax = lmax < o ? lmax : o;
          }
          tau = lmax;
        }
      }
    }
  }

  // butterfly merge across 64 lanes; everyone converges to global top-K
#pragma unroll
  for (int s = 1; s < 64; s <<= 1) {
    u64 other[K];
#pragma unroll
    for (int i = 0; i < K; ++i)
      other[i] = __shfl_xor((unsigned long long)key[i], s, 64);
    // lower half of bitonic(A ++ rev(B)): the K smallest, as a bitonic seq
#pragma unroll
    for (int i = 0; i < K; ++i) {
      u64 o = other[K - 1 - i];
      key[i] = (key[i] < o) ? key[i] : o;
    }
    // bitonic cleanup: sort ascending
#pragma unroll
    for (int d = K / 2; d >= 1; d >>= 1) {
#pragma unroll
      for (int i = 0; i < K; ++i) {
        if ((i & d) == 0) {
          if (key[i + d] < key[i]) {
            u64 t = key[i]; key[i] = key[i + d]; key[i + d] = t;
          }
        }
      }
    }
  }

  if (lane == 0) {
    size_t base = ((size_t)b * Mq + q) * KOUT;
#pragma unroll
    for (int i = 0; i < KOUT; ++i) {
      oidx[base + i] = (int)(u32)key[i];
      od2[base + i] = fmaxf(funbias((u32)(key[i] >> 32)), 0.0f);
    }
  }
}

// ------------------------------------------------------------- down MLP ----
// One block per (batch, center). blockDim == CHID == COUT; thread t owns
// output channel t with K=16 register accumulators. feat and h1 staged in LDS,
// read via aligned float4 broadcasts.
template<int FEAT, int FEATP, int CIN, int CHID>
__global__ __launch_bounds__(CHID) void down_kernel(
    const float* __restrict__ pos, const float* __restrict__ xin,
    const int* __restrict__ idx, const float* __restrict__ W1,
    const float* __restrict__ b1, const float* __restrict__ W2,
    const float* __restrict__ b2, float* __restrict__ out,
    int n, int nprev) {
  const int K = 16;
  __shared__ int sIdx[K];
  __shared__ float sCtr[3];
  __shared__ float sFeat[K][FEATP];
  __shared__ float sH1[K][CHID];
  int b = blockIdx.y, q = blockIdx.x, t = threadIdx.x;
  const float* pb = pos + (size_t)b * NFULL * 3;
  const float* xb = xin + (size_t)b * nprev * CIN;
  if (t < K) sIdx[t] = idx[((size_t)b * n + q) * K + t];
  if (t < 3) sCtr[t] = pb[q * 3 + t];
  __syncthreads();
  for (int e = t; e < K * FEATP; e += CHID) {
    int k = e / FEATP, c = e % FEATP;
    float v = 0.f;
    if (c < 3) v = pb[sIdx[k] * 3 + c] - sCtr[c];
    else if (c < FEAT) v = xb[(size_t)sIdx[k] * CIN + (c - 3)];
    sFeat[k][c] = v;
  }
  __syncthreads();
  // layer 1: h1 = relu(feat @ W1 + b1)
  float acc[K];
  float bb = b1[t];
#pragma unroll
  for (int k = 0; k < K; ++k) acc[k] = bb;
  for (int c4 = 0; c4 < FEAT / 4; ++c4) {
    int c = c4 * 4;
    float w0 = W1[(c + 0) * CHID + t];
    float w1 = W1[(c + 1) * CHID + t];
    float w2 = W1[(c + 2) * CHID + t];
    float w3 = W1[(c + 3) * CHID + t];
#pragma unroll
    for (int k = 0; k < K; ++k) {
      float4 f = *(const float4*)&sFeat[k][c];
      acc[k] = fmaf(f.x, w0, acc[k]);
      acc[k] = fmaf(f.y, w1, acc[k]);
      acc[k] = fmaf(f.z, w2, acc[k]);
      acc[k] = fmaf(f.w, w3, acc[k]);
    }
  }
  for (int c = (FEAT / 4) * 4; c < FEAT; ++c) {
    float w = W1[c * CHID + t];
#pragma unroll
    for (int k = 0; k < K; ++k) acc[k] = fmaf(sFeat[k][c], w, acc[k]);
  }
#pragma unroll
  for (int k = 0; k < K; ++k) sH1[k][t] = fmaxf(acc[k], 0.f);
  __syncthreads();
  // layer 2: out = max_k (h1 @ W2 + b2)
  float acc2[K];
  float bb2 = b2[t];
#pragma unroll
  for (int k = 0; k < K; ++k) acc2[k] = bb2;
  for (int c4 = 0; c4 < CHID / 4; ++c4) {
    int c = c4 * 4;
    float w0 = W2[(c + 0) * CHID + t];
    float w1 = W2[(c + 1) * CHID + t];
    float w2 = W2[(c + 2) * CHID + t];
    float w3 = W2[(c + 3) * CHID + t];
#pragma unroll
    for (int k = 0; k < K; ++k) {
      float4 h = *(const float4*)&sH1[k][c];
      acc2[k] = fmaf(h.x, w0, acc2[k]);
      acc2[k] = fmaf(h.y, w1, acc2[k]);
      acc2[k] = fmaf(h.z, w2, acc2[k]);
      acc2[k] = fmaf(h.w, w3, acc2[k]);
    }
  }
  float m = acc2[0];
#pragma unroll
  for (int k = 1; k < K; ++k) m = fmaxf(m, acc2[k]);
  out[((size_t)b * n + q) * CHID + t] = m;
}

// --------------------------------------------------------------- up MLP ----
template<int CIN, int CPRV, int COUT>
__global__ __launch_bounds__(COUT) void up_kernel(
    const float* __restrict__ xc, int ncoarse,
    const int* __restrict__ idx3, const float* __restrict__ d23,
    const float* __restrict__ prv, const float* __restrict__ W,
    const float* __restrict__ bvec, float* __restrict__ out, int m) {
  const int CTOT = CIN + CPRV;
  __shared__ float sCat[CTOT];
  __shared__ float sW[3];
  __shared__ int sI[3];
  int b = blockIdx.y, q = blockIdx.x, t = threadIdx.x;
  if (t == 0) {
    size_t base = ((size_t)b * m + q) * 3;
    float d0 = d23[base + 0], d1 = d23[base + 1], d2v = d23[base + 2];
    float w0 = 1.f / (d0 + 1e-8f), w1 = 1.f / (d1 + 1e-8f), w2 = 1.f / (d2v + 1e-8f);
    float s = w0 + w1 + w2;
    sW[0] = w0 / s; sW[1] = w1 / s; sW[2] = w2 / s;
    sI[0] = (int)idx3[base + 0]; sI[1] = (int)idx3[base + 1]; sI[2] = (int)idx3[base + 2];
  }
  __syncthreads();
  const float* xb = xc + (size_t)b * ncoarse * CIN;
  const float* pvb = prv + ((size_t)b * m + q) * CPRV;
  for (int c = t; c < CIN; c += COUT)
    sCat[c] = sW[0] * xb[(size_t)sI[0] * CIN + c]
            + sW[1] * xb[(size_t)sI[1] * CIN + c]
            + sW[2] * xb[(size_t)sI[2] * CIN + c];
  for (int c = t; c < CPRV; c += COUT) sCat[CIN + c] = pvb[c];
  __syncthreads();
  float acc = bvec[t];
  for (int c4 = 0; c4 < CTOT / 4; ++c4) {
    int c = 4 * c4;
    float4 v = *(const float4*)&sCat[c];
    acc = fmaf(v.x, W[(c + 0) * COUT + t], acc);
    acc = fmaf(v.y, W[(c + 1) * COUT + t], acc);
    acc = fmaf(v.z, W[(c + 2) * COUT + t], acc);
    acc = fmaf(v.w, W[(c + 3) * COUT + t], acc);
  }
  out[((size_t)b * m + q) * COUT + t] = fmaxf(acc, 0.f);
}

// ---------------------------------------------- fused up2 + final MLP ------
__global__ __launch_bounds__(128) void up2_final_kernel(
    const float* __restrict__ xc,
    const int* __restrict__ idx3, const float* __restrict__ d23,
    const float* __restrict__ x0, const float* __restrict__ pos0,
    const float* __restrict__ u2W, const float* __restrict__ u2b,
    const float* __restrict__ fW1, const float* __restrict__ fb1,
    const float* __restrict__ fW2, const float* __restrict__ fb2,
    float* __restrict__ out) {
  __shared__ float sA[136];
  __shared__ float sB[128];
  __shared__ float sW[3];
  __shared__ int sI[3];
  int b = blockIdx.y, q = blockIdx.x, t = threadIdx.x;
  if (t == 0) {
    size_t base = ((size_t)b * NFULL + q) * 3;
    float d0 = d23[base + 0], d1 = d23[base + 1], d2v = d23[base + 2];
    float w0 = 1.f / (d0 + 1e-8f), w1 = 1.f / (d1 + 1e-8f), w2 = 1.f / (d2v + 1e-8f);
    float s = w0 + w1 + w2;
    sW[0] = w0 / s; sW[1] = w1 / s; sW[2] = w2 / s;
    sI[0] = (int)idx3[base + 0]; sI[1] = (int)idx3[base + 1]; sI[2] = (int)idx3[base + 2];
  }
  __syncthreads();
  const float* xb = xc + (size_t)b * 2048 * 128;
  sA[t] = sW[0] * xb[(size_t)sI[0] * 128 + t]
        + sW[1] * xb[(size_t)sI[1] * 128 + t]
        + sW[2] * xb[(size_t)sI[2] * 128 + t];
  if (t < 6) {
    const float* src = (t < 3) ? x0 : pos0;
    int c = (t < 3) ? t : t - 3;
    sA[128 + t] = src[((size_t)b * NFULL + q) * 3 + c];
  }
  __syncthreads();
  float acc = u2b[t];
  for (int c4 = 0; c4 < 33; ++c4) {
    int c = 4 * c4;
    float4 v = *(const float4*)&sA[c];
    acc = fmaf(v.x, u2W[(c + 0) * 128 + t], acc);
    acc = fmaf(v.y, u2W[(c + 1) * 128 + t], acc);
    acc = fmaf(v.z, u2W[(c + 2) * 128 + t], acc);
    acc = fmaf(v.w, u2W[(c + 3) * 128 + t], acc);
  }
  acc = fmaf(sA[132], u2W[132 * 128 + t], acc);
  acc = fmaf(sA[133], u2W[133 * 128 + t], acc);
  sB[t] = fmaxf(acc, 0.f);
  __syncthreads();
  float acc2 = fb1[t];
  for (int c4 = 0; c4 < 32; ++c4) {
    int c = 4 * c4;
    float4 v = *(const float4*)&sB[c];
    acc2 = fmaf(v.x, fW1[(c + 0) * 128 + t], acc2);
    acc2 = fmaf(v.y, fW1[(c + 1) * 128 + t], acc2);
    acc2 = fmaf(v.z, fW1[(c + 2) * 128 + t], acc2);
    acc2 = fmaf(v.w, fW1[(c + 3) * 128 + t], acc2);
  }
  sA[t] = fmaxf(acc2, 0.f);
  __syncthreads();
  float acc3 = fb2[t];
  for (int c4 = 0; c4 < 32; ++c4) {
    int c = 4 * c4;
    float4 v = *(const float4*)&sA[c];
    acc3 = fmaf(v.x, fW2[(c + 0) * 128 + t], acc3);
    acc3 = fmaf(v.y, fW2[(c + 1) * 128 + t], acc3);
    acc3 = fmaf(v.z, fW2[(c + 2) * 128 + t], acc3);
    acc3 = fmaf(v.w, fW2[(c + 3) * 128 + t], acc3);
  }
  out[((size_t)b * NFULL + q) * 128 + t] = acc3;
}

__global__ void copy_kernel(const float* __restrict__ src, float* __restrict__ dst, int n) {
  int i = blockIdx.x * blockDim.x + threadIdx.x;
  if (i < n) dst[i] = src[i];
}

// ------------------------------------------------------------------ launch -
extern "C" void kernel_launch(void* const* d_in, const int* in_sizes, int n_in,
                              void* d_out, int out_size, void* d_ws, size_t ws_size,
                              hipStream_t stream) {
  const float* x    = (const float*)d_in[0];
  const float* pos  = (const float*)d_in[1];
  const float* d0W1 = (const float*)d_in[2];
  const float* d0b1 = (const float*)d_in[3];
  const float* d0W2 = (const float*)d_in[4];
  const float* d0b2 = (const float*)d_in[5];
  const float* d1W1 = (const float*)d_in[6];
  const float* d1b1 = (const float*)d_in[7];
  const float* d1W2 = (const float*)d_in[8];
  const float* d1b2 = (const float*)d_in[9];
  const float* d2W1 = (const float*)d_in[10];
  const float* d2b1 = (const float*)d_in[11];
  const float* d2W2 = (const float*)d_in[12];
  const float* d2b2 = (const float*)d_in[13];
  const float* u0W  = (const float*)d_in[14];
  const float* u0b  = (const float*)d_in[15];
  const float* u1W  = (const float*)d_in[16];
  const float* u1b  = (const float*)d_in[17];
  const float* u2W  = (const float*)d_in[18];
  const float* u2b  = (const float*)d_in[19];
  const float* fW1  = (const float*)d_in[20];
  const float* fb1  = (const float*)d_in[21];
  const float* fW2  = (const float*)d_in[22];
  const float* fb2  = (const float*)d_in[23];

  char* ws = (char*)d_ws;
  float* x1    = (float*)(ws + 0);
  float* x2    = (float*)(ws + 4194304);
  float* x3    = (float*)(ws + 6291456);
  float* up0o  = (float*)(ws + 7340032);
  float* up1o  = (float*)(ws + 9437184);
  int*   idx0  = (int*)  (ws + 13631488);
  int*   idx1  = (int*)  (ws + 14155776);
  int*   idx2  = (int*)  (ws + 14286848);
  float* d2s   = (float*)(ws + 14319616);
  int*   idxu0 = (int*)  (ws + 14843904);
  float* d2u0  = (float*)(ws + 14868480);
  int*   idxu1 = (int*)  (ws + 14893056);
  float* d2u1  = (float*)(ws + 14991360);
  int*   idxu2 = (int*)  (ws + 15089664);
  float* d2u2  = (float*)(ws + 15482880);

  float* out = (float*)d_out;

  // ---- down path ----
  knn_kernel<16, 16, 4><<<dim3(512, BATCH), 256, 0, stream>>>(pos, 8192, 2048, idx0, d2s);
  down_kernel<6, 8, 3, 128><<<dim3(2048, BATCH), 128, 0, stream>>>(
      pos, x, idx0, d0W1, d0b1, d0W2, d0b2, x1, 2048, 8192);
  knn_kernel<16, 16, 4><<<dim3(128, BATCH), 256, 0, stream>>>(pos, 2048, 512, idx1, d2s);
  down_kernel<131, 132, 128, 256><<<dim3(512, BATCH), 256, 0, stream>>>(
      pos, x1, idx1, d1W1, d1b1, d1W2, d1b2, x2, 512, 2048);
  knn_kernel<16, 16, 4><<<dim3(32, BATCH), 256, 0, stream>>>(pos, 512, 128, idx2, d2s);
  down_kernel<259, 260, 256, 512><<<dim3(128, BATCH), 512, 0, stream>>>(
      pos, x2, idx2, d2W1, d2b1, d2W2, d2b2, x3, 128, 512);

  // ---- up path ----
  knn_kernel<4, 3, 4><<<dim3(128, BATCH), 256, 0, stream>>>(pos, 128, 512, idxu0, d2u0);
  up_kernel<512, 256, 256><<<dim3(512, BATCH), 256, 0, stream>>>(
      x3, 128, idxu0, d2u0, x2, u0W, u0b, up0o, 512);
  knn_kernel<4, 3, 4><<<dim3(512, BATCH), 256, 0, stream>>>(pos, 512, 2048, idxu1, d2u1);
  up_kernel<256, 128, 128><<<dim3(2048, BATCH), 128, 0, stream>>>(
      up0o, 512, idxu1, d2u1, x1, u1W, u1b, up1o, 2048);
  knn_kernel<4, 3, 4><<<dim3(2048, BATCH), 256, 0, stream>>>(pos, 2048, 8192, idxu2, d2u2);
  up2_final_kernel<<<dim3(8192, BATCH), 128, 0, stream>>>(
      up1o, idxu2, d2u2, x, pos, u2W, u2b, fW1, fb1, fW2, fb2, out);

  // ---- second tuple element: pos passthrough ----
  copy_kernel<<<dim3(384), 256, 0, stream>>>(pos, out + (size_t)BATCH * NFULL * 128,
                                             BATCH * NFULL * 3);
}

// Round 4
// 983.189 us; speedup vs baseline: 1.2479x; 1.2479x over previous
//
#include <hip/hip_runtime.h>

#define NFULL 8192
#define BATCH 4

typedef unsigned long long u64;
typedef unsigned int u32;

// Total-order bias: monotone map fp32 -> u32 (handles negatives correctly).
__device__ __forceinline__ u32 fbias(float f) {
  u32 u = __float_as_uint(f);
  return (u & 0x80000000u) ? ~u : (u | 0x80000000u);
}
__device__ __forceinline__ float funbias(u32 b) {
  u32 u = (b & 0x80000000u) ? (b & 0x7fffffffu) : ~b;
  return __uint_as_float(u);
}

// ---------------------------------------------------------------- kNN ------
// Wave-per-query. Lanes split refs 64 ways; each lane keeps a sorted local
// top-K of u64 keys (biased-d2 << 32 | idx) => lexicographic (d2, idx) order
// exactly matches jax.lax.top_k stable tie-break.
//
// HYBRID (used only for the big Nref=8192 scan): after the first 1024
// candidates, butterfly-merge once so ALL lanes hold the identical exact
// global top-K-so-far. Remaining tiles use a guarded fast path: candidates
// are compared against the replicated exact kth-best (key[K-1]); the 16-deep
// insert chain runs only when __ballot says a true insert exists (expected
// ~45 of 112 steps, ~33 serialized inserts total). R3's failure mode
// (wave-min of per-lane kth-bests ~ global 1024th => ballot always fires) is
// avoided because the threshold here is the exact global kth. Top-K set
// membership is order-independent, so serialized inserts preserve exactness;
// the final merge is unnecessary since the list is already replicated+global.
template<int K, int KOUT, int QPB, bool HYBRID>
__global__ __launch_bounds__(64 * QPB) void knn_kernel(
    const float* __restrict__ pos, int Nref, int Mq,
    int* __restrict__ oidx, float* __restrict__ od2) {
  const int TILE = 256;
  __shared__ float4 sRef[TILE];
  int b = blockIdx.y;
  int w = threadIdx.x >> 6, lane = threadIdx.x & 63;
  int q = blockIdx.x * QPB + w;  // all Mq are multiples of QPB
  const float* pb = pos + (size_t)b * NFULL * 3;
  float qx = pb[q * 3 + 0], qy = pb[q * 3 + 1], qz = pb[q * 3 + 2];
  float qq = qx * qx + qy * qy + qz * qz;

  u64 key[K];
#pragma unroll
  for (int i = 0; i < K; ++i) key[i] = ~0ull;

  // ---- phase A: per-lane parallel top-K over the first `split` candidates
  int split = HYBRID ? (Nref < 1024 ? Nref : 1024) : Nref;
  for (int t0 = 0; t0 < split; t0 += TILE) {
    int cnt = min(TILE, Nref - t0);
    __syncthreads();
    for (int j = threadIdx.x; j < cnt; j += 64 * QPB) {
      float rx = pb[(t0 + j) * 3 + 0];
      float ry = pb[(t0 + j) * 3 + 1];
      float rz = pb[(t0 + j) * 3 + 2];
      sRef[j] = make_float4(rx, ry, rz, rx * rx + ry * ry + rz * rz);
    }
    __syncthreads();
#pragma unroll
    for (int c = 0; c < TILE / 64; ++c) {
      int j = lane + 64 * c;
      if (j < cnt) {
        float4 r = sRef[j];
        float d2 = qq + r.w - 2.0f * (qx * r.x + qy * r.y + qz * r.z);
        u64 ck = ((u64)fbias(d2) << 32) | (u32)(t0 + j);
        if (ck < key[K - 1]) {
          key[K - 1] = ck;
#pragma unroll
          for (int s = K - 1; s > 0; --s) {
            if (key[s] < key[s - 1]) {
              u64 t = key[s]; key[s] = key[s - 1]; key[s - 1] = t;
            }
          }
        }
      }
    }
  }

  // ---- butterfly merge across 64 lanes -> all lanes hold global top-K
#pragma unroll
  for (int s = 1; s < 64; s <<= 1) {
    u64 other[K];
#pragma unroll
    for (int i = 0; i < K; ++i)
      other[i] = __shfl_xor((unsigned long long)key[i], s, 64);
    // lower half of bitonic(A ++ rev(B)): the K smallest, as a bitonic seq
#pragma unroll
    for (int i = 0; i < K; ++i) {
      u64 o = other[K - 1 - i];
      key[i] = (key[i] < o) ? key[i] : o;
    }
    // bitonic cleanup: sort ascending
#pragma unroll
    for (int d = K / 2; d >= 1; d >>= 1) {
#pragma unroll
      for (int i = 0; i < K; ++i) {
        if ((i & d) == 0) {
          if (key[i + d] < key[i]) {
            u64 t = key[i]; key[i] = key[i + d]; key[i + d] = t;
          }
        }
      }
    }
  }

  // ---- phase C (HYBRID): guarded scan against exact replicated kth-best
  if (HYBRID) {
    for (int t0 = split; t0 < Nref; t0 += TILE) {
      int cnt = min(TILE, Nref - t0);
      __syncthreads();
      for (int j = threadIdx.x; j < cnt; j += 64 * QPB) {
        float rx = pb[(t0 + j) * 3 + 0];
        float ry = pb[(t0 + j) * 3 + 1];
        float rz = pb[(t0 + j) * 3 + 2];
        sRef[j] = make_float4(rx, ry, rz, rx * rx + ry * ry + rz * rz);
      }
      __syncthreads();
#pragma unroll
      for (int c = 0; c < TILE / 64; ++c) {
        int j = lane + 64 * c;  // tiles are full (Nref multiple of 256 here)
        float4 r = sRef[j];
        float d2 = qq + r.w - 2.0f * (qx * r.x + qy * r.y + qz * r.z);
        u64 ck = ((u64)fbias(d2) << 32) | (u32)(t0 + j);
        u64 mask = __ballot(ck < key[K - 1]);
        while (mask) {  // wave-uniform: ballot identical on all lanes
          int src = __ffsll(mask) - 1;
          u64 cks = __shfl((unsigned long long)ck, src, 64);
          if (cks < key[K - 1]) {  // uniform: replicated list, broadcast cand
            key[K - 1] = cks;
#pragma unroll
            for (int s = K - 1; s > 0; --s) {
              if (key[s] < key[s - 1]) {
                u64 t = key[s]; key[s] = key[s - 1]; key[s - 1] = t;
              }
            }
          }
          mask &= mask - 1;
        }
      }
    }
  }

  if (lane == 0) {
    size_t base = ((size_t)b * Mq + q) * KOUT;
#pragma unroll
    for (int i = 0; i < KOUT; ++i) {
      oidx[base + i] = (int)(u32)key[i];
      od2[base + i] = fmaxf(funbias((u32)(key[i] >> 32)), 0.0f);
    }
  }
}

// ------------------------------------------------------------- down MLP ----
// One block per (batch, center). blockDim == CHID == COUT; thread t owns
// output channel t with K=16 register accumulators. feat and h1 staged in LDS,
// read via aligned float4 broadcasts.
template<int FEAT, int FEATP, int CIN, int CHID>
__global__ __launch_bounds__(CHID) void down_kernel(
    const float* __restrict__ pos, const float* __restrict__ xin,
    const int* __restrict__ idx, const float* __restrict__ W1,
    const float* __restrict__ b1, const float* __restrict__ W2,
    const float* __restrict__ b2, float* __restrict__ out,
    int n, int nprev) {
  const int K = 16;
  __shared__ int sIdx[K];
  __shared__ float sCtr[3];
  __shared__ float sFeat[K][FEATP];
  __shared__ float sH1[K][CHID];
  int b = blockIdx.y, q = blockIdx.x, t = threadIdx.x;
  const float* pb = pos + (size_t)b * NFULL * 3;
  const float* xb = xin + (size_t)b * nprev * CIN;
  if (t < K) sIdx[t] = idx[((size_t)b * n + q) * K + t];
  if (t < 3) sCtr[t] = pb[q * 3 + t];
  __syncthreads();
  for (int e = t; e < K * FEATP; e += CHID) {
    int k = e / FEATP, c = e % FEATP;
    float v = 0.f;
    if (c < 3) v = pb[sIdx[k] * 3 + c] - sCtr[c];
    else if (c < FEAT) v = xb[(size_t)sIdx[k] * CIN + (c - 3)];
    sFeat[k][c] = v;
  }
  __syncthreads();
  // layer 1: h1 = relu(feat @ W1 + b1)
  float acc[K];
  float bb = b1[t];
#pragma unroll
  for (int k = 0; k < K; ++k) acc[k] = bb;
  for (int c4 = 0; c4 < FEAT / 4; ++c4) {
    int c = c4 * 4;
    float w0 = W1[(c + 0) * CHID + t];
    float w1 = W1[(c + 1) * CHID + t];
    float w2 = W1[(c + 2) * CHID + t];
    float w3 = W1[(c + 3) * CHID + t];
#pragma unroll
    for (int k = 0; k < K; ++k) {
      float4 f = *(const float4*)&sFeat[k][c];
      acc[k] = fmaf(f.x, w0, acc[k]);
      acc[k] = fmaf(f.y, w1, acc[k]);
      acc[k] = fmaf(f.z, w2, acc[k]);
      acc[k] = fmaf(f.w, w3, acc[k]);
    }
  }
  for (int c = (FEAT / 4) * 4; c < FEAT; ++c) {
    float w = W1[c * CHID + t];
#pragma unroll
    for (int k = 0; k < K; ++k) acc[k] = fmaf(sFeat[k][c], w, acc[k]);
  }
#pragma unroll
  for (int k = 0; k < K; ++k) sH1[k][t] = fmaxf(acc[k], 0.f);
  __syncthreads();
  // layer 2: out = max_k (h1 @ W2 + b2)
  float acc2[K];
  float bb2 = b2[t];
#pragma unroll
  for (int k = 0; k < K; ++k) acc2[k] = bb2;
  for (int c4 = 0; c4 < CHID / 4; ++c4) {
    int c = c4 * 4;
    float w0 = W2[(c + 0) * CHID + t];
    float w1 = W2[(c + 1) * CHID + t];
    float w2 = W2[(c + 2) * CHID + t];
    float w3 = W2[(c + 3) * CHID + t];
#pragma unroll
    for (int k = 0; k < K; ++k) {
      float4 h = *(const float4*)&sH1[k][c];
      acc2[k] = fmaf(h.x, w0, acc2[k]);
      acc2[k] = fmaf(h.y, w1, acc2[k]);
      acc2[k] = fmaf(h.z, w2, acc2[k]);
      acc2[k] = fmaf(h.w, w3, acc2[k]);
    }
  }
  float m = acc2[0];
#pragma unroll
  for (int k = 1; k < K; ++k) m = fmaxf(m, acc2[k]);
  out[((size_t)b * n + q) * CHID + t] = m;
}

// --------------------------------------------------------------- up MLP ----
template<int CIN, int CPRV, int COUT>
__global__ __launch_bounds__(COUT) void up_kernel(
    const float* __restrict__ xc, int ncoarse,
    const int* __restrict__ idx3, const float* __restrict__ d23,
    const float* __restrict__ prv, const float* __restrict__ W,
    const float* __restrict__ bvec, float* __restrict__ out, int m) {
  const int CTOT = CIN + CPRV;
  __shared__ float sCat[CTOT];
  __shared__ float sW[3];
  __shared__ int sI[3];
  int b = blockIdx.y, q = blockIdx.x, t = threadIdx.x;
  if (t == 0) {
    size_t base = ((size_t)b * m + q) * 3;
    float d0 = d23[base + 0], d1 = d23[base + 1], d2v = d23[base + 2];
    float w0 = 1.f / (d0 + 1e-8f), w1 = 1.f / (d1 + 1e-8f), w2 = 1.f / (d2v + 1e-8f);
    float s = w0 + w1 + w2;
    sW[0] = w0 / s; sW[1] = w1 / s; sW[2] = w2 / s;
    sI[0] = (int)idx3[base + 0]; sI[1] = (int)idx3[base + 1]; sI[2] = (int)idx3[base + 2];
  }
  __syncthreads();
  const float* xb = xc + (size_t)b * ncoarse * CIN;
  const float* pvb = prv + ((size_t)b * m + q) * CPRV;
  for (int c = t; c < CIN; c += COUT)
    sCat[c] = sW[0] * xb[(size_t)sI[0] * CIN + c]
            + sW[1] * xb[(size_t)sI[1] * CIN + c]
            + sW[2] * xb[(size_t)sI[2] * CIN + c];
  for (int c = t; c < CPRV; c += COUT) sCat[CIN + c] = pvb[c];
  __syncthreads();
  float acc = bvec[t];
  for (int c4 = 0; c4 < CTOT / 4; ++c4) {
    int c = 4 * c4;
    float4 v = *(const float4*)&sCat[c];
    acc = fmaf(v.x, W[(c + 0) * COUT + t], acc);
    acc = fmaf(v.y, W[(c + 1) * COUT + t], acc);
    acc = fmaf(v.z, W[(c + 2) * COUT + t], acc);
    acc = fmaf(v.w, W[(c + 3) * COUT + t], acc);
  }
  out[((size_t)b * m + q) * COUT + t] = fmaxf(acc, 0.f);
}

// ---------------------------------------------- fused up2 + final MLP ------
__global__ __launch_bounds__(128) void up2_final_kernel(
    const float* __restrict__ xc,
    const int* __restrict__ idx3, const float* __restrict__ d23,
    const float* __restrict__ x0, const float* __restrict__ pos0,
    const float* __restrict__ u2W, const float* __restrict__ u2b,
    const float* __restrict__ fW1, const float* __restrict__ fb1,
    const float* __restrict__ fW2, const float* __restrict__ fb2,
    float* __restrict__ out) {
  __shared__ float sA[136];
  __shared__ float sB[128];
  __shared__ float sW[3];
  __shared__ int sI[3];
  int b = blockIdx.y, q = blockIdx.x, t = threadIdx.x;
  if (t == 0) {
    size_t base = ((size_t)b * NFULL + q) * 3;
    float d0 = d23[base + 0], d1 = d23[base + 1], d2v = d23[base + 2];
    float w0 = 1.f / (d0 + 1e-8f), w1 = 1.f / (d1 + 1e-8f), w2 = 1.f / (d2v + 1e-8f);
    float s = w0 + w1 + w2;
    sW[0] = w0 / s; sW[1] = w1 / s; sW[2] = w2 / s;
    sI[0] = (int)idx3[base + 0]; sI[1] = (int)idx3[base + 1]; sI[2] = (int)idx3[base + 2];
  }
  __syncthreads();
  const float* xb = xc + (size_t)b * 2048 * 128;
  sA[t] = sW[0] * xb[(size_t)sI[0] * 128 + t]
        + sW[1] * xb[(size_t)sI[1] * 128 + t]
        + sW[2] * xb[(size_t)sI[2] * 128 + t];
  if (t < 6) {
    const float* src = (t < 3) ? x0 : pos0;
    int c = (t < 3) ? t : t - 3;
    sA[128 + t] = src[((size_t)b * NFULL + q) * 3 + c];
  }
  __syncthreads();
  float acc = u2b[t];
  for (int c4 = 0; c4 < 33; ++c4) {
    int c = 4 * c4;
    float4 v = *(const float4*)&sA[c];
    acc = fmaf(v.x, u2W[(c + 0) * 128 + t], acc);
    acc = fmaf(v.y, u2W[(c + 1) * 128 + t], acc);
    acc = fmaf(v.z, u2W[(c + 2) * 128 + t], acc);
    acc = fmaf(v.w, u2W[(c + 3) * 128 + t], acc);
  }
  acc = fmaf(sA[132], u2W[132 * 128 + t], acc);
  acc = fmaf(sA[133], u2W[133 * 128 + t], acc);
  sB[t] = fmaxf(acc, 0.f);
  __syncthreads();
  float acc2 = fb1[t];
  for (int c4 = 0; c4 < 32; ++c4) {
    int c = 4 * c4;
    float4 v = *(const float4*)&sB[c];
    acc2 = fmaf(v.x, fW1[(c + 0) * 128 + t], acc2);
    acc2 = fmaf(v.y, fW1[(c + 1) * 128 + t], acc2);
    acc2 = fmaf(v.z, fW1[(c + 2) * 128 + t], acc2);
    acc2 = fmaf(v.w, fW1[(c + 3) * 128 + t], acc2);
  }
  sA[t] = fmaxf(acc2, 0.f);
  __syncthreads();
  float acc3 = fb2[t];
  for (int c4 = 0; c4 < 32; ++c4) {
    int c = 4 * c4;
    float4 v = *(const float4*)&sA[c];
    acc3 = fmaf(v.x, fW2[(c + 0) * 128 + t], acc3);
    acc3 = fmaf(v.y, fW2[(c + 1) * 128 + t], acc3);
    acc3 = fmaf(v.z, fW2[(c + 2) * 128 + t], acc3);
    acc3 = fmaf(v.w, fW2[(c + 3) * 128 + t], acc3);
  }
  out[((size_t)b * NFULL + q) * 128 + t] = acc3;
}

__global__ void copy_kernel(const float* __restrict__ src, float* __restrict__ dst, int n) {
  int i = blockIdx.x * blockDim.x + threadIdx.x;
  if (i < n) dst[i] = src[i];
}

// ------------------------------------------------------------------ launch -
extern "C" void kernel_launch(void* const* d_in, const int* in_sizes, int n_in,
                              void* d_out, int out_size, void* d_ws, size_t ws_size,
                              hipStream_t stream) {
  const float* x    = (const float*)d_in[0];
  const float* pos  = (const float*)d_in[1];
  const float* d0W1 = (const float*)d_in[2];
  const float* d0b1 = (const float*)d_in[3];
  const float* d0W2 = (const float*)d_in[4];
  const float* d0b2 = (const float*)d_in[5];
  const float* d1W1 = (const float*)d_in[6];
  const float* d1b1 = (const float*)d_in[7];
  const float* d1W2 = (const float*)d_in[8];
  const float* d1b2 = (const float*)d_in[9];
  const float* d2W1 = (const float*)d_in[10];
  const float* d2b1 = (const float*)d_in[11];
  const float* d2W2 = (const float*)d_in[12];
  const float* d2b2 = (const float*)d_in[13];
  const float* u0W  = (const float*)d_in[14];
  const float* u0b  = (const float*)d_in[15];
  const float* u1W  = (const float*)d_in[16];
  const float* u1b  = (const float*)d_in[17];
  const float* u2W  = (const float*)d_in[18];
  const float* u2b  = (const float*)d_in[19];
  const float* fW1  = (const float*)d_in[20];
  const float* fb1  = (const float*)d_in[21];
  const float* fW2  = (const float*)d_in[22];
  const float* fb2  = (const float*)d_in[23];

  char* ws = (char*)d_ws;
  float* x1    = (float*)(ws + 0);
  float* x2    = (float*)(ws + 4194304);
  float* x3    = (float*)(ws + 6291456);
  float* up0o  = (float*)(ws + 7340032);
  float* up1o  = (float*)(ws + 9437184);
  int*   idx0  = (int*)  (ws + 13631488);
  int*   idx1  = (int*)  (ws + 14155776);
  int*   idx2  = (int*)  (ws + 14286848);
  float* d2s   = (float*)(ws + 14319616);
  int*   idxu0 = (int*)  (ws + 14843904);
  float* d2u0  = (float*)(ws + 14868480);
  int*   idxu1 = (int*)  (ws + 14893056);
  float* d2u1  = (float*)(ws + 14991360);
  int*   idxu2 = (int*)  (ws + 15089664);
  float* d2u2  = (float*)(ws + 15482880);

  float* out = (float*)d_out;

  // ---- down path ----
  knn_kernel<16, 16, 4, true><<<dim3(512, BATCH), 256, 0, stream>>>(pos, 8192, 2048, idx0, d2s);
  down_kernel<6, 8, 3, 128><<<dim3(2048, BATCH), 128, 0, stream>>>(
      pos, x, idx0, d0W1, d0b1, d0W2, d0b2, x1, 2048, 8192);
  knn_kernel<16, 16, 4, false><<<dim3(128, BATCH), 256, 0, stream>>>(pos, 2048, 512, idx1, d2s);
  down_kernel<131, 132, 128, 256><<<dim3(512, BATCH), 256, 0, stream>>>(
      pos, x1, idx1, d1W1, d1b1, d1W2, d1b2, x2, 512, 2048);
  knn_kernel<16, 16, 4, false><<<dim3(32, BATCH), 256, 0, stream>>>(pos, 512, 128, idx2, d2s);
  down_kernel<259, 260, 256, 512><<<dim3(128, BATCH), 512, 0, stream>>>(
      pos, x2, idx2, d2W1, d2b1, d2W2, d2b2, x3, 128, 512);

  // ---- up path ----
  knn_kernel<4, 3, 4, false><<<dim3(128, BATCH), 256, 0, stream>>>(pos, 128, 512, idxu0, d2u0);
  up_kernel<512, 256, 256><<<dim3(512, BATCH), 256, 0, stream>>>(
      x3, 128, idxu0, d2u0, x2, u0W, u0b, up0o, 512);
  knn_kernel<4, 3, 4, false><<<dim3(512, BATCH), 256, 0, stream>>>(pos, 512, 2048, idxu1, d2u1);
  up_kernel<256, 128, 128><<<dim3(2048, BATCH), 128, 0, stream>>>(
      up0o, 512, idxu1, d2u1, x1, u1W, u1b, up1o, 2048);
  knn_kernel<4, 3, 4, false><<<dim3(2048, BATCH), 256, 0, stream>>>(pos, 2048, 8192, idxu2, d2u2);
  up2_final_kernel<<<dim3(8192, BATCH), 128, 0, stream>>>(
      up1o, idxu2, d2u2, x, pos, u2W, u2b, fW1, fb1, fW2, fb2, out);

  // ---- second tuple element: pos passthrough ----
  copy_kernel<<<dim3(384), 256, 0, stream>>>(pos, out + (size_t)BATCH * NFULL * 128,
                                             BATCH * NFULL * 3);
}

// Round 5
// 844.384 us; speedup vs baseline: 1.4530x; 1.1644x over previous
//
#include <hip/hip_runtime.h>

#define NFULL 8192
#define BATCH 4

typedef unsigned long long u64;
typedef unsigned int u32;

// Total-order bias: monotone map fp32 -> u32 (handles negatives correctly).
__device__ __forceinline__ u32 fbias(float f) {
  u32 u = __float_as_uint(f);
  return (u & 0x80000000u) ? ~u : (u | 0x80000000u);
}
__device__ __forceinline__ float funbias(u32 b) {
  u32 u = (b & 0x80000000u) ? (b & 0x7fffffffu) : ~b;
  return __uint_as_float(u);
}

// ---------------------------------------------------------------- kNN ------
// Wave-per-query, hybrid exact-threshold guard for the big scan (see R4).
template<int K, int KOUT, int QPB, bool HYBRID>
__global__ __launch_bounds__(64 * QPB) void knn_kernel(
    const float* __restrict__ pos, int Nref, int Mq,
    int* __restrict__ oidx, float* __restrict__ od2) {
  const int TILE = 256;
  __shared__ float4 sRef[TILE];
  int b = blockIdx.y;
  int w = threadIdx.x >> 6, lane = threadIdx.x & 63;
  int q = blockIdx.x * QPB + w;  // all Mq are multiples of QPB
  const float* pb = pos + (size_t)b * NFULL * 3;
  float qx = pb[q * 3 + 0], qy = pb[q * 3 + 1], qz = pb[q * 3 + 2];
  float qq = qx * qx + qy * qy + qz * qz;

  u64 key[K];
#pragma unroll
  for (int i = 0; i < K; ++i) key[i] = ~0ull;

  // ---- phase A: per-lane parallel top-K over the first `split` candidates
  int split = HYBRID ? (Nref < 1024 ? Nref : 1024) : Nref;
  for (int t0 = 0; t0 < split; t0 += TILE) {
    int cnt = min(TILE, Nref - t0);
    __syncthreads();
    for (int j = threadIdx.x; j < cnt; j += 64 * QPB) {
      float rx = pb[(t0 + j) * 3 + 0];
      float ry = pb[(t0 + j) * 3 + 1];
      float rz = pb[(t0 + j) * 3 + 2];
      sRef[j] = make_float4(rx, ry, rz, rx * rx + ry * ry + rz * rz);
    }
    __syncthreads();
#pragma unroll
    for (int c = 0; c < TILE / 64; ++c) {
      int j = lane + 64 * c;
      if (j < cnt) {
        float4 r = sRef[j];
        float d2 = qq + r.w - 2.0f * (qx * r.x + qy * r.y + qz * r.z);
        u64 ck = ((u64)fbias(d2) << 32) | (u32)(t0 + j);
        if (ck < key[K - 1]) {
          key[K - 1] = ck;
#pragma unroll
          for (int s = K - 1; s > 0; --s) {
            if (key[s] < key[s - 1]) {
              u64 t = key[s]; key[s] = key[s - 1]; key[s - 1] = t;
            }
          }
        }
      }
    }
  }

  // ---- butterfly merge across 64 lanes -> all lanes hold global top-K
#pragma unroll
  for (int s = 1; s < 64; s <<= 1) {
    u64 other[K];
#pragma unroll
    for (int i = 0; i < K; ++i)
      other[i] = __shfl_xor((unsigned long long)key[i], s, 64);
#pragma unroll
    for (int i = 0; i < K; ++i) {
      u64 o = other[K - 1 - i];
      key[i] = (key[i] < o) ? key[i] : o;
    }
#pragma unroll
    for (int d = K / 2; d >= 1; d >>= 1) {
#pragma unroll
      for (int i = 0; i < K; ++i) {
        if ((i & d) == 0) {
          if (key[i + d] < key[i]) {
            u64 t = key[i]; key[i] = key[i + d]; key[i + d] = t;
          }
        }
      }
    }
  }

  // ---- phase C (HYBRID): guarded scan against exact replicated kth-best
  if (HYBRID) {
    for (int t0 = split; t0 < Nref; t0 += TILE) {
      int cnt = min(TILE, Nref - t0);
      __syncthreads();
      for (int j = threadIdx.x; j < cnt; j += 64 * QPB) {
        float rx = pb[(t0 + j) * 3 + 0];
        float ry = pb[(t0 + j) * 3 + 1];
        float rz = pb[(t0 + j) * 3 + 2];
        sRef[j] = make_float4(rx, ry, rz, rx * rx + ry * ry + rz * rz);
      }
      __syncthreads();
#pragma unroll
      for (int c = 0; c < TILE / 64; ++c) {
        int j = lane + 64 * c;  // tiles are full (Nref multiple of 256 here)
        float4 r = sRef[j];
        float d2 = qq + r.w - 2.0f * (qx * r.x + qy * r.y + qz * r.z);
        u64 ck = ((u64)fbias(d2) << 32) | (u32)(t0 + j);
        u64 mask = __ballot(ck < key[K - 1]);
        while (mask) {  // wave-uniform: ballot identical on all lanes
          int src = __ffsll(mask) - 1;
          u64 cks = __shfl((unsigned long long)ck, src, 64);
          if (cks < key[K - 1]) {
            key[K - 1] = cks;
#pragma unroll
            for (int s = K - 1; s > 0; --s) {
              if (key[s] < key[s - 1]) {
                u64 t = key[s]; key[s] = key[s - 1]; key[s - 1] = t;
              }
            }
          }
          mask &= mask - 1;
        }
      }
    }
  }

  if (lane == 0) {
    size_t base = ((size_t)b * Mq + q) * KOUT;
#pragma unroll
    for (int i = 0; i < KOUT; ++i) {
      oidx[base + i] = (int)(u32)key[i];
      od2[base + i] = fmaxf(funbias((u32)(key[i] >> 32)), 0.0f);
    }
  }
}

// ------------------------------------------------------------- down MLP ----
template<int FEAT, int FEATP, int CIN, int CHID>
__global__ __launch_bounds__(CHID) void down_kernel(
    const float* __restrict__ pos, const float* __restrict__ xin,
    const int* __restrict__ idx, const float* __restrict__ W1,
    const float* __restrict__ b1, const float* __restrict__ W2,
    const float* __restrict__ b2, float* __restrict__ out,
    int n, int nprev) {
  const int K = 16;
  __shared__ int sIdx[K];
  __shared__ float sCtr[3];
  __shared__ float sFeat[K][FEATP];
  __shared__ float sH1[K][CHID];
  int b = blockIdx.y, q = blockIdx.x, t = threadIdx.x;
  const float* pb = pos + (size_t)b * NFULL * 3;
  const float* xb = xin + (size_t)b * nprev * CIN;
  if (t < K) sIdx[t] = idx[((size_t)b * n + q) * K + t];
  if (t < 3) sCtr[t] = pb[q * 3 + t];
  __syncthreads();
  for (int e = t; e < K * FEATP; e += CHID) {
    int k = e / FEATP, c = e % FEATP;
    float v = 0.f;
    if (c < 3) v = pb[sIdx[k] * 3 + c] - sCtr[c];
    else if (c < FEAT) v = xb[(size_t)sIdx[k] * CIN + (c - 3)];
    sFeat[k][c] = v;
  }
  __syncthreads();
  // layer 1: h1 = relu(feat @ W1 + b1)
  float acc[K];
  float bb = b1[t];
#pragma unroll
  for (int k = 0; k < K; ++k) acc[k] = bb;
  for (int c4 = 0; c4 < FEAT / 4; ++c4) {
    int c = c4 * 4;
    float w0 = W1[(c + 0) * CHID + t];
    float w1 = W1[(c + 1) * CHID + t];
    float w2 = W1[(c + 2) * CHID + t];
    float w3 = W1[(c + 3) * CHID + t];
#pragma unroll
    for (int k = 0; k < K; ++k) {
      float4 f = *(const float4*)&sFeat[k][c];
      acc[k] = fmaf(f.x, w0, acc[k]);
      acc[k] = fmaf(f.y, w1, acc[k]);
      acc[k] = fmaf(f.z, w2, acc[k]);
      acc[k] = fmaf(f.w, w3, acc[k]);
    }
  }
  for (int c = (FEAT / 4) * 4; c < FEAT; ++c) {
    float w = W1[c * CHID + t];
#pragma unroll
    for (int k = 0; k < K; ++k) acc[k] = fmaf(sFeat[k][c], w, acc[k]);
  }
#pragma unroll
  for (int k = 0; k < K; ++k) sH1[k][t] = fmaxf(acc[k], 0.f);
  __syncthreads();
  // layer 2: out = max_k (h1 @ W2 + b2)
  float acc2[K];
  float bb2 = b2[t];
#pragma unroll
  for (int k = 0; k < K; ++k) acc2[k] = bb2;
  for (int c4 = 0; c4 < CHID / 4; ++c4) {
    int c = c4 * 4;
    float w0 = W2[(c + 0) * CHID + t];
    float w1 = W2[(c + 1) * CHID + t];
    float w2 = W2[(c + 2) * CHID + t];
    float w3 = W2[(c + 3) * CHID + t];
#pragma unroll
    for (int k = 0; k < K; ++k) {
      float4 h = *(const float4*)&sH1[k][c];
      acc2[k] = fmaf(h.x, w0, acc2[k]);
      acc2[k] = fmaf(h.y, w1, acc2[k]);
      acc2[k] = fmaf(h.z, w2, acc2[k]);
      acc2[k] = fmaf(h.w, w3, acc2[k]);
    }
  }
  float m = acc2[0];
#pragma unroll
  for (int k = 1; k < K; ++k) m = fmaxf(m, acc2[k]);
  out[((size_t)b * n + q) * CHID + t] = m;
}

// --------------------------------------------------------------- up MLP ----
// R5: point-tiled. TP points per block; thread t owns output channel t with
// acc[TP] registers. Weight loads amortized TP x (was 1 point/block => the
// whole W re-read from L2 per point: 1.6 GB L2 traffic each for up0/up1).
// LDS reads are wave-uniform float4 broadcasts (no bank conflicts).
template<int CIN, int CPRV, int COUT, int TP>
__global__ __launch_bounds__(COUT) void up_kernel(
    const float* __restrict__ xc, int ncoarse,
    const int* __restrict__ idx3, const float* __restrict__ d23,
    const float* __restrict__ prv, const float* __restrict__ W,
    const float* __restrict__ bvec, float* __restrict__ out, int m) {
  const int CTOT = CIN + CPRV;
  __shared__ float sCat[TP][CTOT];
  __shared__ float sWt[TP][3];
  __shared__ int   sIt[TP][3];
  int b = blockIdx.y, q0 = blockIdx.x * TP, t = threadIdx.x;
  if (t < TP) {
    size_t base = ((size_t)b * m + q0 + t) * 3;
    float d0 = d23[base + 0], d1 = d23[base + 1], d2v = d23[base + 2];
    float w0 = 1.f / (d0 + 1e-8f), w1 = 1.f / (d1 + 1e-8f), w2 = 1.f / (d2v + 1e-8f);
    float s = w0 + w1 + w2;
    sWt[t][0] = w0 / s; sWt[t][1] = w1 / s; sWt[t][2] = w2 / s;
    sIt[t][0] = idx3[base + 0]; sIt[t][1] = idx3[base + 1]; sIt[t][2] = idx3[base + 2];
  }
  __syncthreads();
  const float* xb = xc + (size_t)b * ncoarse * CIN;
  const float* pvb = prv + ((size_t)b * m + q0) * CPRV;
  for (int e = t; e < TP * CIN; e += COUT) {
    int p = e / CIN, c = e % CIN;  // CIN is a power of 2
    sCat[p][c] = sWt[p][0] * xb[(size_t)sIt[p][0] * CIN + c]
               + sWt[p][1] * xb[(size_t)sIt[p][1] * CIN + c]
               + sWt[p][2] * xb[(size_t)sIt[p][2] * CIN + c];
  }
  for (int e = t; e < TP * CPRV; e += COUT) {
    int p = e / CPRV, c = e % CPRV;  // CPRV is a power of 2
    sCat[p][CIN + c] = pvb[(size_t)p * CPRV + c];
  }
  __syncthreads();
  float acc[TP];
  float bb = bvec[t];
#pragma unroll
  for (int p = 0; p < TP; ++p) acc[p] = bb;
  for (int c4 = 0; c4 < CTOT / 4; ++c4) {
    int c = 4 * c4;
    float w0 = W[(c + 0) * COUT + t];
    float w1 = W[(c + 1) * COUT + t];
    float w2 = W[(c + 2) * COUT + t];
    float w3 = W[(c + 3) * COUT + t];
#pragma unroll
    for (int p = 0; p < TP; ++p) {
      float4 v = *(const float4*)&sCat[p][c];
      acc[p] = fmaf(v.x, w0, acc[p]);
      acc[p] = fmaf(v.y, w1, acc[p]);
      acc[p] = fmaf(v.z, w2, acc[p]);
      acc[p] = fmaf(v.w, w3, acc[p]);
    }
  }
#pragma unroll
  for (int p = 0; p < TP; ++p)
    out[((size_t)b * m + q0 + p) * COUT + t] = fmaxf(acc[p], 0.f);
}

// ---------------------------------------------- fused up2 + final MLP ------
// R5: point-tiled (TP points/block). Was 1 point/block => 200 KB weights
// re-read from L2 per point = 6.4 GB L2 traffic ~ 186 us at 34.5 TB/s (the
// measured 220 us). Tiling cuts weight traffic TP x; FLOP floor is ~21 us.
template<int TP>
__global__ __launch_bounds__(128) void up2_final_kernel(
    const float* __restrict__ xc,
    const int* __restrict__ idx3, const float* __restrict__ d23,
    const float* __restrict__ x0, const float* __restrict__ pos0,
    const float* __restrict__ u2W, const float* __restrict__ u2b,
    const float* __restrict__ fW1, const float* __restrict__ fb1,
    const float* __restrict__ fW2, const float* __restrict__ fb2,
    float* __restrict__ out) {
  __shared__ float sA[TP][136];
  __shared__ float sB[TP][128];
  __shared__ float sWt[TP][3];
  __shared__ int   sIt[TP][3];
  int b = blockIdx.y, q0 = blockIdx.x * TP, t = threadIdx.x;
  if (t < TP) {
    size_t base = ((size_t)b * NFULL + q0 + t) * 3;
    float d0 = d23[base + 0], d1 = d23[base + 1], d2v = d23[base + 2];
    float w0 = 1.f / (d0 + 1e-8f), w1 = 1.f / (d1 + 1e-8f), w2 = 1.f / (d2v + 1e-8f);
    float s = w0 + w1 + w2;
    sWt[t][0] = w0 / s; sWt[t][1] = w1 / s; sWt[t][2] = w2 / s;
    sIt[t][0] = idx3[base + 0]; sIt[t][1] = idx3[base + 1]; sIt[t][2] = idx3[base + 2];
  }
  __syncthreads();
  const float* xb = xc + (size_t)b * 2048 * 128;
#pragma unroll
  for (int p = 0; p < TP; ++p) {
    sA[p][t] = sWt[p][0] * xb[(size_t)sIt[p][0] * 128 + t]
             + sWt[p][1] * xb[(size_t)sIt[p][1] * 128 + t]
             + sWt[p][2] * xb[(size_t)sIt[p][2] * 128 + t];
  }
  if (t < TP * 6) {
    int p = t / 6, c = t % 6;
    const float* src = (c < 3) ? x0 : pos0;
    int cc = (c < 3) ? c : c - 3;
    sA[p][128 + c] = src[((size_t)b * NFULL + q0 + p) * 3 + cc];
  }
  __syncthreads();
  // layer 1: relu(cat(134) @ u2W + u2b) -> sB
  float acc[TP];
  float bb = u2b[t];
#pragma unroll
  for (int p = 0; p < TP; ++p) acc[p] = bb;
  for (int c4 = 0; c4 < 33; ++c4) {
    int c = 4 * c4;
    float w0 = u2W[(c + 0) * 128 + t];
    float w1 = u2W[(c + 1) * 128 + t];
    float w2 = u2W[(c + 2) * 128 + t];
    float w3 = u2W[(c + 3) * 128 + t];
#pragma unroll
    for (int p = 0; p < TP; ++p) {
      float4 v = *(const float4*)&sA[p][c];
      acc[p] = fmaf(v.x, w0, acc[p]);
      acc[p] = fmaf(v.y, w1, acc[p]);
      acc[p] = fmaf(v.z, w2, acc[p]);
      acc[p] = fmaf(v.w, w3, acc[p]);
    }
  }
  {
    float wa = u2W[132 * 128 + t], wbv = u2W[133 * 128 + t];
#pragma unroll
    for (int p = 0; p < TP; ++p) {
      acc[p] = fmaf(sA[p][132], wa, acc[p]);
      acc[p] = fmaf(sA[p][133], wbv, acc[p]);
      sB[p][t] = fmaxf(acc[p], 0.f);
    }
  }
  __syncthreads();
  // layer 2: relu(sB @ fW1 + fb1) -> sA (sA reads all completed pre-sync)
  float acc2[TP];
  float bb2 = fb1[t];
#pragma unroll
  for (int p = 0; p < TP; ++p) acc2[p] = bb2;
  for (int c4 = 0; c4 < 32; ++c4) {
    int c = 4 * c4;
    float w0 = fW1[(c + 0) * 128 + t];
    float w1 = fW1[(c + 1) * 128 + t];
    float w2 = fW1[(c + 2) * 128 + t];
    float w3 = fW1[(c + 3) * 128 + t];
#pragma unroll
    for (int p = 0; p < TP; ++p) {
      float4 v = *(const float4*)&sB[p][c];
      acc2[p] = fmaf(v.x, w0, acc2[p]);
      acc2[p] = fmaf(v.y, w1, acc2[p]);
      acc2[p] = fmaf(v.z, w2, acc2[p]);
      acc2[p] = fmaf(v.w, w3, acc2[p]);
    }
  }
#pragma unroll
  for (int p = 0; p < TP; ++p) sA[p][t] = fmaxf(acc2[p], 0.f);
  __syncthreads();
  // layer 3: sA @ fW2 + fb2 -> out
  float acc3[TP];
  float bb3 = fb2[t];
#pragma unroll
  for (int p = 0; p < TP; ++p) acc3[p] = bb3;
  for (int c4 = 0; c4 < 32; ++c4) {
    int c = 4 * c4;
    float w0 = fW2[(c + 0) * 128 + t];
    float w1 = fW2[(c + 1) * 128 + t];
    float w2 = fW2[(c + 2) * 128 + t];
    float w3 = fW2[(c + 3) * 128 + t];
#pragma unroll
    for (int p = 0; p < TP; ++p) {
      float4 v = *(const float4*)&sA[p][c];
      acc3[p] = fmaf(v.x, w0, acc3[p]);
      acc3[p] = fmaf(v.y, w1, acc3[p]);
      acc3[p] = fmaf(v.z, w2, acc3[p]);
      acc3[p] = fmaf(v.w, w3, acc3[p]);
    }
  }
#pragma unroll
  for (int p = 0; p < TP; ++p)
    out[((size_t)b * NFULL + q0 + p) * 128 + t] = acc3[p];
}

__global__ void copy_kernel(const float* __restrict__ src, float* __restrict__ dst, int n) {
  int i = blockIdx.x * blockDim.x + threadIdx.x;
  if (i < n) dst[i] = src[i];
}

// ------------------------------------------------------------------ launch -
extern "C" void kernel_launch(void* const* d_in, const int* in_sizes, int n_in,
                              void* d_out, int out_size, void* d_ws, size_t ws_size,
                              hipStream_t stream) {
  const float* x    = (const float*)d_in[0];
  const float* pos  = (const float*)d_in[1];
  const float* d0W1 = (const float*)d_in[2];
  const float* d0b1 = (const float*)d_in[3];
  const float* d0W2 = (const float*)d_in[4];
  const float* d0b2 = (const float*)d_in[5];
  const float* d1W1 = (const float*)d_in[6];
  const float* d1b1 = (const float*)d_in[7];
  const float* d1W2 = (const float*)d_in[8];
  const float* d1b2 = (const float*)d_in[9];
  const float* d2W1 = (const float*)d_in[10];
  const float* d2b1 = (const float*)d_in[11];
  const float* d2W2 = (const float*)d_in[12];
  const float* d2b2 = (const float*)d_in[13];
  const float* u0W  = (const float*)d_in[14];
  const float* u0b  = (const float*)d_in[15];
  const float* u1W  = (const float*)d_in[16];
  const float* u1b  = (const float*)d_in[17];
  const float* u2W  = (const float*)d_in[18];
  const float* u2b  = (const float*)d_in[19];
  const float* fW1  = (const float*)d_in[20];
  const float* fb1  = (const float*)d_in[21];
  const float* fW2  = (const float*)d_in[22];
  const float* fb2  = (const float*)d_in[23];

  char* ws = (char*)d_ws;
  float* x1    = (float*)(ws + 0);
  float* x2    = (float*)(ws + 4194304);
  float* x3    = (float*)(ws + 6291456);
  float* up0o  = (float*)(ws + 7340032);
  float* up1o  = (float*)(ws + 9437184);
  int*   idx0  = (int*)  (ws + 13631488);
  int*   idx1  = (int*)  (ws + 14155776);
  int*   idx2  = (int*)  (ws + 14286848);
  float* d2s   = (float*)(ws + 14319616);
  int*   idxu0 = (int*)  (ws + 14843904);
  float* d2u0  = (float*)(ws + 14868480);
  int*   idxu1 = (int*)  (ws + 14893056);
  float* d2u1  = (float*)(ws + 14991360);
  int*   idxu2 = (int*)  (ws + 15089664);
  float* d2u2  = (float*)(ws + 15482880);

  float* out = (float*)d_out;

  // ---- down path ----
  knn_kernel<16, 16, 4, true><<<dim3(512, BATCH), 256, 0, stream>>>(pos, 8192, 2048, idx0, d2s);
  down_kernel<6, 8, 3, 128><<<dim3(2048, BATCH), 128, 0, stream>>>(
      pos, x, idx0, d0W1, d0b1, d0W2, d0b2, x1, 2048, 8192);
  knn_kernel<16, 16, 4, false><<<dim3(128, BATCH), 256, 0, stream>>>(pos, 2048, 512, idx1, d2s);
  down_kernel<131, 132, 128, 256><<<dim3(512, BATCH), 256, 0, stream>>>(
      pos, x1, idx1, d1W1, d1b1, d1W2, d1b2, x2, 512, 2048);
  knn_kernel<16, 16, 4, false><<<dim3(32, BATCH), 256, 0, stream>>>(pos, 512, 128, idx2, d2s);
  down_kernel<259, 260, 256, 512><<<dim3(128, BATCH), 512, 0, stream>>>(
      pos, x2, idx2, d2W1, d2b1, d2W2, d2b2, x3, 128, 512);

  // ---- up path (point-tiled) ----
  knn_kernel<4, 3, 4, false><<<dim3(128, BATCH), 256, 0, stream>>>(pos, 128, 512, idxu0, d2u0);
  up_kernel<512, 256, 256, 8><<<dim3(64, BATCH), 256, 0, stream>>>(
      x3, 128, idxu0, d2u0, x2, u0W, u0b, up0o, 512);
  knn_kernel<4, 3, 4, false><<<dim3(512, BATCH), 256, 0, stream>>>(pos, 512, 2048, idxu1, d2u1);
  up_kernel<256, 128, 128, 16><<<dim3(128, BATCH), 128, 0, stream>>>(
      up0o, 512, idxu1, d2u1, x1, u1W, u1b, up1o, 2048);
  knn_kernel<4, 3, 4, false><<<dim3(2048, BATCH), 256, 0, stream>>>(pos, 2048, 8192, idxu2, d2u2);
  up2_final_kernel<16><<<dim3(512, BATCH), 128, 0, stream>>>(
      up1o, idxu2, d2u2, x, pos, u2W, u2b, fW1, fb1, fW2, fb2, out);

  // ---- second tuple element: pos passthrough ----
  copy_kernel<<<dim3(384), 256, 0, stream>>>(pos, out + (size_t)BATCH * NFULL * 128,
                                             BATCH * NFULL * 3);
}

// Round 6
// 692.329 us; speedup vs baseline: 1.7721x; 1.2196x over previous
//
#include <hip/hip_runtime.h>

#define NFULL 8192
#define BATCH 4

typedef unsigned long long u64;
typedef unsigned int u32;
typedef unsigned short ushort_t;
typedef __attribute__((ext_vector_type(8))) short bf8_t;   // 8 bf16 (4 VGPRs)
typedef __attribute__((ext_vector_type(4))) float f4_t;    // MFMA C/D

// Total-order bias: monotone map fp32 -> u32 (handles negatives correctly).
__device__ __forceinline__ u32 fbias(float f) {
  u32 u = __float_as_uint(f);
  return (u & 0x80000000u) ? ~u : (u | 0x80000000u);
}
__device__ __forceinline__ float funbias(u32 b) {
  u32 u = (b & 0x80000000u) ? (b & 0x7fffffffu) : ~b;
  return __uint_as_float(u);
}
// fp32 -> bf16 round-to-nearest-even
__device__ __forceinline__ short f2bf(float f) {
  u32 u = __float_as_uint(f);
  u32 r = u + 0x7FFFu + ((u >> 16) & 1u);
  return (short)(r >> 16);
}

// ---------------------------------------------------------------- kNN ------
// Wave-per-query, hybrid exact-threshold guard for the big scan (see R4).
template<int K, int KOUT, int QPB, bool HYBRID>
__global__ __launch_bounds__(64 * QPB) void knn_kernel(
    const float* __restrict__ pos, int Nref, int Mq,
    int* __restrict__ oidx, float* __restrict__ od2) {
  const int TILE = 256;
  __shared__ float4 sRef[TILE];
  int b = blockIdx.y;
  int w = threadIdx.x >> 6, lane = threadIdx.x & 63;
  int q = blockIdx.x * QPB + w;  // all Mq are multiples of QPB
  const float* pb = pos + (size_t)b * NFULL * 3;
  float qx = pb[q * 3 + 0], qy = pb[q * 3 + 1], qz = pb[q * 3 + 2];
  float qq = qx * qx + qy * qy + qz * qz;

  u64 key[K];
#pragma unroll
  for (int i = 0; i < K; ++i) key[i] = ~0ull;

  int split = HYBRID ? (Nref < 1024 ? Nref : 1024) : Nref;
  for (int t0 = 0; t0 < split; t0 += TILE) {
    int cnt = min(TILE, Nref - t0);
    __syncthreads();
    for (int j = threadIdx.x; j < cnt; j += 64 * QPB) {
      float rx = pb[(t0 + j) * 3 + 0];
      float ry = pb[(t0 + j) * 3 + 1];
      float rz = pb[(t0 + j) * 3 + 2];
      sRef[j] = make_float4(rx, ry, rz, rx * rx + ry * ry + rz * rz);
    }
    __syncthreads();
#pragma unroll
    for (int c = 0; c < TILE / 64; ++c) {
      int j = lane + 64 * c;
      if (j < cnt) {
        float4 r = sRef[j];
        float d2 = qq + r.w - 2.0f * (qx * r.x + qy * r.y + qz * r.z);
        u64 ck = ((u64)fbias(d2) << 32) | (u32)(t0 + j);
        if (ck < key[K - 1]) {
          key[K - 1] = ck;
#pragma unroll
          for (int s = K - 1; s > 0; --s) {
            if (key[s] < key[s - 1]) {
              u64 t = key[s]; key[s] = key[s - 1]; key[s - 1] = t;
            }
          }
        }
      }
    }
  }

#pragma unroll
  for (int s = 1; s < 64; s <<= 1) {
    u64 other[K];
#pragma unroll
    for (int i = 0; i < K; ++i)
      other[i] = __shfl_xor((unsigned long long)key[i], s, 64);
#pragma unroll
    for (int i = 0; i < K; ++i) {
      u64 o = other[K - 1 - i];
      key[i] = (key[i] < o) ? key[i] : o;
    }
#pragma unroll
    for (int d = K / 2; d >= 1; d >>= 1) {
#pragma unroll
      for (int i = 0; i < K; ++i) {
        if ((i & d) == 0) {
          if (key[i + d] < key[i]) {
            u64 t = key[i]; key[i] = key[i + d]; key[i + d] = t;
          }
        }
      }
    }
  }

  if (HYBRID) {
    for (int t0 = split; t0 < Nref; t0 += TILE) {
      int cnt = min(TILE, Nref - t0);
      __syncthreads();
      for (int j = threadIdx.x; j < cnt; j += 64 * QPB) {
        float rx = pb[(t0 + j) * 3 + 0];
        float ry = pb[(t0 + j) * 3 + 1];
        float rz = pb[(t0 + j) * 3 + 2];
        sRef[j] = make_float4(rx, ry, rz, rx * rx + ry * ry + rz * rz);
      }
      __syncthreads();
#pragma unroll
      for (int c = 0; c < TILE / 64; ++c) {
        int j = lane + 64 * c;
        float4 r = sRef[j];
        float d2 = qq + r.w - 2.0f * (qx * r.x + qy * r.y + qz * r.z);
        u64 ck = ((u64)fbias(d2) << 32) | (u32)(t0 + j);
        u64 mask = __ballot(ck < key[K - 1]);
        while (mask) {
          int src = __ffsll(mask) - 1;
          u64 cks = __shfl((unsigned long long)ck, src, 64);
          if (cks < key[K - 1]) {
            key[K - 1] = cks;
#pragma unroll
            for (int s = K - 1; s > 0; --s) {
              if (key[s] < key[s - 1]) {
                u64 t = key[s]; key[s] = key[s - 1]; key[s - 1] = t;
              }
            }
          }
          mask &= mask - 1;
        }
      }
    }
  }

  if (lane == 0) {
    size_t base = ((size_t)b * Mq + q) * KOUT;
#pragma unroll
    for (int i = 0; i < KOUT; ++i) {
      oidx[base + i] = (int)(u32)key[i];
      od2[base + i] = fmaxf(funbias((u32)(key[i] >> 32)), 0.0f);
    }
  }
}

// -------------------------------------------------- weight packing (bf16) --
// Pack W (KDIM x N fp32, row-major) into MFMA B-fragment tile order for
// mfma_f32_16x16x32_bf16: tile (kt,nt) holds B[k=kt*32+(lane>>4)*8+j]
// [n=nt*16+(lane&15)], 8 bf16 contiguous per lane => one dwordx4 load.
// Rows k >= KDIM are zero (K-padding contributes 0 to the accumulator).
template<int KDIM, int N>
__global__ __launch_bounds__(64) void pack_w_kernel(
    const float* __restrict__ W, short* __restrict__ outp) {
  const int NT = N / 16;
  int tile = blockIdx.x;
  int kt = tile / NT, nt = tile % NT;
  int lane = threadIdx.x;
  int n = nt * 16 + (lane & 15);
  int k0 = kt * 32 + (lane >> 4) * 8;
  bf8_t v;
#pragma unroll
  for (int j = 0; j < 8; ++j) {
    int k = k0 + j;
    v[j] = (k < KDIM) ? f2bf(W[(size_t)k * N + n]) : (short)0;
  }
  *(bf8_t*)(outp + ((size_t)tile * 64 + lane) * 8) = v;
}

// ----------------------------------------------------- down MLP (MFMA) -----
// One wave per (center, nt-slice); WPB waves/block share one center's LDS.
// M=16 = the K neighbors. feat staged in LDS as bf16 in row-major order so
// A-frags (A[m=lane&15][k=quad*8+j], m89/m91 layout) are single ds_read_b128;
// h1 likewise. B-tiles come from the packed weights (1 dwordx4/lane/tile).
// Bias folds into acc init; k-max epilogue = 3 fmax + 2 shfl_xor (bias is
// constant over k so it commutes with the max).
template<int FEAT, int CIN, int CHID, int FPAD, int WPB>
__global__ __launch_bounds__(64 * WPB) void down_mfma_kernel(
    const float* __restrict__ pos, const float* __restrict__ xin,
    const int* __restrict__ idx,
    const short* __restrict__ W1p, const float* __restrict__ b1,
    const short* __restrict__ W2p, const float* __restrict__ b2,
    float* __restrict__ out, int n, int nprev) {
  const int KT1 = FPAD / 32, NT1 = CHID / 16;
  const int KT2 = CHID / 32, NT2 = CHID / 16;
  __shared__ short sFeat[16][FPAD];
  __shared__ short sH1[16][CHID];
  __shared__ int sIdx[16];
  __shared__ float sCtr[3];
  int b = blockIdx.y, q = blockIdx.x;
  int lane = threadIdx.x & 63, wv = threadIdx.x >> 6;
  const float* pb = pos + (size_t)b * NFULL * 3;
  const float* xb = xin + (size_t)b * nprev * CIN;
  if (threadIdx.x < 16) sIdx[threadIdx.x] = idx[((size_t)b * n + q) * 16 + threadIdx.x];
  if (threadIdx.x < 3) sCtr[threadIdx.x] = pb[q * 3 + threadIdx.x];
  __syncthreads();
  for (int e = threadIdx.x; e < 16 * FPAD; e += 64 * WPB) {
    int k = e / FPAD, c = e % FPAD;
    float v = 0.f;
    if (c < 3) v = pb[sIdx[k] * 3 + c] - sCtr[c];
    else if (c < FEAT) v = xb[(size_t)sIdx[k] * CIN + (c - 3)];
    sFeat[k][c] = f2bf(v);
  }
  __syncthreads();

  int col = lane & 15, quad = lane >> 4;
  // ---- layer 1: h1 = relu(feat @ W1 + b1) ----
  bf8_t afr[KT1];
#pragma unroll
  for (int kt = 0; kt < KT1; ++kt)
    afr[kt] = *(const bf8_t*)&sFeat[col][kt * 32 + quad * 8];
  const bf8_t* W1t = (const bf8_t*)W1p;
  for (int nt = 2 * wv; nt < NT1; nt += 2 * WPB) {
    float bb0 = b1[nt * 16 + col], bb1 = b1[nt * 16 + 16 + col];
    f4_t acc0 = {bb0, bb0, bb0, bb0}, acc1 = {bb1, bb1, bb1, bb1};
#pragma unroll
    for (int kt = 0; kt < KT1; ++kt) {
      bf8_t bf0 = W1t[(kt * NT1 + nt) * 64 + lane];
      bf8_t bf1 = W1t[(kt * NT1 + nt + 1) * 64 + lane];
      acc0 = __builtin_amdgcn_mfma_f32_16x16x32_bf16(afr[kt], bf0, acc0, 0, 0, 0);
      acc1 = __builtin_amdgcn_mfma_f32_16x16x32_bf16(afr[kt], bf1, acc1, 0, 0, 0);
    }
#pragma unroll
    for (int r = 0; r < 4; ++r) {  // D: col=lane&15, row=quad*4+r
      sH1[quad * 4 + r][nt * 16 + col] = f2bf(fmaxf(acc0[r], 0.f));
      sH1[quad * 4 + r][nt * 16 + 16 + col] = f2bf(fmaxf(acc1[r], 0.f));
    }
  }
  __syncthreads();

  // ---- layer 2: out = max_k (h1 @ W2 + b2) ----
  bf8_t afr2[KT2];
#pragma unroll
  for (int kt = 0; kt < KT2; ++kt)
    afr2[kt] = *(const bf8_t*)&sH1[col][kt * 32 + quad * 8];
  const bf8_t* W2t = (const bf8_t*)W2p;
  float* ob = out + ((size_t)b * n + q) * CHID;
  for (int nt = 2 * wv; nt < NT2; nt += 2 * WPB) {
    float bb0 = b2[nt * 16 + col], bb1 = b2[nt * 16 + 16 + col];
    f4_t acc0 = {bb0, bb0, bb0, bb0}, acc1 = {bb1, bb1, bb1, bb1};
#pragma unroll
    for (int kt = 0; kt < KT2; ++kt) {
      bf8_t bf0 = W2t[(kt * NT2 + nt) * 64 + lane];
      bf8_t bf1 = W2t[(kt * NT2 + nt + 1) * 64 + lane];
      acc0 = __builtin_amdgcn_mfma_f32_16x16x32_bf16(afr2[kt], bf0, acc0, 0, 0, 0);
      acc1 = __builtin_amdgcn_mfma_f32_16x16x32_bf16(afr2[kt], bf1, acc1, 0, 0, 0);
    }
    float m0 = fmaxf(fmaxf(acc0[0], acc0[1]), fmaxf(acc0[2], acc0[3]));
    float m1 = fmaxf(fmaxf(acc1[0], acc1[1]), fmaxf(acc1[2], acc1[3]));
    m0 = fmaxf(m0, __shfl_xor(m0, 16, 64));
    m0 = fmaxf(m0, __shfl_xor(m0, 32, 64));
    m1 = fmaxf(m1, __shfl_xor(m1, 16, 64));
    m1 = fmaxf(m1, __shfl_xor(m1, 32, 64));
    if (lane < 16) {
      ob[nt * 16 + lane] = m0;
      ob[nt * 16 + 16 + lane] = m1;
    }
  }
}

// ------------------------------------------------------------- down MLP ----
// VALU path, kept for d0 only (FEAT=6: gather-bound, not matmul-bound).
template<int FEAT, int FEATP, int CIN, int CHID>
__global__ __launch_bounds__(CHID) void down_kernel(
    const float* __restrict__ pos, const float* __restrict__ xin,
    const int* __restrict__ idx, const float* __restrict__ W1,
    const float* __restrict__ b1, const float* __restrict__ W2,
    const float* __restrict__ b2, float* __restrict__ out,
    int n, int nprev) {
  const int K = 16;
  __shared__ int sIdx[K];
  __shared__ float sCtr[3];
  __shared__ float sFeat[K][FEATP];
  __shared__ float sH1[K][CHID];
  int b = blockIdx.y, q = blockIdx.x, t = threadIdx.x;
  const float* pb = pos + (size_t)b * NFULL * 3;
  const float* xb = xin + (size_t)b * nprev * CIN;
  if (t < K) sIdx[t] = idx[((size_t)b * n + q) * K + t];
  if (t < 3) sCtr[t] = pb[q * 3 + t];
  __syncthreads();
  for (int e = t; e < K * FEATP; e += CHID) {
    int k = e / FEATP, c = e % FEATP;
    float v = 0.f;
    if (c < 3) v = pb[sIdx[k] * 3 + c] - sCtr[c];
    else if (c < FEAT) v = xb[(size_t)sIdx[k] * CIN + (c - 3)];
    sFeat[k][c] = v;
  }
  __syncthreads();
  float acc[K];
  float bb = b1[t];
#pragma unroll
  for (int k = 0; k < K; ++k) acc[k] = bb;
  for (int c4 = 0; c4 < FEAT / 4; ++c4) {
    int c = c4 * 4;
    float w0 = W1[(c + 0) * CHID + t];
    float w1 = W1[(c + 1) * CHID + t];
    float w2 = W1[(c + 2) * CHID + t];
    float w3 = W1[(c + 3) * CHID + t];
#pragma unroll
    for (int k = 0; k < K; ++k) {
      float4 f = *(const float4*)&sFeat[k][c];
      acc[k] = fmaf(f.x, w0, acc[k]);
      acc[k] = fmaf(f.y, w1, acc[k]);
      acc[k] = fmaf(f.z, w2, acc[k]);
      acc[k] = fmaf(f.w, w3, acc[k]);
    }
  }
  for (int c = (FEAT / 4) * 4; c < FEAT; ++c) {
    float w = W1[c * CHID + t];
#pragma unroll
    for (int k = 0; k < K; ++k) acc[k] = fmaf(sFeat[k][c], w, acc[k]);
  }
#pragma unroll
  for (int k = 0; k < K; ++k) sH1[k][t] = fmaxf(acc[k], 0.f);
  __syncthreads();
  float acc2[K];
  float bb2 = b2[t];
#pragma unroll
  for (int k = 0; k < K; ++k) acc2[k] = bb2;
  for (int c4 = 0; c4 < CHID / 4; ++c4) {
    int c = c4 * 4;
    float w0 = W2[(c + 0) * CHID + t];
    float w1 = W2[(c + 1) * CHID + t];
    float w2 = W2[(c + 2) * CHID + t];
    float w3 = W2[(c + 3) * CHID + t];
#pragma unroll
    for (int k = 0; k < K; ++k) {
      float4 h = *(const float4*)&sH1[k][c];
      acc2[k] = fmaf(h.x, w0, acc2[k]);
      acc2[k] = fmaf(h.y, w1, acc2[k]);
      acc2[k] = fmaf(h.z, w2, acc2[k]);
      acc2[k] = fmaf(h.w, w3, acc2[k]);
    }
  }
  float m = acc2[0];
#pragma unroll
  for (int k = 1; k < K; ++k) m = fmaxf(m, acc2[k]);
  out[((size_t)b * n + q) * CHID + t] = m;
}

// --------------------------------------------------------------- up MLP ----
template<int CIN, int CPRV, int COUT, int TP>
__global__ __launch_bounds__(COUT) void up_kernel(
    const float* __restrict__ xc, int ncoarse,
    const int* __restrict__ idx3, const float* __restrict__ d23,
    const float* __restrict__ prv, const float* __restrict__ W,
    const float* __restrict__ bvec, float* __restrict__ out, int m) {
  const int CTOT = CIN + CPRV;
  __shared__ float sCat[TP][CTOT];
  __shared__ float sWt[TP][3];
  __shared__ int   sIt[TP][3];
  int b = blockIdx.y, q0 = blockIdx.x * TP, t = threadIdx.x;
  if (t < TP) {
    size_t base = ((size_t)b * m + q0 + t) * 3;
    float d0 = d23[base + 0], d1 = d23[base + 1], d2v = d23[base + 2];
    float w0 = 1.f / (d0 + 1e-8f), w1 = 1.f / (d1 + 1e-8f), w2 = 1.f / (d2v + 1e-8f);
    float s = w0 + w1 + w2;
    sWt[t][0] = w0 / s; sWt[t][1] = w1 / s; sWt[t][2] = w2 / s;
    sIt[t][0] = idx3[base + 0]; sIt[t][1] = idx3[base + 1]; sIt[t][2] = idx3[base + 2];
  }
  __syncthreads();
  const float* xb = xc + (size_t)b * ncoarse * CIN;
  const float* pvb = prv + ((size_t)b * m + q0) * CPRV;
  for (int e = t; e < TP * CIN; e += COUT) {
    int p = e / CIN, c = e % CIN;
    sCat[p][c] = sWt[p][0] * xb[(size_t)sIt[p][0] * CIN + c]
               + sWt[p][1] * xb[(size_t)sIt[p][1] * CIN + c]
               + sWt[p][2] * xb[(size_t)sIt[p][2] * CIN + c];
  }
  for (int e = t; e < TP * CPRV; e += COUT) {
    int p = e / CPRV, c = e % CPRV;
    sCat[p][CIN + c] = pvb[(size_t)p * CPRV + c];
  }
  __syncthreads();
  float acc[TP];
  float bb = bvec[t];
#pragma unroll
  for (int p = 0; p < TP; ++p) acc[p] = bb;
  for (int c4 = 0; c4 < CTOT / 4; ++c4) {
    int c = 4 * c4;
    float w0 = W[(c + 0) * COUT + t];
    float w1 = W[(c + 1) * COUT + t];
    float w2 = W[(c + 2) * COUT + t];
    float w3 = W[(c + 3) * COUT + t];
#pragma unroll
    for (int p = 0; p < TP; ++p) {
      float4 v = *(const float4*)&sCat[p][c];
      acc[p] = fmaf(v.x, w0, acc[p]);
      acc[p] = fmaf(v.y, w1, acc[p]);
      acc[p] = fmaf(v.z, w2, acc[p]);
      acc[p] = fmaf(v.w, w3, acc[p]);
    }
  }
#pragma unroll
  for (int p = 0; p < TP; ++p)
    out[((size_t)b * m + q0 + p) * COUT + t] = fmaxf(acc[p], 0.f);
}

// ---------------------------------------------- fused up2 + final MLP ------
template<int TP>
__global__ __launch_bounds__(128) void up2_final_kernel(
    const float* __restrict__ xc,
    const int* __restrict__ idx3, const float* __restrict__ d23,
    const float* __restrict__ x0, const float* __restrict__ pos0,
    const float* __restrict__ u2W, const float* __restrict__ u2b,
    const float* __restrict__ fW1, const float* __restrict__ fb1,
    const float* __restrict__ fW2, const float* __restrict__ fb2,
    float* __restrict__ out) {
  __shared__ float sA[TP][136];
  __shared__ float sB[TP][128];
  __shared__ float sWt[TP][3];
  __shared__ int   sIt[TP][3];
  int b = blockIdx.y, q0 = blockIdx.x * TP, t = threadIdx.x;
  if (t < TP) {
    size_t base = ((size_t)b * NFULL + q0 + t) * 3;
    float d0 = d23[base + 0], d1 = d23[base + 1], d2v = d23[base + 2];
    float w0 = 1.f / (d0 + 1e-8f), w1 = 1.f / (d1 + 1e-8f), w2 = 1.f / (d2v + 1e-8f);
    float s = w0 + w1 + w2;
    sWt[t][0] = w0 / s; sWt[t][1] = w1 / s; sWt[t][2] = w2 / s;
    sIt[t][0] = idx3[base + 0]; sIt[t][1] = idx3[base + 1]; sIt[t][2] = idx3[base + 2];
  }
  __syncthreads();
  const float* xb = xc + (size_t)b * 2048 * 128;
#pragma unroll
  for (int p = 0; p < TP; ++p) {
    sA[p][t] = sWt[p][0] * xb[(size_t)sIt[p][0] * 128 + t]
             + sWt[p][1] * xb[(size_t)sIt[p][1] * 128 + t]
             + sWt[p][2] * xb[(size_t)sIt[p][2] * 128 + t];
  }
  if (t < TP * 6) {
    int p = t / 6, c = t % 6;
    const float* src = (c < 3) ? x0 : pos0;
    int cc = (c < 3) ? c : c - 3;
    sA[p][128 + c] = src[((size_t)b * NFULL + q0 + p) * 3 + cc];
  }
  __syncthreads();
  float acc[TP];
  float bb = u2b[t];
#pragma unroll
  for (int p = 0; p < TP; ++p) acc[p] = bb;
  for (int c4 = 0; c4 < 33; ++c4) {
    int c = 4 * c4;
    float w0 = u2W[(c + 0) * 128 + t];
    float w1 = u2W[(c + 1) * 128 + t];
    float w2 = u2W[(c + 2) * 128 + t];
    float w3 = u2W[(c + 3) * 128 + t];
#pragma unroll
    for (int p = 0; p < TP; ++p) {
      float4 v = *(const float4*)&sA[p][c];
      acc[p] = fmaf(v.x, w0, acc[p]);
      acc[p] = fmaf(v.y, w1, acc[p]);
      acc[p] = fmaf(v.z, w2, acc[p]);
      acc[p] = fmaf(v.w, w3, acc[p]);
    }
  }
  {
    float wa = u2W[132 * 128 + t], wbv = u2W[133 * 128 + t];
#pragma unroll
    for (int p = 0; p < TP; ++p) {
      acc[p] = fmaf(sA[p][132], wa, acc[p]);
      acc[p] = fmaf(sA[p][133], wbv, acc[p]);
      sB[p][t] = fmaxf(acc[p], 0.f);
    }
  }
  __syncthreads();
  float acc2[TP];
  float bb2 = fb1[t];
#pragma unroll
  for (int p = 0; p < TP; ++p) acc2[p] = bb2;
  for (int c4 = 0; c4 < 32; ++c4) {
    int c = 4 * c4;
    float w0 = fW1[(c + 0) * 128 + t];
    float w1 = fW1[(c + 1) * 128 + t];
    float w2 = fW1[(c + 2) * 128 + t];
    float w3 = fW1[(c + 3) * 128 + t];
#pragma unroll
    for (int p = 0; p < TP; ++p) {
      float4 v = *(const float4*)&sB[p][c];
      acc2[p] = fmaf(v.x, w0, acc2[p]);
      acc2[p] = fmaf(v.y, w1, acc2[p]);
      acc2[p] = fmaf(v.z, w2, acc2[p]);
      acc2[p] = fmaf(v.w, w3, acc2[p]);
    }
  }
#pragma unroll
  for (int p = 0; p < TP; ++p) sA[p][t] = fmaxf(acc2[p], 0.f);
  __syncthreads();
  float acc3[TP];
  float bb3 = fb2[t];
#pragma unroll
  for (int p = 0; p < TP; ++p) acc3[p] = bb3;
  for (int c4 = 0; c4 < 32; ++c4) {
    int c = 4 * c4;
    float w0 = fW2[(c + 0) * 128 + t];
    float w1 = fW2[(c + 1) * 128 + t];
    float w2 = fW2[(c + 2) * 128 + t];
    float w3 = fW2[(c + 3) * 128 + t];
#pragma unroll
    for (int p = 0; p < TP; ++p) {
      float4 v = *(const float4*)&sA[p][c];
      acc3[p] = fmaf(v.x, w0, acc3[p]);
      acc3[p] = fmaf(v.y, w1, acc3[p]);
      acc3[p] = fmaf(v.z, w2, acc3[p]);
      acc3[p] = fmaf(v.w, w3, acc3[p]);
    }
  }
#pragma unroll
  for (int p = 0; p < TP; ++p)
    out[((size_t)b * NFULL + q0 + p) * 128 + t] = acc3[p];
}

__global__ void copy_kernel(const float* __restrict__ src, float* __restrict__ dst, int n) {
  int i = blockIdx.x * blockDim.x + threadIdx.x;
  if (i < n) dst[i] = src[i];
}

// ------------------------------------------------------------------ launch -
extern "C" void kernel_launch(void* const* d_in, const int* in_sizes, int n_in,
                              void* d_out, int out_size, void* d_ws, size_t ws_size,
                              hipStream_t stream) {
  const float* x    = (const float*)d_in[0];
  const float* pos  = (const float*)d_in[1];
  const float* d0W1 = (const float*)d_in[2];
  const float* d0b1 = (const float*)d_in[3];
  const float* d0W2 = (const float*)d_in[4];
  const float* d0b2 = (const float*)d_in[5];
  const float* d1W1 = (const float*)d_in[6];
  const float* d1b1 = (const float*)d_in[7];
  const float* d1W2 = (const float*)d_in[8];
  const float* d1b2 = (const float*)d_in[9];
  const float* d2W1 = (const float*)d_in[10];
  const float* d2b1 = (const float*)d_in[11];
  const float* d2W2 = (const float*)d_in[12];
  const float* d2b2 = (const float*)d_in[13];
  const float* u0W  = (const float*)d_in[14];
  const float* u0b  = (const float*)d_in[15];
  const float* u1W  = (const float*)d_in[16];
  const float* u1b  = (const float*)d_in[17];
  const float* u2W  = (const float*)d_in[18];
  const float* u2b  = (const float*)d_in[19];
  const float* fW1  = (const float*)d_in[20];
  const float* fb1  = (const float*)d_in[21];
  const float* fW2  = (const float*)d_in[22];
  const float* fb2  = (const float*)d_in[23];

  char* ws = (char*)d_ws;
  float* x1    = (float*)(ws + 0);
  float* x2    = (float*)(ws + 4194304);
  float* x3    = (float*)(ws + 6291456);
  float* up0o  = (float*)(ws + 7340032);
  float* up1o  = (float*)(ws + 9437184);
  int*   idx0  = (int*)  (ws + 13631488);
  int*   idx1  = (int*)  (ws + 14155776);
  int*   idx2  = (int*)  (ws + 14286848);
  float* d2s   = (float*)(ws + 14319616);
  int*   idxu0 = (int*)  (ws + 14843904);
  float* d2u0  = (float*)(ws + 14868480);
  int*   idxu1 = (int*)  (ws + 14893056);
  float* d2u1  = (float*)(ws + 14991360);
  int*   idxu2 = (int*)  (ws + 15089664);
  float* d2u2  = (float*)(ws + 15482880);
  short* d1W1p = (short*)(ws + 15876096);  // 160*256*2  = 81920
  short* d1W2p = (short*)(ws + 15958016);  // 256*256*2  = 131072
  short* d2W1p = (short*)(ws + 16089088);  // 288*512*2  = 294912
  short* d2W2p = (short*)(ws + 16384000);  // 512*512*2  = 524288 (end 16908288)

  float* out = (float*)d_out;

  // ---- weight packing (bf16 MFMA-B layout); stream-ordered before use ----
  pack_w_kernel<131, 256><<<dim3(5 * 16), 64, 0, stream>>>(d1W1, d1W1p);
  pack_w_kernel<256, 256><<<dim3(8 * 16), 64, 0, stream>>>(d1W2, d1W2p);
  pack_w_kernel<259, 512><<<dim3(9 * 32), 64, 0, stream>>>(d2W1, d2W1p);
  pack_w_kernel<512, 512><<<dim3(16 * 32), 64, 0, stream>>>(d2W2, d2W2p);

  // ---- down path ----
  knn_kernel<16, 16, 4, true><<<dim3(512, BATCH), 256, 0, stream>>>(pos, 8192, 2048, idx0, d2s);
  down_kernel<6, 8, 3, 128><<<dim3(2048, BATCH), 128, 0, stream>>>(
      pos, x, idx0, d0W1, d0b1, d0W2, d0b2, x1, 2048, 8192);
  knn_kernel<16, 16, 4, false><<<dim3(128, BATCH), 256, 0, stream>>>(pos, 2048, 512, idx1, d2s);
  down_mfma_kernel<131, 128, 256, 160, 1><<<dim3(512, BATCH), 64, 0, stream>>>(
      pos, x1, idx1, d1W1p, d1b1, d1W2p, d1b2, x2, 512, 2048);
  knn_kernel<16, 16, 4, false><<<dim3(32, BATCH), 256, 0, stream>>>(pos, 512, 128, idx2, d2s);
  down_mfma_kernel<259, 256, 512, 288, 2><<<dim3(128, BATCH), 128, 0, stream>>>(
      pos, x2, idx2, d2W1p, d2b1, d2W2p, d2b2, x3, 128, 512);

  // ---- up path (point-tiled) ----
  knn_kernel<4, 3, 4, false><<<dim3(128, BATCH), 256, 0, stream>>>(pos, 128, 512, idxu0, d2u0);
  up_kernel<512, 256, 256, 8><<<dim3(64, BATCH), 256, 0, stream>>>(
      x3, 128, idxu0, d2u0, x2, u0W, u0b, up0o, 512);
  knn_kernel<4, 3, 4, false><<<dim3(512, BATCH), 256, 0, stream>>>(pos, 512, 2048, idxu1, d2u1);
  up_kernel<256, 128, 128, 16><<<dim3(128, BATCH), 128, 0, stream>>>(
      up0o, 512, idxu1, d2u1, x1, u1W, u1b, up1o, 2048);
  knn_kernel<4, 3, 4, false><<<dim3(2048, BATCH), 256, 0, stream>>>(pos, 2048, 8192, idxu2, d2u2);
  up2_final_kernel<16><<<dim3(512, BATCH), 128, 0, stream>>>(
      up1o, idxu2, d2u2, x, pos, u2W, u2b, fW1, fb1, fW2, fb2, out);

  // ---- second tuple element: pos passthrough ----
  copy_kernel<<<dim3(384), 256, 0, stream>>>(pos, out + (size_t)BATCH * NFULL * 128,
                                             BATCH * NFULL * 3);
}

// Round 7
// 691.790 us; speedup vs baseline: 1.7735x; 1.0008x over previous
//
#include <hip/hip_runtime.h>

#define NFULL 8192
#define BATCH 4

typedef unsigned long long u64;
typedef unsigned int u32;
typedef __attribute__((ext_vector_type(8))) short bf8_t;   // 8 bf16 (4 VGPRs)
typedef __attribute__((ext_vector_type(4))) float f4_t;    // MFMA C/D

// Total-order bias: monotone map fp32 -> u32 (handles negatives correctly).
__device__ __forceinline__ u32 fbias(float f) {
  u32 u = __float_as_uint(f);
  return (u & 0x80000000u) ? ~u : (u | 0x80000000u);
}
__device__ __forceinline__ float funbias(u32 b) {
  u32 u = (b & 0x80000000u) ? (b & 0x7fffffffu) : ~b;
  return __uint_as_float(u);
}
// fp32 -> bf16 round-to-nearest-even
__device__ __forceinline__ short f2bf(float f) {
  u32 u = __float_as_uint(f);
  u32 r = u + 0x7FFFu + ((u >> 16) & 1u);
  return (short)(r >> 16);
}

// ---------------------------------------------------------------- kNN ------
// R7: distributed top-K. Wave-per-query; the sorted top-SL list lives ONE
// ENTRY PER LANE (slot = lane & (SL-1), identical copies per SL-lane group).
// Keys are u64 (biased-d2 << 32 | idx) => lexicographic (d2, idx) order ==
// jax.lax.top_k stable tie-break. Each round: 64 candidates (one/lane),
// ballot against exact replicated kth (tau); passing candidates are
// broadcast-inserted serially at O(1) each:
//   prev = shfl_up(val,1); val = val<=c ? val : (prev<=c ? c : prev);
//   tau  = shfl(val, SL-1)
// (insert of c >= tau is a structural no-op, so stale-mask re-check is just
// an optimization). Sentinels ~0ull make warm-up automatic. Expected inserts
// = SL + SL*ln(Nref/SL) (~116 for Nref=8192,SL=16) at ~15 insts each vs ~100
// for the R6 replicated bubble; phase-A and the butterfly merge are gone.
template<int SL, int KOUT, int QPB>
__global__ __launch_bounds__(64 * QPB) void knn_kernel(
    const float* __restrict__ pos, int Nref, int Mq,
    int* __restrict__ oidx, float* __restrict__ od2) {
  const int TILE = 256;
  __shared__ float4 sRef[TILE];
  int b = blockIdx.y;
  int w = threadIdx.x >> 6, lane = threadIdx.x & 63;
  int q = blockIdx.x * QPB + w;  // all Mq are multiples of QPB
  const float* pb = pos + (size_t)b * NFULL * 3;
  float qx = pb[q * 3 + 0], qy = pb[q * 3 + 1], qz = pb[q * 3 + 2];
  float qq = qx * qx + qy * qy + qz * qz;

  int slot = lane & (SL - 1);
  u64 val = ~0ull;  // this lane's slot of the sorted top-SL list
  u64 tau = ~0ull;  // replicated exact kth-best (slot SL-1's value)

  for (int t0 = 0; t0 < Nref; t0 += TILE) {
    int cnt = min(TILE, Nref - t0);
    __syncthreads();
    for (int j = threadIdx.x; j < cnt; j += 64 * QPB) {
      float rx = pb[(t0 + j) * 3 + 0];
      float ry = pb[(t0 + j) * 3 + 1];
      float rz = pb[(t0 + j) * 3 + 2];
      sRef[j] = make_float4(rx, ry, rz, rx * rx + ry * ry + rz * rz);
    }
    __syncthreads();
#pragma unroll
    for (int c = 0; c < TILE / 64; ++c) {
      int j = lane + 64 * c;
      u64 ck = ~0ull;  // never passes the strict < test
      if (j < cnt) {
        float4 r = sRef[j];
        float d2 = qq + r.w - 2.0f * (qx * r.x + qy * r.y + qz * r.z);
        ck = ((u64)fbias(d2) << 32) | (u32)(t0 + j);
      }
      u64 mask = __ballot(ck < tau);
      while (mask) {  // wave-uniform
        int src = __ffsll(mask) - 1;
        mask &= mask - 1;
        u64 cks = __shfl((unsigned long long)ck, src, 64);
        if (cks < tau) {  // uniform (tau identical on all lanes)
          u64 prev = __shfl_up((unsigned long long)val, 1, 64);
          if (slot == 0) prev = 0ull;
          val = (val <= cks) ? val : ((prev <= cks) ? cks : prev);
          tau = __shfl((unsigned long long)val, SL - 1, 64);
        }
      }
    }
  }

  if (lane < KOUT) {  // slots 0..KOUT-1 of group 0, sorted ascending
    size_t base = ((size_t)b * Mq + q) * KOUT;
    oidx[base + lane] = (int)(u32)val;
    od2[base + lane] = fmaxf(funbias((u32)(val >> 32)), 0.0f);
  }
}

// -------------------------------------------------- weight packing (bf16) --
// Pack W (KDIM x N fp32, row-major) into MFMA B-fragment tile order for
// mfma_f32_16x16x32_bf16: tile (kt,nt) holds B[k=kt*32+(lane>>4)*8+j]
// [n=nt*16+(lane&15)], 8 bf16 contiguous per lane => one dwordx4 load.
// Rows k >= KDIM are zero (K-padding contributes 0 to the accumulator).
template<int KDIM, int N>
__global__ __launch_bounds__(64) void pack_w_kernel(
    const float* __restrict__ W, short* __restrict__ outp) {
  const int NT = N / 16;
  int tile = blockIdx.x;
  int kt = tile / NT, nt = tile % NT;
  int lane = threadIdx.x;
  int n = nt * 16 + (lane & 15);
  int k0 = kt * 32 + (lane >> 4) * 8;
  bf8_t v;
#pragma unroll
  for (int j = 0; j < 8; ++j) {
    int k = k0 + j;
    v[j] = (k < KDIM) ? f2bf(W[(size_t)k * N + n]) : (short)0;
  }
  *(bf8_t*)(outp + ((size_t)tile * 64 + lane) * 8) = v;
}

// ----------------------------------------------------- down MLP (MFMA) -----
// One wave per (center, nt-slice); WPB waves/block share one center's LDS.
// M=16 = the K neighbors. feat staged in LDS as bf16 in row-major order so
// A-frags (A[m=lane&15][k=quad*8+j], m89/m91 layout) are single ds_read_b128;
// h1 likewise. B-tiles come from the packed weights (1 dwordx4/lane/tile).
// Bias folds into acc init; k-max epilogue = 3 fmax + 2 shfl_xor (bias is
// constant over k so it commutes with the max).
template<int FEAT, int CIN, int CHID, int FPAD, int WPB>
__global__ __launch_bounds__(64 * WPB) void down_mfma_kernel(
    const float* __restrict__ pos, const float* __restrict__ xin,
    const int* __restrict__ idx,
    const short* __restrict__ W1p, const float* __restrict__ b1,
    const short* __restrict__ W2p, const float* __restrict__ b2,
    float* __restrict__ out, int n, int nprev) {
  const int KT1 = FPAD / 32, NT1 = CHID / 16;
  const int KT2 = CHID / 32, NT2 = CHID / 16;
  __shared__ short sFeat[16][FPAD];
  __shared__ short sH1[16][CHID];
  __shared__ int sIdx[16];
  __shared__ float sCtr[3];
  int b = blockIdx.y, q = blockIdx.x;
  int lane = threadIdx.x & 63, wv = threadIdx.x >> 6;
  const float* pb = pos + (size_t)b * NFULL * 3;
  const float* xb = xin + (size_t)b * nprev * CIN;
  if (threadIdx.x < 16) sIdx[threadIdx.x] = idx[((size_t)b * n + q) * 16 + threadIdx.x];
  if (threadIdx.x < 3) sCtr[threadIdx.x] = pb[q * 3 + threadIdx.x];
  __syncthreads();
  for (int e = threadIdx.x; e < 16 * FPAD; e += 64 * WPB) {
    int k = e / FPAD, c = e % FPAD;
    float v = 0.f;
    if (c < 3) v = pb[sIdx[k] * 3 + c] - sCtr[c];
    else if (c < FEAT) v = xb[(size_t)sIdx[k] * CIN + (c - 3)];
    sFeat[k][c] = f2bf(v);
  }
  __syncthreads();

  int col = lane & 15, quad = lane >> 4;
  // ---- layer 1: h1 = relu(feat @ W1 + b1) ----
  bf8_t afr[KT1];
#pragma unroll
  for (int kt = 0; kt < KT1; ++kt)
    afr[kt] = *(const bf8_t*)&sFeat[col][kt * 32 + quad * 8];
  const bf8_t* W1t = (const bf8_t*)W1p;
  for (int nt = 2 * wv; nt < NT1; nt += 2 * WPB) {
    float bb0 = b1[nt * 16 + col], bb1 = b1[nt * 16 + 16 + col];
    f4_t acc0 = {bb0, bb0, bb0, bb0}, acc1 = {bb1, bb1, bb1, bb1};
#pragma unroll
    for (int kt = 0; kt < KT1; ++kt) {
      bf8_t bf0 = W1t[(kt * NT1 + nt) * 64 + lane];
      bf8_t bf1 = W1t[(kt * NT1 + nt + 1) * 64 + lane];
      acc0 = __builtin_amdgcn_mfma_f32_16x16x32_bf16(afr[kt], bf0, acc0, 0, 0, 0);
      acc1 = __builtin_amdgcn_mfma_f32_16x16x32_bf16(afr[kt], bf1, acc1, 0, 0, 0);
    }
#pragma unroll
    for (int r = 0; r < 4; ++r) {  // D: col=lane&15, row=quad*4+r
      sH1[quad * 4 + r][nt * 16 + col] = f2bf(fmaxf(acc0[r], 0.f));
      sH1[quad * 4 + r][nt * 16 + 16 + col] = f2bf(fmaxf(acc1[r], 0.f));
    }
  }
  __syncthreads();

  // ---- layer 2: out = max_k (h1 @ W2 + b2) ----
  bf8_t afr2[KT2];
#pragma unroll
  for (int kt = 0; kt < KT2; ++kt)
    afr2[kt] = *(const bf8_t*)&sH1[col][kt * 32 + quad * 8];
  const bf8_t* W2t = (const bf8_t*)W2p;
  float* ob = out + ((size_t)b * n + q) * CHID;
  for (int nt = 2 * wv; nt < NT2; nt += 2 * WPB) {
    float bb0 = b2[nt * 16 + col], bb1 = b2[nt * 16 + 16 + col];
    f4_t acc0 = {bb0, bb0, bb0, bb0}, acc1 = {bb1, bb1, bb1, bb1};
#pragma unroll
    for (int kt = 0; kt < KT2; ++kt) {
      bf8_t bf0 = W2t[(kt * NT2 + nt) * 64 + lane];
      bf8_t bf1 = W2t[(kt * NT2 + nt + 1) * 64 + lane];
      acc0 = __builtin_amdgcn_mfma_f32_16x16x32_bf16(afr2[kt], bf0, acc0, 0, 0, 0);
      acc1 = __builtin_amdgcn_mfma_f32_16x16x32_bf16(afr2[kt], bf1, acc1, 0, 0, 0);
    }
    float m0 = fmaxf(fmaxf(acc0[0], acc0[1]), fmaxf(acc0[2], acc0[3]));
    float m1 = fmaxf(fmaxf(acc1[0], acc1[1]), fmaxf(acc1[2], acc1[3]));
    m0 = fmaxf(m0, __shfl_xor(m0, 16, 64));
    m0 = fmaxf(m0, __shfl_xor(m0, 32, 64));
    m1 = fmaxf(m1, __shfl_xor(m1, 16, 64));
    m1 = fmaxf(m1, __shfl_xor(m1, 32, 64));
    if (lane < 16) {
      ob[nt * 16 + lane] = m0;
      ob[nt * 16 + 16 + lane] = m1;
    }
  }
}

// --------------------------------------------------------------- up MLP ----
template<int CIN, int CPRV, int COUT, int TP>
__global__ __launch_bounds__(COUT) void up_kernel(
    const float* __restrict__ xc, int ncoarse,
    const int* __restrict__ idx3, const float* __restrict__ d23,
    const float* __restrict__ prv, const float* __restrict__ W,
    const float* __restrict__ bvec, float* __restrict__ out, int m) {
  const int CTOT = CIN + CPRV;
  __shared__ float sCat[TP][CTOT];
  __shared__ float sWt[TP][3];
  __shared__ int   sIt[TP][3];
  int b = blockIdx.y, q0 = blockIdx.x * TP, t = threadIdx.x;
  if (t < TP) {
    size_t base = ((size_t)b * m + q0 + t) * 3;
    float d0 = d23[base + 0], d1 = d23[base + 1], d2v = d23[base + 2];
    float w0 = 1.f / (d0 + 1e-8f), w1 = 1.f / (d1 + 1e-8f), w2 = 1.f / (d2v + 1e-8f);
    float s = w0 + w1 + w2;
    sWt[t][0] = w0 / s; sWt[t][1] = w1 / s; sWt[t][2] = w2 / s;
    sIt[t][0] = idx3[base + 0]; sIt[t][1] = idx3[base + 1]; sIt[t][2] = idx3[base + 2];
  }
  __syncthreads();
  const float* xb = xc + (size_t)b * ncoarse * CIN;
  const float* pvb = prv + ((size_t)b * m + q0) * CPRV;
  for (int e = t; e < TP * CIN; e += COUT) {
    int p = e / CIN, c = e % CIN;
    sCat[p][c] = sWt[p][0] * xb[(size_t)sIt[p][0] * CIN + c]
               + sWt[p][1] * xb[(size_t)sIt[p][1] * CIN + c]
               + sWt[p][2] * xb[(size_t)sIt[p][2] * CIN + c];
  }
  for (int e = t; e < TP * CPRV; e += COUT) {
    int p = e / CPRV, c = e % CPRV;
    sCat[p][CIN + c] = pvb[(size_t)p * CPRV + c];
  }
  __syncthreads();
  float acc[TP];
  float bb = bvec[t];
#pragma unroll
  for (int p = 0; p < TP; ++p) acc[p] = bb;
  for (int c4 = 0; c4 < CTOT / 4; ++c4) {
    int c = 4 * c4;
    float w0 = W[(c + 0) * COUT + t];
    float w1 = W[(c + 1) * COUT + t];
    float w2 = W[(c + 2) * COUT + t];
    float w3 = W[(c + 3) * COUT + t];
#pragma unroll
    for (int p = 0; p < TP; ++p) {
      float4 v = *(const float4*)&sCat[p][c];
      acc[p] = fmaf(v.x, w0, acc[p]);
      acc[p] = fmaf(v.y, w1, acc[p]);
      acc[p] = fmaf(v.z, w2, acc[p]);
      acc[p] = fmaf(v.w, w3, acc[p]);
    }
  }
#pragma unroll
  for (int p = 0; p < TP; ++p)
    out[((size_t)b * m + q0 + p) * COUT + t] = fmaxf(acc[p], 0.f);
}

// ---------------------------------------------- fused up2 + final MLP ------
template<int TP>
__global__ __launch_bounds__(128) void up2_final_kernel(
    const float* __restrict__ xc,
    const int* __restrict__ idx3, const float* __restrict__ d23,
    const float* __restrict__ x0, const float* __restrict__ pos0,
    const float* __restrict__ u2W, const float* __restrict__ u2b,
    const float* __restrict__ fW1, const float* __restrict__ fb1,
    const float* __restrict__ fW2, const float* __restrict__ fb2,
    float* __restrict__ out) {
  __shared__ float sA[TP][136];
  __shared__ float sB[TP][128];
  __shared__ float sWt[TP][3];
  __shared__ int   sIt[TP][3];
  int b = blockIdx.y, q0 = blockIdx.x * TP, t = threadIdx.x;
  if (t < TP) {
    size_t base = ((size_t)b * NFULL + q0 + t) * 3;
    float d0 = d23[base + 0], d1 = d23[base + 1], d2v = d23[base + 2];
    float w0 = 1.f / (d0 + 1e-8f), w1 = 1.f / (d1 + 1e-8f), w2 = 1.f / (d2v + 1e-8f);
    float s = w0 + w1 + w2;
    sWt[t][0] = w0 / s; sWt[t][1] = w1 / s; sWt[t][2] = w2 / s;
    sIt[t][0] = idx3[base + 0]; sIt[t][1] = idx3[base + 1]; sIt[t][2] = idx3[base + 2];
  }
  __syncthreads();
  const float* xb = xc + (size_t)b * 2048 * 128;
#pragma unroll
  for (int p = 0; p < TP; ++p) {
    sA[p][t] = sWt[p][0] * xb[(size_t)sIt[p][0] * 128 + t]
             + sWt[p][1] * xb[(size_t)sIt[p][1] * 128 + t]
             + sWt[p][2] * xb[(size_t)sIt[p][2] * 128 + t];
  }
  if (t < TP * 6) {
    int p = t / 6, c = t % 6;
    const float* src = (c < 3) ? x0 : pos0;
    int cc = (c < 3) ? c : c - 3;
    sA[p][128 + c] = src[((size_t)b * NFULL + q0 + p) * 3 + cc];
  }
  __syncthreads();
  float acc[TP];
  float bb = u2b[t];
#pragma unroll
  for (int p = 0; p < TP; ++p) acc[p] = bb;
  for (int c4 = 0; c4 < 33; ++c4) {
    int c = 4 * c4;
    float w0 = u2W[(c + 0) * 128 + t];
    float w1 = u2W[(c + 1) * 128 + t];
    float w2 = u2W[(c + 2) * 128 + t];
    float w3 = u2W[(c + 3) * 128 + t];
#pragma unroll
    for (int p = 0; p < TP; ++p) {
      float4 v = *(const float4*)&sA[p][c];
      acc[p] = fmaf(v.x, w0, acc[p]);
      acc[p] = fmaf(v.y, w1, acc[p]);
      acc[p] = fmaf(v.z, w2, acc[p]);
      acc[p] = fmaf(v.w, w3, acc[p]);
    }
  }
  {
    float wa = u2W[132 * 128 + t], wbv = u2W[133 * 128 + t];
#pragma unroll
    for (int p = 0; p < TP; ++p) {
      acc[p] = fmaf(sA[p][132], wa, acc[p]);
      acc[p] = fmaf(sA[p][133], wbv, acc[p]);
      sB[p][t] = fmaxf(acc[p], 0.f);
    }
  }
  __syncthreads();
  float acc2[TP];
  float bb2 = fb1[t];
#pragma unroll
  for (int p = 0; p < TP; ++p) acc2[p] = bb2;
  for (int c4 = 0; c4 < 32; ++c4) {
    int c = 4 * c4;
    float w0 = fW1[(c + 0) * 128 + t];
    float w1 = fW1[(c + 1) * 128 + t];
    float w2 = fW1[(c + 2) * 128 + t];
    float w3 = fW1[(c + 3) * 128 + t];
#pragma unroll
    for (int p = 0; p < TP; ++p) {
      float4 v = *(const float4*)&sB[p][c];
      acc2[p] = fmaf(v.x, w0, acc2[p]);
      acc2[p] = fmaf(v.y, w1, acc2[p]);
      acc2[p] = fmaf(v.z, w2, acc2[p]);
      acc2[p] = fmaf(v.w, w3, acc2[p]);
    }
  }
#pragma unroll
  for (int p = 0; p < TP; ++p) sA[p][t] = fmaxf(acc2[p], 0.f);
  __syncthreads();
  float acc3[TP];
  float bb3 = fb2[t];
#pragma unroll
  for (int p = 0; p < TP; ++p) acc3[p] = bb3;
  for (int c4 = 0; c4 < 32; ++c4) {
    int c = 4 * c4;
    float w0 = fW2[(c + 0) * 128 + t];
    float w1 = fW2[(c + 1) * 128 + t];
    float w2 = fW2[(c + 2) * 128 + t];
    float w3 = fW2[(c + 3) * 128 + t];
#pragma unroll
    for (int p = 0; p < TP; ++p) {
      float4 v = *(const float4*)&sA[p][c];
      acc3[p] = fmaf(v.x, w0, acc3[p]);
      acc3[p] = fmaf(v.y, w1, acc3[p]);
      acc3[p] = fmaf(v.z, w2, acc3[p]);
      acc3[p] = fmaf(v.w, w3, acc3[p]);
    }
  }
#pragma unroll
  for (int p = 0; p < TP; ++p)
    out[((size_t)b * NFULL + q0 + p) * 128 + t] = acc3[p];
}

__global__ void copy_kernel(const float* __restrict__ src, float* __restrict__ dst, int n) {
  int i = blockIdx.x * blockDim.x + threadIdx.x;
  if (i < n) dst[i] = src[i];
}

// ------------------------------------------------------------------ launch -
extern "C" void kernel_launch(void* const* d_in, const int* in_sizes, int n_in,
                              void* d_out, int out_size, void* d_ws, size_t ws_size,
                              hipStream_t stream) {
  const float* x    = (const float*)d_in[0];
  const float* pos  = (const float*)d_in[1];
  const float* d0W1 = (const float*)d_in[2];
  const float* d0b1 = (const float*)d_in[3];
  const float* d0W2 = (const float*)d_in[4];
  const float* d0b2 = (const float*)d_in[5];
  const float* d1W1 = (const float*)d_in[6];
  const float* d1b1 = (const float*)d_in[7];
  const float* d1W2 = (const float*)d_in[8];
  const float* d1b2 = (const float*)d_in[9];
  const float* d2W1 = (const float*)d_in[10];
  const float* d2b1 = (const float*)d_in[11];
  const float* d2W2 = (const float*)d_in[12];
  const float* d2b2 = (const float*)d_in[13];
  const float* u0W  = (const float*)d_in[14];
  const float* u0b  = (const float*)d_in[15];
  const float* u1W  = (const float*)d_in[16];
  const float* u1b  = (const float*)d_in[17];
  const float* u2W  = (const float*)d_in[18];
  const float* u2b  = (const float*)d_in[19];
  const float* fW1  = (const float*)d_in[20];
  const float* fb1  = (const float*)d_in[21];
  const float* fW2  = (const float*)d_in[22];
  const float* fb2  = (const float*)d_in[23];

  char* ws = (char*)d_ws;
  float* x1    = (float*)(ws + 0);
  float* x2    = (float*)(ws + 4194304);
  float* x3    = (float*)(ws + 6291456);
  float* up0o  = (float*)(ws + 7340032);
  float* up1o  = (float*)(ws + 9437184);
  int*   idx0  = (int*)  (ws + 13631488);
  int*   idx1  = (int*)  (ws + 14155776);
  int*   idx2  = (int*)  (ws + 14286848);
  float* d2s   = (float*)(ws + 14319616);
  int*   idxu0 = (int*)  (ws + 14843904);
  float* d2u0  = (float*)(ws + 14868480);
  int*   idxu1 = (int*)  (ws + 14893056);
  float* d2u1  = (float*)(ws + 14991360);
  int*   idxu2 = (int*)  (ws + 15089664);
  float* d2u2  = (float*)(ws + 15482880);
  short* d1W1p = (short*)(ws + 15876096);  // 160*256*2  = 81920
  short* d1W2p = (short*)(ws + 15958016);  // 256*256*2  = 131072
  short* d2W1p = (short*)(ws + 16089088);  // 288*512*2  = 294912
  short* d2W2p = (short*)(ws + 16384000);  // 512*512*2  = 524288
  short* d0W1p = (short*)(ws + 16908288);  // 32*128*2   = 8192
  short* d0W2p = (short*)(ws + 16916480);  // 128*128*2  = 32768 (end 16949248)

  float* out = (float*)d_out;

  // ---- weight packing (bf16 MFMA-B layout); stream-ordered before use ----
  pack_w_kernel<6, 128><<<dim3(1 * 8), 64, 0, stream>>>(d0W1, d0W1p);
  pack_w_kernel<128, 128><<<dim3(4 * 8), 64, 0, stream>>>(d0W2, d0W2p);
  pack_w_kernel<131, 256><<<dim3(5 * 16), 64, 0, stream>>>(d1W1, d1W1p);
  pack_w_kernel<256, 256><<<dim3(8 * 16), 64, 0, stream>>>(d1W2, d1W2p);
  pack_w_kernel<259, 512><<<dim3(9 * 32), 64, 0, stream>>>(d2W1, d2W1p);
  pack_w_kernel<512, 512><<<dim3(16 * 32), 64, 0, stream>>>(d2W2, d2W2p);

  // ---- down path ----
  knn_kernel<16, 16, 4><<<dim3(512, BATCH), 256, 0, stream>>>(pos, 8192, 2048, idx0, d2s);
  down_mfma_kernel<6, 3, 128, 32, 1><<<dim3(2048, BATCH), 64, 0, stream>>>(
      pos, x, idx0, d0W1p, d0b1, d0W2p, d0b2, x1, 2048, 8192);
  knn_kernel<16, 16, 4><<<dim3(128, BATCH), 256, 0, stream>>>(pos, 2048, 512, idx1, d2s);
  down_mfma_kernel<131, 128, 256, 160, 1><<<dim3(512, BATCH), 64, 0, stream>>>(
      pos, x1, idx1, d1W1p, d1b1, d1W2p, d1b2, x2, 512, 2048);
  knn_kernel<16, 16, 4><<<dim3(32, BATCH), 256, 0, stream>>>(pos, 512, 128, idx2, d2s);
  down_mfma_kernel<259, 256, 512, 288, 2><<<dim3(128, BATCH), 128, 0, stream>>>(
      pos, x2, idx2, d2W1p, d2b1, d2W2p, d2b2, x3, 128, 512);

  // ---- up path (point-tiled) ----
  knn_kernel<4, 3, 4><<<dim3(128, BATCH), 256, 0, stream>>>(pos, 128, 512, idxu0, d2u0);
  up_kernel<512, 256, 256, 8><<<dim3(64, BATCH), 256, 0, stream>>>(
      x3, 128, idxu0, d2u0, x2, u0W, u0b, up0o, 512);
  knn_kernel<4, 3, 4><<<dim3(512, BATCH), 256, 0, stream>>>(pos, 512, 2048, idxu1, d2u1);
  up_kernel<256, 128, 128, 16><<<dim3(128, BATCH), 128, 0, stream>>>(
      up0o, 512, idxu1, d2u1, x1, u1W, u1b, up1o, 2048);
  knn_kernel<4, 3, 4><<<dim3(2048, BATCH), 256, 0, stream>>>(pos, 2048, 8192, idxu2, d2u2);
  up2_final_kernel<16><<<dim3(512, BATCH), 128, 0, stream>>>(
      up1o, idxu2, d2u2, x, pos, u2W, u2b, fW1, fb1, fW2, fb2, out);

  // ---- second tuple element: pos passthrough ----
  copy_kernel<<<dim3(384), 256, 0, stream>>>(pos, out + (size_t)BATCH * NFULL * 128,
                                             BATCH * NFULL * 3);
}

// Round 8
// 673.492 us; speedup vs baseline: 1.8217x; 1.0272x over previous
//
#include <hip/hip_runtime.h>

#define NFULL 8192
#define BATCH 4

typedef unsigned long long u64;
typedef unsigned int u32;
typedef __attribute__((ext_vector_type(8))) short bf8_t;   // 8 bf16 (4 VGPRs)
typedef __attribute__((ext_vector_type(4))) float f4_t;    // MFMA C/D

// Total-order bias: monotone map fp32 -> u32 (handles negatives correctly).
__device__ __forceinline__ u32 fbias(float f) {
  u32 u = __float_as_uint(f);
  return (u & 0x80000000u) ? ~u : (u | 0x80000000u);
}
__device__ __forceinline__ float funbias(u32 b) {
  u32 u = (b & 0x80000000u) ? (b & 0x7fffffffu) : ~b;
  return __uint_as_float(u);
}
// fp32 -> bf16 round-to-nearest-even
__device__ __forceinline__ short f2bf(float f) {
  u32 u = __float_as_uint(f);
  u32 r = u + 0x7FFFu + ((u >> 16) & 1u);
  return (short)(r >> 16);
}

// ---------------------------------------------------------------- kNN ------
// R8: distributed top-K v2 — barrier-free, LDS-free.
// Wave-per-query; sorted top-SL list lives one entry per lane
// (slot = lane & (SL-1), identical copies per SL-lane group). u64 keys
// (biased-d2 << 32 | idx) == jax.lax.top_k order incl. stable tie-break.
// Refs are read directly from global (pos is L2-resident, 96 KB/batch) —
// no LDS staging, no __syncthreads, waves fully independent.
// Insert is UNCONDITIONAL (inserting c >= kth is a structural no-op), so the
// serial chain per insert is just shfl(ck)+shfl_up(val)+6 VALU; tau is
// refreshed once per round (lazy/stale tau => only harmless no-op inserts).
template<int SL, int KOUT, int QPB>
__global__ __launch_bounds__(64 * QPB) void knn_kernel(
    const float* __restrict__ pos, int Nref, int Mq,
    int* __restrict__ oidx, float* __restrict__ od2) {
  int b = blockIdx.y;
  int w = threadIdx.x >> 6, lane = threadIdx.x & 63;
  int q = blockIdx.x * QPB + w;  // all Mq are multiples of QPB
  const float* pb = pos + (size_t)b * NFULL * 3;
  float qx = pb[q * 3 + 0], qy = pb[q * 3 + 1], qz = pb[q * 3 + 2];
  float qq = qx * qx + qy * qy + qz * qz;

  int slot = lane & (SL - 1);
  u64 val = ~0ull;  // this lane's slot of the sorted top-SL list
  u64 tau = ~0ull;  // replicated kth-best, refreshed once per insert-round

  for (int t0 = 0; t0 < Nref; t0 += 64) {  // all Nref are multiples of 64
    int j = t0 + lane;
    float rx = pb[j * 3 + 0];
    float ry = pb[j * 3 + 1];
    float rz = pb[j * 3 + 2];
    float rr = rx * rx + ry * ry + rz * rz;
    float d2 = qq + rr - 2.0f * (qx * rx + qy * ry + qz * rz);
    u64 ck = ((u64)fbias(d2) << 32) | (u32)j;
    u64 mask = __ballot(ck < tau);
    if (mask) {  // wave-uniform
      while (mask) {
        int src = __ffsll(mask) - 1;
        mask &= mask - 1;
        u64 c = __shfl((unsigned long long)ck, src, 64);
        u64 prev = __shfl_up((unsigned long long)val, 1, 64);
        if (slot == 0) prev = 0ull;
        // sorted-insert c (no-op if c >= list max):
        val = (val <= c) ? val : ((prev <= c) ? c : prev);
      }
      tau = __shfl((unsigned long long)val, SL - 1, 64);
    }
  }

  if (lane < KOUT) {  // slots 0..KOUT-1 of group 0, sorted ascending
    size_t base = ((size_t)b * Mq + q) * KOUT;
    oidx[base + lane] = (int)(u32)val;
    od2[base + lane] = fmaxf(funbias((u32)(val >> 32)), 0.0f);
  }
}

// -------------------------------------------------- weight packing (bf16) --
// Pack W (KDIM x N fp32, row-major) into MFMA B-fragment tile order for
// mfma_f32_16x16x32_bf16: tile (kt,nt) holds B[k=kt*32+(lane>>4)*8+j]
// [n=nt*16+(lane&15)], 8 bf16 contiguous per lane => one dwordx4 load.
// Rows k >= KDIM are zero (K-padding contributes 0 to the accumulator).
template<int KDIM, int N>
__global__ __launch_bounds__(64) void pack_w_kernel(
    const float* __restrict__ W, short* __restrict__ outp) {
  const int NT = N / 16;
  int tile = blockIdx.x;
  int kt = tile / NT, nt = tile % NT;
  int lane = threadIdx.x;
  int n = nt * 16 + (lane & 15);
  int k0 = kt * 32 + (lane >> 4) * 8;
  bf8_t v;
#pragma unroll
  for (int j = 0; j < 8; ++j) {
    int k = k0 + j;
    v[j] = (k < KDIM) ? f2bf(W[(size_t)k * N + n]) : (short)0;
  }
  *(bf8_t*)(outp + ((size_t)tile * 64 + lane) * 8) = v;
}

// ----------------------------------------------------- down MLP (MFMA) -----
// One wave per (center, nt-slice); WPB waves/block share one center's LDS.
// M=16 = the K neighbors. feat staged in LDS as bf16 in row-major order so
// A-frags (A[m=lane&15][k=quad*8+j], m89/m91 layout) are single ds_read_b128;
// h1 likewise. B-tiles come from the packed weights (1 dwordx4/lane/tile).
// Bias folds into acc init; k-max epilogue = 3 fmax + 2 shfl_xor (bias is
// constant over k so it commutes with the max).
template<int FEAT, int CIN, int CHID, int FPAD, int WPB>
__global__ __launch_bounds__(64 * WPB) void down_mfma_kernel(
    const float* __restrict__ pos, const float* __restrict__ xin,
    const int* __restrict__ idx,
    const short* __restrict__ W1p, const float* __restrict__ b1,
    const short* __restrict__ W2p, const float* __restrict__ b2,
    float* __restrict__ out, int n, int nprev) {
  const int KT1 = FPAD / 32, NT1 = CHID / 16;
  const int KT2 = CHID / 32, NT2 = CHID / 16;
  __shared__ short sFeat[16][FPAD];
  __shared__ short sH1[16][CHID];
  __shared__ int sIdx[16];
  __shared__ float sCtr[3];
  int b = blockIdx.y, q = blockIdx.x;
  int lane = threadIdx.x & 63, wv = threadIdx.x >> 6;
  const float* pb = pos + (size_t)b * NFULL * 3;
  const float* xb = xin + (size_t)b * nprev * CIN;
  if (threadIdx.x < 16) sIdx[threadIdx.x] = idx[((size_t)b * n + q) * 16 + threadIdx.x];
  if (threadIdx.x < 3) sCtr[threadIdx.x] = pb[q * 3 + threadIdx.x];
  __syncthreads();
  for (int e = threadIdx.x; e < 16 * FPAD; e += 64 * WPB) {
    int k = e / FPAD, c = e % FPAD;
    float v = 0.f;
    if (c < 3) v = pb[sIdx[k] * 3 + c] - sCtr[c];
    else if (c < FEAT) v = xb[(size_t)sIdx[k] * CIN + (c - 3)];
    sFeat[k][c] = f2bf(v);
  }
  __syncthreads();

  int col = lane & 15, quad = lane >> 4;
  // ---- layer 1: h1 = relu(feat @ W1 + b1) ----
  bf8_t afr[KT1];
#pragma unroll
  for (int kt = 0; kt < KT1; ++kt)
    afr[kt] = *(const bf8_t*)&sFeat[col][kt * 32 + quad * 8];
  const bf8_t* W1t = (const bf8_t*)W1p;
  for (int nt = 2 * wv; nt < NT1; nt += 2 * WPB) {
    float bb0 = b1[nt * 16 + col], bb1 = b1[nt * 16 + 16 + col];
    f4_t acc0 = {bb0, bb0, bb0, bb0}, acc1 = {bb1, bb1, bb1, bb1};
#pragma unroll
    for (int kt = 0; kt < KT1; ++kt) {
      bf8_t bf0 = W1t[(kt * NT1 + nt) * 64 + lane];
      bf8_t bf1 = W1t[(kt * NT1 + nt + 1) * 64 + lane];
      acc0 = __builtin_amdgcn_mfma_f32_16x16x32_bf16(afr[kt], bf0, acc0, 0, 0, 0);
      acc1 = __builtin_amdgcn_mfma_f32_16x16x32_bf16(afr[kt], bf1, acc1, 0, 0, 0);
    }
#pragma unroll
    for (int r = 0; r < 4; ++r) {  // D: col=lane&15, row=quad*4+r
      sH1[quad * 4 + r][nt * 16 + col] = f2bf(fmaxf(acc0[r], 0.f));
      sH1[quad * 4 + r][nt * 16 + 16 + col] = f2bf(fmaxf(acc1[r], 0.f));
    }
  }
  __syncthreads();

  // ---- layer 2: out = max_k (h1 @ W2 + b2) ----
  bf8_t afr2[KT2];
#pragma unroll
  for (int kt = 0; kt < KT2; ++kt)
    afr2[kt] = *(const bf8_t*)&sH1[col][kt * 32 + quad * 8];
  const bf8_t* W2t = (const bf8_t*)W2p;
  float* ob = out + ((size_t)b * n + q) * CHID;
  for (int nt = 2 * wv; nt < NT2; nt += 2 * WPB) {
    float bb0 = b2[nt * 16 + col], bb1 = b2[nt * 16 + 16 + col];
    f4_t acc0 = {bb0, bb0, bb0, bb0}, acc1 = {bb1, bb1, bb1, bb1};
#pragma unroll
    for (int kt = 0; kt < KT2; ++kt) {
      bf8_t bf0 = W2t[(kt * NT2 + nt) * 64 + lane];
      bf8_t bf1 = W2t[(kt * NT2 + nt + 1) * 64 + lane];
      acc0 = __builtin_amdgcn_mfma_f32_16x16x32_bf16(afr2[kt], bf0, acc0, 0, 0, 0);
      acc1 = __builtin_amdgcn_mfma_f32_16x16x32_bf16(afr2[kt], bf1, acc1, 0, 0, 0);
    }
    float m0 = fmaxf(fmaxf(acc0[0], acc0[1]), fmaxf(acc0[2], acc0[3]));
    float m1 = fmaxf(fmaxf(acc1[0], acc1[1]), fmaxf(acc1[2], acc1[3]));
    m0 = fmaxf(m0, __shfl_xor(m0, 16, 64));
    m0 = fmaxf(m0, __shfl_xor(m0, 32, 64));
    m1 = fmaxf(m1, __shfl_xor(m1, 16, 64));
    m1 = fmaxf(m1, __shfl_xor(m1, 32, 64));
    if (lane < 16) {
      ob[nt * 16 + lane] = m0;
      ob[nt * 16 + 16 + lane] = m1;
    }
  }
}

// --------------------------------------------------------------- up MLP ----
template<int CIN, int CPRV, int COUT, int TP>
__global__ __launch_bounds__(COUT) void up_kernel(
    const float* __restrict__ xc, int ncoarse,
    const int* __restrict__ idx3, const float* __restrict__ d23,
    const float* __restrict__ prv, const float* __restrict__ W,
    const float* __restrict__ bvec, float* __restrict__ out, int m) {
  const int CTOT = CIN + CPRV;
  __shared__ float sCat[TP][CTOT];
  __shared__ float sWt[TP][3];
  __shared__ int   sIt[TP][3];
  int b = blockIdx.y, q0 = blockIdx.x * TP, t = threadIdx.x;
  if (t < TP) {
    size_t base = ((size_t)b * m + q0 + t) * 3;
    float d0 = d23[base + 0], d1 = d23[base + 1], d2v = d23[base + 2];
    float w0 = 1.f / (d0 + 1e-8f), w1 = 1.f / (d1 + 1e-8f), w2 = 1.f / (d2v + 1e-8f);
    float s = w0 + w1 + w2;
    sWt[t][0] = w0 / s; sWt[t][1] = w1 / s; sWt[t][2] = w2 / s;
    sIt[t][0] = idx3[base + 0]; sIt[t][1] = idx3[base + 1]; sIt[t][2] = idx3[base + 2];
  }
  __syncthreads();
  const float* xb = xc + (size_t)b * ncoarse * CIN;
  const float* pvb = prv + ((size_t)b * m + q0) * CPRV;
  for (int e = t; e < TP * CIN; e += COUT) {
    int p = e / CIN, c = e % CIN;
    sCat[p][c] = sWt[p][0] * xb[(size_t)sIt[p][0] * CIN + c]
               + sWt[p][1] * xb[(size_t)sIt[p][1] * CIN + c]
               + sWt[p][2] * xb[(size_t)sIt[p][2] * CIN + c];
  }
  for (int e = t; e < TP * CPRV; e += COUT) {
    int p = e / CPRV, c = e % CPRV;
    sCat[p][CIN + c] = pvb[(size_t)p * CPRV + c];
  }
  __syncthreads();
  float acc[TP];
  float bb = bvec[t];
#pragma unroll
  for (int p = 0; p < TP; ++p) acc[p] = bb;
  for (int c4 = 0; c4 < CTOT / 4; ++c4) {
    int c = 4 * c4;
    float w0 = W[(c + 0) * COUT + t];
    float w1 = W[(c + 1) * COUT + t];
    float w2 = W[(c + 2) * COUT + t];
    float w3 = W[(c + 3) * COUT + t];
#pragma unroll
    for (int p = 0; p < TP; ++p) {
      float4 v = *(const float4*)&sCat[p][c];
      acc[p] = fmaf(v.x, w0, acc[p]);
      acc[p] = fmaf(v.y, w1, acc[p]);
      acc[p] = fmaf(v.z, w2, acc[p]);
      acc[p] = fmaf(v.w, w3, acc[p]);
    }
  }
#pragma unroll
  for (int p = 0; p < TP; ++p)
    out[((size_t)b * m + q0 + p) * COUT + t] = fmaxf(acc[p], 0.f);
}

// ---------------------------------------------- fused up2 + final MLP ------
template<int TP>
__global__ __launch_bounds__(128) void up2_final_kernel(
    const float* __restrict__ xc,
    const int* __restrict__ idx3, const float* __restrict__ d23,
    const float* __restrict__ x0, const float* __restrict__ pos0,
    const float* __restrict__ u2W, const float* __restrict__ u2b,
    const float* __restrict__ fW1, const float* __restrict__ fb1,
    const float* __restrict__ fW2, const float* __restrict__ fb2,
    float* __restrict__ out) {
  __shared__ float sA[TP][136];
  __shared__ float sB[TP][128];
  __shared__ float sWt[TP][3];
  __shared__ int   sIt[TP][3];
  int b = blockIdx.y, q0 = blockIdx.x * TP, t = threadIdx.x;
  if (t < TP) {
    size_t base = ((size_t)b * NFULL + q0 + t) * 3;
    float d0 = d23[base + 0], d1 = d23[base + 1], d2v = d23[base + 2];
    float w0 = 1.f / (d0 + 1e-8f), w1 = 1.f / (d1 + 1e-8f), w2 = 1.f / (d2v + 1e-8f);
    float s = w0 + w1 + w2;
    sWt[t][0] = w0 / s; sWt[t][1] = w1 / s; sWt[t][2] = w2 / s;
    sIt[t][0] = idx3[base + 0]; sIt[t][1] = idx3[base + 1]; sIt[t][2] = idx3[base + 2];
  }
  __syncthreads();
  const float* xb = xc + (size_t)b * 2048 * 128;
#pragma unroll
  for (int p = 0; p < TP; ++p) {
    sA[p][t] = sWt[p][0] * xb[(size_t)sIt[p][0] * 128 + t]
             + sWt[p][1] * xb[(size_t)sIt[p][1] * 128 + t]
             + sWt[p][2] * xb[(size_t)sIt[p][2] * 128 + t];
  }
  if (t < TP * 6) {
    int p = t / 6, c = t % 6;
    const float* src = (c < 3) ? x0 : pos0;
    int cc = (c < 3) ? c : c - 3;
    sA[p][128 + c] = src[((size_t)b * NFULL + q0 + p) * 3 + cc];
  }
  __syncthreads();
  float acc[TP];
  float bb = u2b[t];
#pragma unroll
  for (int p = 0; p < TP; ++p) acc[p] = bb;
  for (int c4 = 0; c4 < 33; ++c4) {
    int c = 4 * c4;
    float w0 = u2W[(c + 0) * 128 + t];
    float w1 = u2W[(c + 1) * 128 + t];
    float w2 = u2W[(c + 2) * 128 + t];
    float w3 = u2W[(c + 3) * 128 + t];
#pragma unroll
    for (int p = 0; p < TP; ++p) {
      float4 v = *(const float4*)&sA[p][c];
      acc[p] = fmaf(v.x, w0, acc[p]);
      acc[p] = fmaf(v.y, w1, acc[p]);
      acc[p] = fmaf(v.z, w2, acc[p]);
      acc[p] = fmaf(v.w, w3, acc[p]);
    }
  }
  {
    float wa = u2W[132 * 128 + t], wbv = u2W[133 * 128 + t];
#pragma unroll
    for (int p = 0; p < TP; ++p) {
      acc[p] = fmaf(sA[p][132], wa, acc[p]);
      acc[p] = fmaf(sA[p][133], wbv, acc[p]);
      sB[p][t] = fmaxf(acc[p], 0.f);
    }
  }
  __syncthreads();
  float acc2[TP];
  float bb2 = fb1[t];
#pragma unroll
  for (int p = 0; p < TP; ++p) acc2[p] = bb2;
  for (int c4 = 0; c4 < 32; ++c4) {
    int c = 4 * c4;
    float w0 = fW1[(c + 0) * 128 + t];
    float w1 = fW1[(c + 1) * 128 + t];
    float w2 = fW1[(c + 2) * 128 + t];
    float w3 = fW1[(c + 3) * 128 + t];
#pragma unroll
    for (int p = 0; p < TP; ++p) {
      float4 v = *(const float4*)&sB[p][c];
      acc2[p] = fmaf(v.x, w0, acc2[p]);
      acc2[p] = fmaf(v.y, w1, acc2[p]);
      acc2[p] = fmaf(v.z, w2, acc2[p]);
      acc2[p] = fmaf(v.w, w3, acc2[p]);
    }
  }
#pragma unroll
  for (int p = 0; p < TP; ++p) sA[p][t] = fmaxf(acc2[p], 0.f);
  __syncthreads();
  float acc3[TP];
  float bb3 = fb2[t];
#pragma unroll
  for (int p = 0; p < TP; ++p) acc3[p] = bb3;
  for (int c4 = 0; c4 < 32; ++c4) {
    int c = 4 * c4;
    float w0 = fW2[(c + 0) * 128 + t];
    float w1 = fW2[(c + 1) * 128 + t];
    float w2 = fW2[(c + 2) * 128 + t];
    float w3 = fW2[(c + 3) * 128 + t];
#pragma unroll
    for (int p = 0; p < TP; ++p) {
      float4 v = *(const float4*)&sA[p][c];
      acc3[p] = fmaf(v.x, w0, acc3[p]);
      acc3[p] = fmaf(v.y, w1, acc3[p]);
      acc3[p] = fmaf(v.z, w2, acc3[p]);
      acc3[p] = fmaf(v.w, w3, acc3[p]);
    }
  }
#pragma unroll
  for (int p = 0; p < TP; ++p)
    out[((size_t)b * NFULL + q0 + p) * 128 + t] = acc3[p];
}

__global__ void copy_kernel(const float* __restrict__ src, float* __restrict__ dst, int n) {
  int i = blockIdx.x * blockDim.x + threadIdx.x;
  if (i < n) dst[i] = src[i];
}

// ------------------------------------------------------------------ launch -
extern "C" void kernel_launch(void* const* d_in, const int* in_sizes, int n_in,
                              void* d_out, int out_size, void* d_ws, size_t ws_size,
                              hipStream_t stream) {
  const float* x    = (const float*)d_in[0];
  const float* pos  = (const float*)d_in[1];
  const float* d0W1 = (const float*)d_in[2];
  const float* d0b1 = (const float*)d_in[3];
  const float* d0W2 = (const float*)d_in[4];
  const float* d0b2 = (const float*)d_in[5];
  const float* d1W1 = (const float*)d_in[6];
  const float* d1b1 = (const float*)d_in[7];
  const float* d1W2 = (const float*)d_in[8];
  const float* d1b2 = (const float*)d_in[9];
  const float* d2W1 = (const float*)d_in[10];
  const float* d2b1 = (const float*)d_in[11];
  const float* d2W2 = (const float*)d_in[12];
  const float* d2b2 = (const float*)d_in[13];
  const float* u0W  = (const float*)d_in[14];
  const float* u0b  = (const float*)d_in[15];
  const float* u1W  = (const float*)d_in[16];
  const float* u1b  = (const float*)d_in[17];
  const float* u2W  = (const float*)d_in[18];
  const float* u2b  = (const float*)d_in[19];
  const float* fW1  = (const float*)d_in[20];
  const float* fb1  = (const float*)d_in[21];
  const float* fW2  = (const float*)d_in[22];
  const float* fb2  = (const float*)d_in[23];

  char* ws = (char*)d_ws;
  float* x1    = (float*)(ws + 0);
  float* x2    = (float*)(ws + 4194304);
  float* x3    = (float*)(ws + 6291456);
  float* up0o  = (float*)(ws + 7340032);
  float* up1o  = (float*)(ws + 9437184);
  int*   idx0  = (int*)  (ws + 13631488);
  int*   idx1  = (int*)  (ws + 14155776);
  int*   idx2  = (int*)  (ws + 14286848);
  float* d2s   = (float*)(ws + 14319616);
  int*   idxu0 = (int*)  (ws + 14843904);
  float* d2u0  = (float*)(ws + 14868480);
  int*   idxu1 = (int*)  (ws + 14893056);
  float* d2u1  = (float*)(ws + 14991360);
  int*   idxu2 = (int*)  (ws + 15089664);
  float* d2u2  = (float*)(ws + 15482880);
  short* d1W1p = (short*)(ws + 15876096);  // 160*256*2  = 81920
  short* d1W2p = (short*)(ws + 15958016);  // 256*256*2  = 131072
  short* d2W1p = (short*)(ws + 16089088);  // 288*512*2  = 294912
  short* d2W2p = (short*)(ws + 16384000);  // 512*512*2  = 524288
  short* d0W1p = (short*)(ws + 16908288);  // 32*128*2   = 8192
  short* d0W2p = (short*)(ws + 16916480);  // 128*128*2  = 32768 (end 16949248)

  float* out = (float*)d_out;

  // ---- weight packing (bf16 MFMA-B layout); stream-ordered before use ----
  pack_w_kernel<6, 128><<<dim3(1 * 8), 64, 0, stream>>>(d0W1, d0W1p);
  pack_w_kernel<128, 128><<<dim3(4 * 8), 64, 0, stream>>>(d0W2, d0W2p);
  pack_w_kernel<131, 256><<<dim3(5 * 16), 64, 0, stream>>>(d1W1, d1W1p);
  pack_w_kernel<256, 256><<<dim3(8 * 16), 64, 0, stream>>>(d1W2, d1W2p);
  pack_w_kernel<259, 512><<<dim3(9 * 32), 64, 0, stream>>>(d2W1, d2W1p);
  pack_w_kernel<512, 512><<<dim3(16 * 32), 64, 0, stream>>>(d2W2, d2W2p);

  // ---- down path ----
  knn_kernel<16, 16, 4><<<dim3(512, BATCH), 256, 0, stream>>>(pos, 8192, 2048, idx0, d2s);
  down_mfma_kernel<6, 3, 128, 32, 1><<<dim3(2048, BATCH), 64, 0, stream>>>(
      pos, x, idx0, d0W1p, d0b1, d0W2p, d0b2, x1, 2048, 8192);
  knn_kernel<16, 16, 4><<<dim3(128, BATCH), 256, 0, stream>>>(pos, 2048, 512, idx1, d2s);
  down_mfma_kernel<131, 128, 256, 160, 1><<<dim3(512, BATCH), 64, 0, stream>>>(
      pos, x1, idx1, d1W1p, d1b1, d1W2p, d1b2, x2, 512, 2048);
  knn_kernel<16, 16, 4><<<dim3(32, BATCH), 256, 0, stream>>>(pos, 512, 128, idx2, d2s);
  down_mfma_kernel<259, 256, 512, 288, 2><<<dim3(128, BATCH), 128, 0, stream>>>(
      pos, x2, idx2, d2W1p, d2b1, d2W2p, d2b2, x3, 128, 512);

  // ---- up path (point-tiled) ----
  knn_kernel<4, 3, 4><<<dim3(128, BATCH), 256, 0, stream>>>(pos, 128, 512, idxu0, d2u0);
  up_kernel<512, 256, 256, 8><<<dim3(64, BATCH), 256, 0, stream>>>(
      x3, 128, idxu0, d2u0, x2, u0W, u0b, up0o, 512);
  knn_kernel<4, 3, 4><<<dim3(512, BATCH), 256, 0, stream>>>(pos, 512, 2048, idxu1, d2u1);
  up_kernel<256, 128, 128, 16><<<dim3(128, BATCH), 128, 0, stream>>>(
      up0o, 512, idxu1, d2u1, x1, u1W, u1b, up1o, 2048);
  knn_kernel<4, 3, 4><<<dim3(2048, BATCH), 256, 0, stream>>>(pos, 2048, 8192, idxu2, d2u2);
  up2_final_kernel<16><<<dim3(512, BATCH), 128, 0, stream>>>(
      up1o, idxu2, d2u2, x, pos, u2W, u2b, fW1, fb1, fW2, fb2, out);

  // ---- second tuple element: pos passthrough ----
  copy_kernel<<<dim3(384), 256, 0, stream>>>(pos, out + (size_t)BATCH * NFULL * 128,
                                             BATCH * NFULL * 3);
}

// Round 9
// 620.577 us; speedup vs baseline: 1.9770x; 1.0853x over previous
//
#include <hip/hip_runtime.h>

#define NFULL 8192
#define BATCH 4

typedef unsigned long long u64;
typedef unsigned int u32;
typedef __attribute__((ext_vector_type(8))) short bf8_t;   // 8 bf16 (4 VGPRs)
typedef __attribute__((ext_vector_type(4))) float f4_t;    // MFMA C/D

// Total-order bias: monotone map fp32 -> u32 (handles negatives correctly).
__device__ __forceinline__ u32 fbias(float f) {
  u32 u = __float_as_uint(f);
  return (u & 0x80000000u) ? ~u : (u | 0x80000000u);
}
__device__ __forceinline__ float funbias(u32 b) {
  u32 u = (b & 0x80000000u) ? (b & 0x7fffffffu) : ~b;
  return __uint_as_float(u);
}
// fp32 -> bf16 round-to-nearest-even
__device__ __forceinline__ short f2bf(float f) {
  u32 u = __float_as_uint(f);
  u32 r = u + 0x7FFFu + ((u >> 16) & 1u);
  return (short)(r >> 16);
}

// ------------------------------------------------------------ grid build ---
// One block per batch. Histogram (LDS atomics) -> exclusive scan (two-level)
// -> global cellStart -> scatter points sorted by cell as float4(x,y,z,idx).
// Cell classification (int)(x*GR) clamped — identical expression in the query
// kernel's membership test => bitwise-identical classification.
template<int NREF, int GR>
__global__ __launch_bounds__(256) void build_grid_kernel(
    const float* __restrict__ pos, float4* __restrict__ sorted,
    int* __restrict__ cellStart, int csStride) {
  const int NC = GR * GR * GR;
  __shared__ int cnt[NC];
  __shared__ int partial[256];
  int b = blockIdx.x, t = threadIdx.x;
  const float* pb = pos + (size_t)b * NFULL * 3;
  for (int c = t; c < NC; c += 256) cnt[c] = 0;
  __syncthreads();
  for (int p = t; p < NREF; p += 256) {
    float x = pb[p * 3 + 0], y = pb[p * 3 + 1], z = pb[p * 3 + 2];
    int cx = min(max((int)(x * GR), 0), GR - 1);
    int cy = min(max((int)(y * GR), 0), GR - 1);
    int cz = min(max((int)(z * GR), 0), GR - 1);
    atomicAdd(&cnt[(cz * GR + cy) * GR + cx], 1);
  }
  __syncthreads();
  const int chunk = (NC + 255) / 256;
  int s = 0;
  for (int i = 0; i < chunk; ++i) {
    int c = t * chunk + i;
    if (c < NC) s += cnt[c];
  }
  partial[t] = s;
  __syncthreads();
  if (t == 0) {
    int run = 0;
    for (int i = 0; i < 256; ++i) { int v = partial[i]; partial[i] = run; run += v; }
  }
  __syncthreads();
  int run = partial[t];
  for (int i = 0; i < chunk; ++i) {
    int c = t * chunk + i;
    if (c < NC) { int v = cnt[c]; cnt[c] = run; run += v; }
  }
  __syncthreads();
  int* cs = cellStart + b * csStride;
  for (int c = t; c < NC; c += 256) cs[c] = cnt[c];
  if (t == 0) cs[NC] = NREF;
  __syncthreads();
  float4* sb = sorted + (size_t)b * NREF;
  for (int p = t; p < NREF; p += 256) {
    float x = pb[p * 3 + 0], y = pb[p * 3 + 1], z = pb[p * 3 + 2];
    int cx = min(max((int)(x * GR), 0), GR - 1);
    int cy = min(max((int)(y * GR), 0), GR - 1);
    int cz = min(max((int)(z * GR), 0), GR - 1);
    int slot = atomicAdd(&cnt[(cz * GR + cy) * GR + cx], 1);
    sb[slot] = make_float4(x, y, z, __uint_as_float((u32)p));
  }
}

// ------------------------------------------------------ kNN (grid-pruned) --
// Wave-per-query, distributed top-SL list (one entry/lane, R8 machinery).
// Box pass: scan the +/-R cell box around the query cell; each (y,z) row of
// the box is one contiguous segment of the sorted array (x-adjacent cells
// contiguous). EXACTNESS: any point outside the box is >= R*h away; after the
// box, if kth-d2 < (R*h)^2 strictly, stop. Otherwise full-scan fallback that
// SKIPS box members via the membership test (avoids duplicate-key inserts).
// Sentinel kth (NaN after funbias) fails the < test => fallback. Keys unique
// (d2<<32|idx) => set-exact == jax.lax.top_k incl. stable tie-break.
template<int SL, int KOUT, int QPB, int GR, int R, int NREF>
__global__ __launch_bounds__(64 * QPB) void knn_grid_kernel(
    const float* __restrict__ pos, const float4* __restrict__ sorted,
    const int* __restrict__ cellStart, int csStride, int Mq,
    int* __restrict__ oidx, float* __restrict__ od2) {
  int b = blockIdx.y;
  int w = threadIdx.x >> 6, lane = threadIdx.x & 63;
  int q = blockIdx.x * QPB + w;  // Mq multiple of QPB
  const float* pb = pos + (size_t)b * NFULL * 3;
  const float4* sb = sorted + (size_t)b * NREF;
  const int* cs = cellStart + b * csStride;
  float qx = pb[q * 3 + 0], qy = pb[q * 3 + 1], qz = pb[q * 3 + 2];
  float qq = qx * qx + qy * qy + qz * qz;
  int ix = min(max((int)(qx * GR), 0), GR - 1);
  int iy = min(max((int)(qy * GR), 0), GR - 1);
  int iz = min(max((int)(qz * GR), 0), GR - 1);
  int x0 = max(ix - R, 0), x1 = min(ix + R, GR - 1);
  int y0 = max(iy - R, 0), y1 = min(iy + R, GR - 1);
  int z0 = max(iz - R, 0), z1 = min(iz + R, GR - 1);

  int slot = lane & (SL - 1);
  u64 val = ~0ull, tau = ~0ull;

  for (int zz = z0; zz <= z1; ++zz) {
    for (int yy = y0; yy <= y1; ++yy) {
      int c0 = (zz * GR + yy) * GR + x0;
      int s = cs[c0], e = cs[c0 + (x1 - x0) + 1];
      for (int t0 = s; t0 < e; t0 += 64) {
        int j = t0 + lane;
        u64 ck = ~0ull;
        if (j < e) {
          float4 P = sb[j];
          float rr = P.x * P.x + P.y * P.y + P.z * P.z;
          float d2 = qq + rr - 2.0f * (qx * P.x + qy * P.y + qz * P.z);
          ck = ((u64)fbias(d2) << 32) | (u32)__float_as_uint(P.w);
        }
        u64 mask = __ballot(ck < tau);
        if (mask) {
          while (mask) {
            int src = __ffsll(mask) - 1;
            mask &= mask - 1;
            u64 c = __shfl((unsigned long long)ck, src, 64);
            u64 prev = __shfl_up((unsigned long long)val, 1, 64);
            if (slot == 0) prev = 0ull;
            val = (val <= c) ? val : ((prev <= c) ? c : prev);
          }
          tau = __shfl((unsigned long long)val, SL - 1, 64);
        }
      }
    }
  }

  // exactness check; fallback full scan (skipping box members) if needed
  float h = 1.0f / GR;
  float bound = (R * h) * (R * h);
  float tau_d2 = funbias((u32)(tau >> 32));
  if (!(tau_d2 < bound)) {
    for (int t0 = 0; t0 < NREF; t0 += 64) {
      int j = t0 + lane;
      u64 ck = ~0ull;
      if (j < NREF) {
        float4 P = sb[j];
        int cx = min(max((int)(P.x * GR), 0), GR - 1);
        int cy = min(max((int)(P.y * GR), 0), GR - 1);
        int cz = min(max((int)(P.z * GR), 0), GR - 1);
        bool inbox = (cx >= x0 && cx <= x1 && cy >= y0 && cy <= y1 &&
                      cz >= z0 && cz <= z1);
        if (!inbox) {
          float rr = P.x * P.x + P.y * P.y + P.z * P.z;
          float d2 = qq + rr - 2.0f * (qx * P.x + qy * P.y + qz * P.z);
          ck = ((u64)fbias(d2) << 32) | (u32)__float_as_uint(P.w);
        }
      }
      u64 mask = __ballot(ck < tau);
      if (mask) {
        while (mask) {
          int src = __ffsll(mask) - 1;
          mask &= mask - 1;
          u64 c = __shfl((unsigned long long)ck, src, 64);
          u64 prev = __shfl_up((unsigned long long)val, 1, 64);
          if (slot == 0) prev = 0ull;
          val = (val <= c) ? val : ((prev <= c) ? c : prev);
        }
        tau = __shfl((unsigned long long)val, SL - 1, 64);
      }
    }
  }

  if (lane < KOUT) {
    size_t base = ((size_t)b * Mq + q) * KOUT;
    oidx[base + lane] = (int)(u32)val;
    od2[base + lane] = fmaxf(funbias((u32)(val >> 32)), 0.0f);
  }
}

// ---------------------------------------------------------------- kNN ------
// R8 brute-force variant, kept for the small kNNs (Nref <= 2048 w/ few q).
template<int SL, int KOUT, int QPB>
__global__ __launch_bounds__(64 * QPB) void knn_kernel(
    const float* __restrict__ pos, int Nref, int Mq,
    int* __restrict__ oidx, float* __restrict__ od2) {
  int b = blockIdx.y;
  int w = threadIdx.x >> 6, lane = threadIdx.x & 63;
  int q = blockIdx.x * QPB + w;  // all Mq are multiples of QPB
  const float* pb = pos + (size_t)b * NFULL * 3;
  float qx = pb[q * 3 + 0], qy = pb[q * 3 + 1], qz = pb[q * 3 + 2];
  float qq = qx * qx + qy * qy + qz * qz;

  int slot = lane & (SL - 1);
  u64 val = ~0ull;
  u64 tau = ~0ull;

  for (int t0 = 0; t0 < Nref; t0 += 64) {  // all Nref are multiples of 64
    int j = t0 + lane;
    float rx = pb[j * 3 + 0];
    float ry = pb[j * 3 + 1];
    float rz = pb[j * 3 + 2];
    float rr = rx * rx + ry * ry + rz * rz;
    float d2 = qq + rr - 2.0f * (qx * rx + qy * ry + qz * rz);
    u64 ck = ((u64)fbias(d2) << 32) | (u32)j;
    u64 mask = __ballot(ck < tau);
    if (mask) {
      while (mask) {
        int src = __ffsll(mask) - 1;
        mask &= mask - 1;
        u64 c = __shfl((unsigned long long)ck, src, 64);
        u64 prev = __shfl_up((unsigned long long)val, 1, 64);
        if (slot == 0) prev = 0ull;
        val = (val <= c) ? val : ((prev <= c) ? c : prev);
      }
      tau = __shfl((unsigned long long)val, SL - 1, 64);
    }
  }

  if (lane < KOUT) {
    size_t base = ((size_t)b * Mq + q) * KOUT;
    oidx[base + lane] = (int)(u32)val;
    od2[base + lane] = fmaxf(funbias((u32)(val >> 32)), 0.0f);
  }
}

// -------------------------------------------------- weight packing (bf16) --
template<int KDIM, int N>
__global__ __launch_bounds__(64) void pack_w_kernel(
    const float* __restrict__ W, short* __restrict__ outp) {
  const int NT = N / 16;
  int tile = blockIdx.x;
  int kt = tile / NT, nt = tile % NT;
  int lane = threadIdx.x;
  int n = nt * 16 + (lane & 15);
  int k0 = kt * 32 + (lane >> 4) * 8;
  bf8_t v;
#pragma unroll
  for (int j = 0; j < 8; ++j) {
    int k = k0 + j;
    v[j] = (k < KDIM) ? f2bf(W[(size_t)k * N + n]) : (short)0;
  }
  *(bf8_t*)(outp + ((size_t)tile * 64 + lane) * 8) = v;
}

// ----------------------------------------------------- down MLP (MFMA) -----
template<int FEAT, int CIN, int CHID, int FPAD, int WPB>
__global__ __launch_bounds__(64 * WPB) void down_mfma_kernel(
    const float* __restrict__ pos, const float* __restrict__ xin,
    const int* __restrict__ idx,
    const short* __restrict__ W1p, const float* __restrict__ b1,
    const short* __restrict__ W2p, const float* __restrict__ b2,
    float* __restrict__ out, int n, int nprev) {
  const int KT1 = FPAD / 32, NT1 = CHID / 16;
  const int KT2 = CHID / 32, NT2 = CHID / 16;
  __shared__ short sFeat[16][FPAD];
  __shared__ short sH1[16][CHID];
  __shared__ int sIdx[16];
  __shared__ float sCtr[3];
  int b = blockIdx.y, q = blockIdx.x;
  int lane = threadIdx.x & 63, wv = threadIdx.x >> 6;
  const float* pb = pos + (size_t)b * NFULL * 3;
  const float* xb = xin + (size_t)b * nprev * CIN;
  if (threadIdx.x < 16) sIdx[threadIdx.x] = idx[((size_t)b * n + q) * 16 + threadIdx.x];
  if (threadIdx.x < 3) sCtr[threadIdx.x] = pb[q * 3 + threadIdx.x];
  __syncthreads();
  for (int e = threadIdx.x; e < 16 * FPAD; e += 64 * WPB) {
    int k = e / FPAD, c = e % FPAD;
    float v = 0.f;
    if (c < 3) v = pb[sIdx[k] * 3 + c] - sCtr[c];
    else if (c < FEAT) v = xb[(size_t)sIdx[k] * CIN + (c - 3)];
    sFeat[k][c] = f2bf(v);
  }
  __syncthreads();

  int col = lane & 15, quad = lane >> 4;
  // ---- layer 1: h1 = relu(feat @ W1 + b1) ----
  bf8_t afr[KT1];
#pragma unroll
  for (int kt = 0; kt < KT1; ++kt)
    afr[kt] = *(const bf8_t*)&sFeat[col][kt * 32 + quad * 8];
  const bf8_t* W1t = (const bf8_t*)W1p;
  for (int nt = 2 * wv; nt < NT1; nt += 2 * WPB) {
    float bb0 = b1[nt * 16 + col], bb1 = b1[nt * 16 + 16 + col];
    f4_t acc0 = {bb0, bb0, bb0, bb0}, acc1 = {bb1, bb1, bb1, bb1};
#pragma unroll
    for (int kt = 0; kt < KT1; ++kt) {
      bf8_t bf0 = W1t[(kt * NT1 + nt) * 64 + lane];
      bf8_t bf1 = W1t[(kt * NT1 + nt + 1) * 64 + lane];
      acc0 = __builtin_amdgcn_mfma_f32_16x16x32_bf16(afr[kt], bf0, acc0, 0, 0, 0);
      acc1 = __builtin_amdgcn_mfma_f32_16x16x32_bf16(afr[kt], bf1, acc1, 0, 0, 0);
    }
#pragma unroll
    for (int r = 0; r < 4; ++r) {  // D: col=lane&15, row=quad*4+r
      sH1[quad * 4 + r][nt * 16 + col] = f2bf(fmaxf(acc0[r], 0.f));
      sH1[quad * 4 + r][nt * 16 + 16 + col] = f2bf(fmaxf(acc1[r], 0.f));
    }
  }
  __syncthreads();

  // ---- layer 2: out = max_k (h1 @ W2 + b2) ----
  bf8_t afr2[KT2];
#pragma unroll
  for (int kt = 0; kt < KT2; ++kt)
    afr2[kt] = *(const bf8_t*)&sH1[col][kt * 32 + quad * 8];
  const bf8_t* W2t = (const bf8_t*)W2p;
  float* ob = out + ((size_t)b * n + q) * CHID;
  for (int nt = 2 * wv; nt < NT2; nt += 2 * WPB) {
    float bb0 = b2[nt * 16 + col], bb1 = b2[nt * 16 + 16 + col];
    f4_t acc0 = {bb0, bb0, bb0, bb0}, acc1 = {bb1, bb1, bb1, bb1};
#pragma unroll
    for (int kt = 0; kt < KT2; ++kt) {
      bf8_t bf0 = W2t[(kt * NT2 + nt) * 64 + lane];
      bf8_t bf1 = W2t[(kt * NT2 + nt + 1) * 64 + lane];
      acc0 = __builtin_amdgcn_mfma_f32_16x16x32_bf16(afr2[kt], bf0, acc0, 0, 0, 0);
      acc1 = __builtin_amdgcn_mfma_f32_16x16x32_bf16(afr2[kt], bf1, acc1, 0, 0, 0);
    }
    float m0 = fmaxf(fmaxf(acc0[0], acc0[1]), fmaxf(acc0[2], acc0[3]));
    float m1 = fmaxf(fmaxf(acc1[0], acc1[1]), fmaxf(acc1[2], acc1[3]));
    m0 = fmaxf(m0, __shfl_xor(m0, 16, 64));
    m0 = fmaxf(m0, __shfl_xor(m0, 32, 64));
    m1 = fmaxf(m1, __shfl_xor(m1, 16, 64));
    m1 = fmaxf(m1, __shfl_xor(m1, 32, 64));
    if (lane < 16) {
      ob[nt * 16 + lane] = m0;
      ob[nt * 16 + 16 + lane] = m1;
    }
  }
}

// --------------------------------------------------------------- up MLP ----
template<int CIN, int CPRV, int COUT, int TP>
__global__ __launch_bounds__(COUT) void up_kernel(
    const float* __restrict__ xc, int ncoarse,
    const int* __restrict__ idx3, const float* __restrict__ d23,
    const float* __restrict__ prv, const float* __restrict__ W,
    const float* __restrict__ bvec, float* __restrict__ out, int m) {
  const int CTOT = CIN + CPRV;
  __shared__ float sCat[TP][CTOT];
  __shared__ float sWt[TP][3];
  __shared__ int   sIt[TP][3];
  int b = blockIdx.y, q0 = blockIdx.x * TP, t = threadIdx.x;
  if (t < TP) {
    size_t base = ((size_t)b * m + q0 + t) * 3;
    float d0 = d23[base + 0], d1 = d23[base + 1], d2v = d23[base + 2];
    float w0 = 1.f / (d0 + 1e-8f), w1 = 1.f / (d1 + 1e-8f), w2 = 1.f / (d2v + 1e-8f);
    float s = w0 + w1 + w2;
    sWt[t][0] = w0 / s; sWt[t][1] = w1 / s; sWt[t][2] = w2 / s;
    sIt[t][0] = idx3[base + 0]; sIt[t][1] = idx3[base + 1]; sIt[t][2] = idx3[base + 2];
  }
  __syncthreads();
  const float* xb = xc + (size_t)b * ncoarse * CIN;
  const float* pvb = prv + ((size_t)b * m + q0) * CPRV;
  for (int e = t; e < TP * CIN; e += COUT) {
    int p = e / CIN, c = e % CIN;
    sCat[p][c] = sWt[p][0] * xb[(size_t)sIt[p][0] * CIN + c]
               + sWt[p][1] * xb[(size_t)sIt[p][1] * CIN + c]
               + sWt[p][2] * xb[(size_t)sIt[p][2] * CIN + c];
  }
  for (int e = t; e < TP * CPRV; e += COUT) {
    int p = e / CPRV, c = e % CPRV;
    sCat[p][CIN + c] = pvb[(size_t)p * CPRV + c];
  }
  __syncthreads();
  float acc[TP];
  float bb = bvec[t];
#pragma unroll
  for (int p = 0; p < TP; ++p) acc[p] = bb;
  for (int c4 = 0; c4 < CTOT / 4; ++c4) {
    int c = 4 * c4;
    float w0 = W[(c + 0) * COUT + t];
    float w1 = W[(c + 1) * COUT + t];
    float w2 = W[(c + 2) * COUT + t];
    float w3 = W[(c + 3) * COUT + t];
#pragma unroll
    for (int p = 0; p < TP; ++p) {
      float4 v = *(const float4*)&sCat[p][c];
      acc[p] = fmaf(v.x, w0, acc[p]);
      acc[p] = fmaf(v.y, w1, acc[p]);
      acc[p] = fmaf(v.z, w2, acc[p]);
      acc[p] = fmaf(v.w, w3, acc[p]);
    }
  }
#pragma unroll
  for (int p = 0; p < TP; ++p)
    out[((size_t)b * m + q0 + p) * COUT + t] = fmaxf(acc[p], 0.f);
}

// ---------------------------------------------- fused up2 + final MLP ------
template<int TP>
__global__ __launch_bounds__(128) void up2_final_kernel(
    const float* __restrict__ xc,
    const int* __restrict__ idx3, const float* __restrict__ d23,
    const float* __restrict__ x0, const float* __restrict__ pos0,
    const float* __restrict__ u2W, const float* __restrict__ u2b,
    const float* __restrict__ fW1, const float* __restrict__ fb1,
    const float* __restrict__ fW2, const float* __restrict__ fb2,
    float* __restrict__ out) {
  __shared__ float sA[TP][136];
  __shared__ float sB[TP][128];
  __shared__ float sWt[TP][3];
  __shared__ int   sIt[TP][3];
  int b = blockIdx.y, q0 = blockIdx.x * TP, t = threadIdx.x;
  if (t < TP) {
    size_t base = ((size_t)b * NFULL + q0 + t) * 3;
    float d0 = d23[base + 0], d1 = d23[base + 1], d2v = d23[base + 2];
    float w0 = 1.f / (d0 + 1e-8f), w1 = 1.f / (d1 + 1e-8f), w2 = 1.f / (d2v + 1e-8f);
    float s = w0 + w1 + w2;
    sWt[t][0] = w0 / s; sWt[t][1] = w1 / s; sWt[t][2] = w2 / s;
    sIt[t][0] = idx3[base + 0]; sIt[t][1] = idx3[base + 1]; sIt[t][2] = idx3[base + 2];
  }
  __syncthreads();
  const float* xb = xc + (size_t)b * 2048 * 128;
#pragma unroll
  for (int p = 0; p < TP; ++p) {
    sA[p][t] = sWt[p][0] * xb[(size_t)sIt[p][0] * 128 + t]
             + sWt[p][1] * xb[(size_t)sIt[p][1] * 128 + t]
             + sWt[p][2] * xb[(size_t)sIt[p][2] * 128 + t];
  }
  if (t < TP * 6) {
    int p = t / 6, c = t % 6;
    const float* src = (c < 3) ? x0 : pos0;
    int cc = (c < 3) ? c : c - 3;
    sA[p][128 + c] = src[((size_t)b * NFULL + q0 + p) * 3 + cc];
  }
  __syncthreads();
  float acc[TP];
  float bb = u2b[t];
#pragma unroll
  for (int p = 0; p < TP; ++p) acc[p] = bb;
  for (int c4 = 0; c4 < 33; ++c4) {
    int c = 4 * c4;
    float w0 = u2W[(c + 0) * 128 + t];
    float w1 = u2W[(c + 1) * 128 + t];
    float w2 = u2W[(c + 2) * 128 + t];
    float w3 = u2W[(c + 3) * 128 + t];
#pragma unroll
    for (int p = 0; p < TP; ++p) {
      float4 v = *(const float4*)&sA[p][c];
      acc[p] = fmaf(v.x, w0, acc[p]);
      acc[p] = fmaf(v.y, w1, acc[p]);
      acc[p] = fmaf(v.z, w2, acc[p]);
      acc[p] = fmaf(v.w, w3, acc[p]);
    }
  }
  {
    float wa = u2W[132 * 128 + t], wbv = u2W[133 * 128 + t];
#pragma unroll
    for (int p = 0; p < TP; ++p) {
      acc[p] = fmaf(sA[p][132], wa, acc[p]);
      acc[p] = fmaf(sA[p][133], wbv, acc[p]);
      sB[p][t] = fmaxf(acc[p], 0.f);
    }
  }
  __syncthreads();
  float acc2[TP];
  float bb2 = fb1[t];
#pragma unroll
  for (int p = 0; p < TP; ++p) acc2[p] = bb2;
  for (int c4 = 0; c4 < 32; ++c4) {
    int c = 4 * c4;
    float w0 = fW1[(c + 0) * 128 + t];
    float w1 = fW1[(c + 1) * 128 + t];
    float w2 = fW1[(c + 2) * 128 + t];
    float w3 = fW1[(c + 3) * 128 + t];
#pragma unroll
    for (int p = 0; p < TP; ++p) {
      float4 v = *(const float4*)&sB[p][c];
      acc2[p] = fmaf(v.x, w0, acc2[p]);
      acc2[p] = fmaf(v.y, w1, acc2[p]);
      acc2[p] = fmaf(v.z, w2, acc2[p]);
      acc2[p] = fmaf(v.w, w3, acc2[p]);
    }
  }
#pragma unroll
  for (int p = 0; p < TP; ++p) sA[p][t] = fmaxf(acc2[p], 0.f);
  __syncthreads();
  float acc3[TP];
  float bb3 = fb2[t];
#pragma unroll
  for (int p = 0; p < TP; ++p) acc3[p] = bb3;
  for (int c4 = 0; c4 < 32; ++c4) {
    int c = 4 * c4;
    float w0 = fW2[(c + 0) * 128 + t];
    float w1 = fW2[(c + 1) * 128 + t];
    float w2 = fW2[(c + 2) * 128 + t];
    float w3 = fW2[(c + 3) * 128 + t];
#pragma unroll
    for (int p = 0; p < TP; ++p) {
      float4 v = *(const float4*)&sA[p][c];
      acc3[p] = fmaf(v.x, w0, acc3[p]);
      acc3[p] = fmaf(v.y, w1, acc3[p]);
      acc3[p] = fmaf(v.z, w2, acc3[p]);
      acc3[p] = fmaf(v.w, w3, acc3[p]);
    }
  }
#pragma unroll
  for (int p = 0; p < TP; ++p)
    out[((size_t)b * NFULL + q0 + p) * 128 + t] = acc3[p];
}

__global__ void copy_kernel(const float* __restrict__ src, float* __restrict__ dst, int n) {
  int i = blockIdx.x * blockDim.x + threadIdx.x;
  if (i < n) dst[i] = src[i];
}

// ------------------------------------------------------------------ launch -
extern "C" void kernel_launch(void* const* d_in, const int* in_sizes, int n_in,
                              void* d_out, int out_size, void* d_ws, size_t ws_size,
                              hipStream_t stream) {
  const float* x    = (const float*)d_in[0];
  const float* pos  = (const float*)d_in[1];
  const float* d0W1 = (const float*)d_in[2];
  const float* d0b1 = (const float*)d_in[3];
  const float* d0W2 = (const float*)d_in[4];
  const float* d0b2 = (const float*)d_in[5];
  const float* d1W1 = (const float*)d_in[6];
  const float* d1b1 = (const float*)d_in[7];
  const float* d1W2 = (const float*)d_in[8];
  const float* d1b2 = (const float*)d_in[9];
  const float* d2W1 = (const float*)d_in[10];
  const float* d2b1 = (const float*)d_in[11];
  const float* d2W2 = (const float*)d_in[12];
  const float* d2b2 = (const float*)d_in[13];
  const float* u0W  = (const float*)d_in[14];
  const float* u0b  = (const float*)d_in[15];
  const float* u1W  = (const float*)d_in[16];
  const float* u1b  = (const float*)d_in[17];
  const float* u2W  = (const float*)d_in[18];
  const float* u2b  = (const float*)d_in[19];
  const float* fW1  = (const float*)d_in[20];
  const float* fb1  = (const float*)d_in[21];
  const float* fW2  = (const float*)d_in[22];
  const float* fb2  = (const float*)d_in[23];

  char* ws = (char*)d_ws;
  float* x1    = (float*)(ws + 0);
  float* x2    = (float*)(ws + 4194304);
  float* x3    = (float*)(ws + 6291456);
  float* up0o  = (float*)(ws + 7340032);
  float* up1o  = (float*)(ws + 9437184);
  int*   idx0  = (int*)  (ws + 13631488);
  int*   idx1  = (int*)  (ws + 14155776);
  int*   idx2  = (int*)  (ws + 14286848);
  float* d2s   = (float*)(ws + 14319616);
  int*   idxu0 = (int*)  (ws + 14843904);
  float* d2u0  = (float*)(ws + 14868480);
  int*   idxu1 = (int*)  (ws + 14893056);
  float* d2u1  = (float*)(ws + 14991360);
  int*   idxu2 = (int*)  (ws + 15089664);
  float* d2u2  = (float*)(ws + 15482880);
  short* d1W1p = (short*)(ws + 15876096);  // 160*256*2  = 81920
  short* d1W2p = (short*)(ws + 15958016);  // 256*256*2  = 131072
  short* d2W1p = (short*)(ws + 16089088);  // 288*512*2  = 294912
  short* d2W2p = (short*)(ws + 16384000);  // 512*512*2  = 524288
  short* d0W1p = (short*)(ws + 16908288);  // 32*128*2   = 8192
  short* d0W2p = (short*)(ws + 16916480);  // 128*128*2  = 32768 (end 16949248)
  float4* sortedA = (float4*)(ws + 16949248);  // 4*8192*16 = 524288
  int*    csA     = (int*)   (ws + 17473536);  // 4*4100*4  = 65600
  float4* sortedB = (float4*)(ws + 17539136);  // 4*2048*16 = 131072
  int*    csB     = (int*)   (ws + 17670208);  // 4*1732*4  = 27712 (end 17697920)

  float* out = (float*)d_out;

  // ---- weight packing (bf16 MFMA-B layout) + grid builds ----
  pack_w_kernel<6, 128><<<dim3(1 * 8), 64, 0, stream>>>(d0W1, d0W1p);
  pack_w_kernel<128, 128><<<dim3(4 * 8), 64, 0, stream>>>(d0W2, d0W2p);
  pack_w_kernel<131, 256><<<dim3(5 * 16), 64, 0, stream>>>(d1W1, d1W1p);
  pack_w_kernel<256, 256><<<dim3(8 * 16), 64, 0, stream>>>(d1W2, d1W2p);
  pack_w_kernel<259, 512><<<dim3(9 * 32), 64, 0, stream>>>(d2W1, d2W1p);
  pack_w_kernel<512, 512><<<dim3(16 * 32), 64, 0, stream>>>(d2W2, d2W2p);
  build_grid_kernel<8192, 16><<<dim3(BATCH), 256, 0, stream>>>(pos, sortedA, csA, 4100);
  build_grid_kernel<2048, 12><<<dim3(BATCH), 256, 0, stream>>>(pos, sortedB, csB, 1732);

  // ---- down path ----
  knn_grid_kernel<16, 16, 4, 16, 2, 8192><<<dim3(512, BATCH), 256, 0, stream>>>(
      pos, sortedA, csA, 4100, 2048, idx0, d2s);
  down_mfma_kernel<6, 3, 128, 32, 1><<<dim3(2048, BATCH), 64, 0, stream>>>(
      pos, x, idx0, d0W1p, d0b1, d0W2p, d0b2, x1, 2048, 8192);
  knn_kernel<16, 16, 4><<<dim3(128, BATCH), 256, 0, stream>>>(pos, 2048, 512, idx1, d2s);
  down_mfma_kernel<131, 128, 256, 160, 1><<<dim3(512, BATCH), 64, 0, stream>>>(
      pos, x1, idx1, d1W1p, d1b1, d1W2p, d1b2, x2, 512, 2048);
  knn_kernel<16, 16, 4><<<dim3(32, BATCH), 256, 0, stream>>>(pos, 512, 128, idx2, d2s);
  down_mfma_kernel<259, 256, 512, 288, 2><<<dim3(128, BATCH), 128, 0, stream>>>(
      pos, x2, idx2, d2W1p, d2b1, d2W2p, d2b2, x3, 128, 512);

  // ---- up path (point-tiled) ----
  knn_kernel<4, 3, 4><<<dim3(128, BATCH), 256, 0, stream>>>(pos, 128, 512, idxu0, d2u0);
  up_kernel<512, 256, 256, 8><<<dim3(64, BATCH), 256, 0, stream>>>(
      x3, 128, idxu0, d2u0, x2, u0W, u0b, up0o, 512);
  knn_kernel<4, 3, 4><<<dim3(512, BATCH), 256, 0, stream>>>(pos, 512, 2048, idxu1, d2u1);
  up_kernel<256, 128, 128, 16><<<dim3(128, BATCH), 128, 0, stream>>>(
      up0o, 512, idxu1, d2u1, x1, u1W, u1b, up1o, 2048);
  knn_grid_kernel<4, 3, 4, 12, 1, 2048><<<dim3(2048, BATCH), 256, 0, stream>>>(
      pos, sortedB, csB, 1732, 8192, idxu2, d2u2);
  up2_final_kernel<16><<<dim3(512, BATCH), 128, 0, stream>>>(
      up1o, idxu2, d2u2, x, pos, u2W, u2b, fW1, fb1, fW2, fb2, out);

  // ---- second tuple element: pos passthrough ----
  copy_kernel<<<dim3(384), 256, 0, stream>>>(pos, out + (size_t)BATCH * NFULL * 128,
                                             BATCH * NFULL * 3);
}

// Round 10
// 573.672 us; speedup vs baseline: 2.1387x; 1.0818x over previous
//
#include <hip/hip_runtime.h>

#define NFULL 8192
#define BATCH 4

typedef unsigned long long u64;
typedef unsigned int u32;
typedef __attribute__((ext_vector_type(8))) short bf8_t;   // 8 bf16 (4 VGPRs)
typedef __attribute__((ext_vector_type(4))) float f4_t;    // MFMA C/D

// Total-order bias: monotone map fp32 -> u32 (handles negatives correctly).
__device__ __forceinline__ u32 fbias(float f) {
  u32 u = __float_as_uint(f);
  return (u & 0x80000000u) ? ~u : (u | 0x80000000u);
}
__device__ __forceinline__ float funbias(u32 b) {
  u32 u = (b & 0x80000000u) ? (b & 0x7fffffffu) : ~b;
  return __uint_as_float(u);
}
// fp32 -> bf16 round-to-nearest-even
__device__ __forceinline__ short f2bf(float f) {
  u32 u = __float_as_uint(f);
  u32 r = u + 0x7FFFu + ((u >> 16) & 1u);
  return (short)(r >> 16);
}

// ------------------------------------------------------------ grid build ---
template<int NREF, int GR>
__global__ __launch_bounds__(256) void build_grid_kernel(
    const float* __restrict__ pos, float4* __restrict__ sorted,
    int* __restrict__ cellStart, int csStride) {
  const int NC = GR * GR * GR;
  __shared__ int cnt[NC];
  __shared__ int partial[256];
  int b = blockIdx.x, t = threadIdx.x;
  const float* pb = pos + (size_t)b * NFULL * 3;
  for (int c = t; c < NC; c += 256) cnt[c] = 0;
  __syncthreads();
  for (int p = t; p < NREF; p += 256) {
    float x = pb[p * 3 + 0], y = pb[p * 3 + 1], z = pb[p * 3 + 2];
    int cx = min(max((int)(x * GR), 0), GR - 1);
    int cy = min(max((int)(y * GR), 0), GR - 1);
    int cz = min(max((int)(z * GR), 0), GR - 1);
    atomicAdd(&cnt[(cz * GR + cy) * GR + cx], 1);
  }
  __syncthreads();
  const int chunk = (NC + 255) / 256;
  int s = 0;
  for (int i = 0; i < chunk; ++i) {
    int c = t * chunk + i;
    if (c < NC) s += cnt[c];
  }
  partial[t] = s;
  __syncthreads();
  if (t == 0) {
    int run = 0;
    for (int i = 0; i < 256; ++i) { int v = partial[i]; partial[i] = run; run += v; }
  }
  __syncthreads();
  int run = partial[t];
  for (int i = 0; i < chunk; ++i) {
    int c = t * chunk + i;
    if (c < NC) { int v = cnt[c]; cnt[c] = run; run += v; }
  }
  __syncthreads();
  int* cs = cellStart + b * csStride;
  for (int c = t; c < NC; c += 256) cs[c] = cnt[c];
  if (t == 0) cs[NC] = NREF;
  __syncthreads();
  float4* sb = sorted + (size_t)b * NREF;
  for (int p = t; p < NREF; p += 256) {
    float x = pb[p * 3 + 0], y = pb[p * 3 + 1], z = pb[p * 3 + 2];
    int cx = min(max((int)(x * GR), 0), GR - 1);
    int cy = min(max((int)(y * GR), 0), GR - 1);
    int cz = min(max((int)(z * GR), 0), GR - 1);
    int slot = atomicAdd(&cnt[(cz * GR + cy) * GR + cx], 1);
    sb[slot] = make_float4(x, y, z, __uint_as_float((u32)p));
  }
}

// ------------------------------------------------------ kNN (grid-pruned) --
template<int SL, int KOUT, int QPB, int GR, int R, int NREF>
__global__ __launch_bounds__(64 * QPB) void knn_grid_kernel(
    const float* __restrict__ pos, const float4* __restrict__ sorted,
    const int* __restrict__ cellStart, int csStride, int Mq,
    int* __restrict__ oidx, float* __restrict__ od2) {
  int b = blockIdx.y;
  int w = threadIdx.x >> 6, lane = threadIdx.x & 63;
  int q = blockIdx.x * QPB + w;  // Mq multiple of QPB
  const float* pb = pos + (size_t)b * NFULL * 3;
  const float4* sb = sorted + (size_t)b * NREF;
  const int* cs = cellStart + b * csStride;
  float qx = pb[q * 3 + 0], qy = pb[q * 3 + 1], qz = pb[q * 3 + 2];
  float qq = qx * qx + qy * qy + qz * qz;
  int ix = min(max((int)(qx * GR), 0), GR - 1);
  int iy = min(max((int)(qy * GR), 0), GR - 1);
  int iz = min(max((int)(qz * GR), 0), GR - 1);
  int x0 = max(ix - R, 0), x1 = min(ix + R, GR - 1);
  int y0 = max(iy - R, 0), y1 = min(iy + R, GR - 1);
  int z0 = max(iz - R, 0), z1 = min(iz + R, GR - 1);

  int slot = lane & (SL - 1);
  u64 val = ~0ull, tau = ~0ull;

  for (int zz = z0; zz <= z1; ++zz) {
    for (int yy = y0; yy <= y1; ++yy) {
      int c0 = (zz * GR + yy) * GR + x0;
      int s = cs[c0], e = cs[c0 + (x1 - x0) + 1];
      for (int t0 = s; t0 < e; t0 += 64) {
        int j = t0 + lane;
        u64 ck = ~0ull;
        if (j < e) {
          float4 P = sb[j];
          float rr = P.x * P.x + P.y * P.y + P.z * P.z;
          float d2 = qq + rr - 2.0f * (qx * P.x + qy * P.y + qz * P.z);
          ck = ((u64)fbias(d2) << 32) | (u32)__float_as_uint(P.w);
        }
        u64 mask = __ballot(ck < tau);
        if (mask) {
          while (mask) {
            int src = __ffsll(mask) - 1;
            mask &= mask - 1;
            u64 c = __shfl((unsigned long long)ck, src, 64);
            u64 prev = __shfl_up((unsigned long long)val, 1, 64);
            if (slot == 0) prev = 0ull;
            val = (val <= c) ? val : ((prev <= c) ? c : prev);
          }
          tau = __shfl((unsigned long long)val, SL - 1, 64);
        }
      }
    }
  }

  // exactness check; fallback full scan (skipping box members) if needed
  float h = 1.0f / GR;
  float bound = (R * h) * (R * h);
  float tau_d2 = funbias((u32)(tau >> 32));
  if (!(tau_d2 < bound)) {
    for (int t0 = 0; t0 < NREF; t0 += 64) {
      int j = t0 + lane;
      u64 ck = ~0ull;
      if (j < NREF) {
        float4 P = sb[j];
        int cx = min(max((int)(P.x * GR), 0), GR - 1);
        int cy = min(max((int)(P.y * GR), 0), GR - 1);
        int cz = min(max((int)(P.z * GR), 0), GR - 1);
        bool inbox = (cx >= x0 && cx <= x1 && cy >= y0 && cy <= y1 &&
                      cz >= z0 && cz <= z1);
        if (!inbox) {
          float rr = P.x * P.x + P.y * P.y + P.z * P.z;
          float d2 = qq + rr - 2.0f * (qx * P.x + qy * P.y + qz * P.z);
          ck = ((u64)fbias(d2) << 32) | (u32)__float_as_uint(P.w);
        }
      }
      u64 mask = __ballot(ck < tau);
      if (mask) {
        while (mask) {
          int src = __ffsll(mask) - 1;
          mask &= mask - 1;
          u64 c = __shfl((unsigned long long)ck, src, 64);
          u64 prev = __shfl_up((unsigned long long)val, 1, 64);
          if (slot == 0) prev = 0ull;
          val = (val <= c) ? val : ((prev <= c) ? c : prev);
        }
        tau = __shfl((unsigned long long)val, SL - 1, 64);
      }
    }
  }

  if (lane < KOUT) {
    size_t base = ((size_t)b * Mq + q) * KOUT;
    oidx[base + lane] = (int)(u32)val;
    od2[base + lane] = fmaxf(funbias((u32)(val >> 32)), 0.0f);
  }
}

// ---------------------------------------------------------------- kNN ------
template<int SL, int KOUT, int QPB>
__global__ __launch_bounds__(64 * QPB) void knn_kernel(
    const float* __restrict__ pos, int Nref, int Mq,
    int* __restrict__ oidx, float* __restrict__ od2) {
  int b = blockIdx.y;
  int w = threadIdx.x >> 6, lane = threadIdx.x & 63;
  int q = blockIdx.x * QPB + w;  // all Mq are multiples of QPB
  const float* pb = pos + (size_t)b * NFULL * 3;
  float qx = pb[q * 3 + 0], qy = pb[q * 3 + 1], qz = pb[q * 3 + 2];
  float qq = qx * qx + qy * qy + qz * qz;

  int slot = lane & (SL - 1);
  u64 val = ~0ull;
  u64 tau = ~0ull;

  for (int t0 = 0; t0 < Nref; t0 += 64) {  // all Nref are multiples of 64
    int j = t0 + lane;
    float rx = pb[j * 3 + 0];
    float ry = pb[j * 3 + 1];
    float rz = pb[j * 3 + 2];
    float rr = rx * rx + ry * ry + rz * rz;
    float d2 = qq + rr - 2.0f * (qx * rx + qy * ry + qz * rz);
    u64 ck = ((u64)fbias(d2) << 32) | (u32)j;
    u64 mask = __ballot(ck < tau);
    if (mask) {
      while (mask) {
        int src = __ffsll(mask) - 1;
        mask &= mask - 1;
        u64 c = __shfl((unsigned long long)ck, src, 64);
        u64 prev = __shfl_up((unsigned long long)val, 1, 64);
        if (slot == 0) prev = 0ull;
        val = (val <= c) ? val : ((prev <= c) ? c : prev);
      }
      tau = __shfl((unsigned long long)val, SL - 1, 64);
    }
  }

  if (lane < KOUT) {
    size_t base = ((size_t)b * Mq + q) * KOUT;
    oidx[base + lane] = (int)(u32)val;
    od2[base + lane] = fmaxf(funbias((u32)(val >> 32)), 0.0f);
  }
}

// -------------------------------------------------- weight packing (bf16) --
template<int KDIM, int N>
__global__ __launch_bounds__(64) void pack_w_kernel(
    const float* __restrict__ W, short* __restrict__ outp) {
  const int NT = N / 16;
  int tile = blockIdx.x;
  int kt = tile / NT, nt = tile % NT;
  int lane = threadIdx.x;
  int n = nt * 16 + (lane & 15);
  int k0 = kt * 32 + (lane >> 4) * 8;
  bf8_t v;
#pragma unroll
  for (int j = 0; j < 8; ++j) {
    int k = k0 + j;
    v[j] = (k < KDIM) ? f2bf(W[(size_t)k * N + n]) : (short)0;
  }
  *(bf8_t*)(outp + ((size_t)tile * 64 + lane) * 8) = v;
}

// ----------------------------------------------------- down MLP (MFMA) -----
template<int FEAT, int CIN, int CHID, int FPAD, int WPB>
__global__ __launch_bounds__(64 * WPB) void down_mfma_kernel(
    const float* __restrict__ pos, const float* __restrict__ xin,
    const int* __restrict__ idx,
    const short* __restrict__ W1p, const float* __restrict__ b1,
    const short* __restrict__ W2p, const float* __restrict__ b2,
    float* __restrict__ out, int n, int nprev) {
  const int KT1 = FPAD / 32, NT1 = CHID / 16;
  const int KT2 = CHID / 32, NT2 = CHID / 16;
  __shared__ short sFeat[16][FPAD];
  __shared__ short sH1[16][CHID];
  __shared__ int sIdx[16];
  __shared__ float sCtr[3];
  int b = blockIdx.y, q = blockIdx.x;
  int lane = threadIdx.x & 63, wv = threadIdx.x >> 6;
  const float* pb = pos + (size_t)b * NFULL * 3;
  const float* xb = xin + (size_t)b * nprev * CIN;
  if (threadIdx.x < 16) sIdx[threadIdx.x] = idx[((size_t)b * n + q) * 16 + threadIdx.x];
  if (threadIdx.x < 3) sCtr[threadIdx.x] = pb[q * 3 + threadIdx.x];
  __syncthreads();
  for (int e = threadIdx.x; e < 16 * FPAD; e += 64 * WPB) {
    int k = e / FPAD, c = e % FPAD;
    float v = 0.f;
    if (c < 3) v = pb[sIdx[k] * 3 + c] - sCtr[c];
    else if (c < FEAT) v = xb[(size_t)sIdx[k] * CIN + (c - 3)];
    sFeat[k][c] = f2bf(v);
  }
  __syncthreads();

  int col = lane & 15, quad = lane >> 4;
  // ---- layer 1: h1 = relu(feat @ W1 + b1) ----
  bf8_t afr[KT1];
#pragma unroll
  for (int kt = 0; kt < KT1; ++kt)
    afr[kt] = *(const bf8_t*)&sFeat[col][kt * 32 + quad * 8];
  const bf8_t* W1t = (const bf8_t*)W1p;
  for (int nt = 2 * wv; nt < NT1; nt += 2 * WPB) {
    float bb0 = b1[nt * 16 + col], bb1 = b1[nt * 16 + 16 + col];
    f4_t acc0 = {bb0, bb0, bb0, bb0}, acc1 = {bb1, bb1, bb1, bb1};
#pragma unroll
    for (int kt = 0; kt < KT1; ++kt) {
      bf8_t bf0 = W1t[(kt * NT1 + nt) * 64 + lane];
      bf8_t bf1 = W1t[(kt * NT1 + nt + 1) * 64 + lane];
      acc0 = __builtin_amdgcn_mfma_f32_16x16x32_bf16(afr[kt], bf0, acc0, 0, 0, 0);
      acc1 = __builtin_amdgcn_mfma_f32_16x16x32_bf16(afr[kt], bf1, acc1, 0, 0, 0);
    }
#pragma unroll
    for (int r = 0; r < 4; ++r) {  // D: col=lane&15, row=quad*4+r
      sH1[quad * 4 + r][nt * 16 + col] = f2bf(fmaxf(acc0[r], 0.f));
      sH1[quad * 4 + r][nt * 16 + 16 + col] = f2bf(fmaxf(acc1[r], 0.f));
    }
  }
  __syncthreads();

  // ---- layer 2: out = max_k (h1 @ W2 + b2) ----
  bf8_t afr2[KT2];
#pragma unroll
  for (int kt = 0; kt < KT2; ++kt)
    afr2[kt] = *(const bf8_t*)&sH1[col][kt * 32 + quad * 8];
  const bf8_t* W2t = (const bf8_t*)W2p;
  float* ob = out + ((size_t)b * n + q) * CHID;
  for (int nt = 2 * wv; nt < NT2; nt += 2 * WPB) {
    float bb0 = b2[nt * 16 + col], bb1 = b2[nt * 16 + 16 + col];
    f4_t acc0 = {bb0, bb0, bb0, bb0}, acc1 = {bb1, bb1, bb1, bb1};
#pragma unroll
    for (int kt = 0; kt < KT2; ++kt) {
      bf8_t bf0 = W2t[(kt * NT2 + nt) * 64 + lane];
      bf8_t bf1 = W2t[(kt * NT2 + nt + 1) * 64 + lane];
      acc0 = __builtin_amdgcn_mfma_f32_16x16x32_bf16(afr2[kt], bf0, acc0, 0, 0, 0);
      acc1 = __builtin_amdgcn_mfma_f32_16x16x32_bf16(afr2[kt], bf1, acc1, 0, 0, 0);
    }
    float m0 = fmaxf(fmaxf(acc0[0], acc0[1]), fmaxf(acc0[2], acc0[3]));
    float m1 = fmaxf(fmaxf(acc1[0], acc1[1]), fmaxf(acc1[2], acc1[3]));
    m0 = fmaxf(m0, __shfl_xor(m0, 16, 64));
    m0 = fmaxf(m0, __shfl_xor(m0, 32, 64));
    m1 = fmaxf(m1, __shfl_xor(m1, 16, 64));
    m1 = fmaxf(m1, __shfl_xor(m1, 32, 64));
    if (lane < 16) {
      ob[nt * 16 + lane] = m0;
      ob[nt * 16 + 16 + lane] = m1;
    }
  }
}

// --------------------------------------------------------------- up MLP ----
template<int CIN, int CPRV, int COUT, int TP>
__global__ __launch_bounds__(COUT) void up_kernel(
    const float* __restrict__ xc, int ncoarse,
    const int* __restrict__ idx3, const float* __restrict__ d23,
    const float* __restrict__ prv, const float* __restrict__ W,
    const float* __restrict__ bvec, float* __restrict__ out, int m) {
  const int CTOT = CIN + CPRV;
  __shared__ float sCat[TP][CTOT];
  __shared__ float sWt[TP][3];
  __shared__ int   sIt[TP][3];
  int b = blockIdx.y, q0 = blockIdx.x * TP, t = threadIdx.x;
  if (t < TP) {
    size_t base = ((size_t)b * m + q0 + t) * 3;
    float d0 = d23[base + 0], d1 = d23[base + 1], d2v = d23[base + 2];
    float w0 = 1.f / (d0 + 1e-8f), w1 = 1.f / (d1 + 1e-8f), w2 = 1.f / (d2v + 1e-8f);
    float s = w0 + w1 + w2;
    sWt[t][0] = w0 / s; sWt[t][1] = w1 / s; sWt[t][2] = w2 / s;
    sIt[t][0] = idx3[base + 0]; sIt[t][1] = idx3[base + 1]; sIt[t][2] = idx3[base + 2];
  }
  __syncthreads();
  const float* xb = xc + (size_t)b * ncoarse * CIN;
  const float* pvb = prv + ((size_t)b * m + q0) * CPRV;
  for (int e = t; e < TP * CIN; e += COUT) {
    int p = e / CIN, c = e % CIN;
    sCat[p][c] = sWt[p][0] * xb[(size_t)sIt[p][0] * CIN + c]
               + sWt[p][1] * xb[(size_t)sIt[p][1] * CIN + c]
               + sWt[p][2] * xb[(size_t)sIt[p][2] * CIN + c];
  }
  for (int e = t; e < TP * CPRV; e += COUT) {
    int p = e / CPRV, c = e % CPRV;
    sCat[p][CIN + c] = pvb[(size_t)p * CPRV + c];
  }
  __syncthreads();
  float acc[TP];
  float bb = bvec[t];
#pragma unroll
  for (int p = 0; p < TP; ++p) acc[p] = bb;
  for (int c4 = 0; c4 < CTOT / 4; ++c4) {
    int c = 4 * c4;
    float w0 = W[(c + 0) * COUT + t];
    float w1 = W[(c + 1) * COUT + t];
    float w2 = W[(c + 2) * COUT + t];
    float w3 = W[(c + 3) * COUT + t];
#pragma unroll
    for (int p = 0; p < TP; ++p) {
      float4 v = *(const float4*)&sCat[p][c];
      acc[p] = fmaf(v.x, w0, acc[p]);
      acc[p] = fmaf(v.y, w1, acc[p]);
      acc[p] = fmaf(v.z, w2, acc[p]);
      acc[p] = fmaf(v.w, w3, acc[p]);
    }
  }
#pragma unroll
  for (int p = 0; p < TP; ++p)
    out[((size_t)b * m + q0 + p) * COUT + t] = fmaxf(acc[p], 0.f);
}

// ------------------------------------- fused up2 + final MLP (bf16 MFMA) ---
// M=16 points per block, 2 waves. Three chained 16xKx128 matmuls:
//   L1: K=160 (134 real: interp128 ++ x0(3) ++ pos0(3), zero-pad), relu
//   L2: K=128, relu      L3: K=128, fp32 out (C-layout coalesced store)
// A staged in LDS bf16 row-major (fragments = single ds_read_b128, m89/m91
// layout); weights pre-packed B-tiles; bias in acc init. A-frags are loaded
// into registers before each MFMA loop, so writing the next layer's A into
// the same LDS after __syncthreads is hazard-free.
__global__ __launch_bounds__(128) void up2f_mfma_kernel(
    const float* __restrict__ xc,
    const int* __restrict__ idx3, const float* __restrict__ d23,
    const float* __restrict__ x0, const float* __restrict__ pos0,
    const short* __restrict__ u2Wp, const float* __restrict__ u2b,
    const short* __restrict__ fW1p, const float* __restrict__ fb1,
    const short* __restrict__ fW2p, const float* __restrict__ fb2,
    float* __restrict__ out) {
  __shared__ short sA[16][160];
  __shared__ short sB[16][128];
  __shared__ float sWt[16][3];
  __shared__ int   sIt[16][3];
  int b = blockIdx.y, q0 = blockIdx.x * 16, t = threadIdx.x;
  int lane = t & 63, wv = t >> 6;
  if (t < 16) {
    size_t base = ((size_t)b * NFULL + q0 + t) * 3;
    float d0 = d23[base + 0], d1 = d23[base + 1], d2v = d23[base + 2];
    float w0 = 1.f / (d0 + 1e-8f), w1 = 1.f / (d1 + 1e-8f), w2 = 1.f / (d2v + 1e-8f);
    float s = w0 + w1 + w2;
    sWt[t][0] = w0 / s; sWt[t][1] = w1 / s; sWt[t][2] = w2 / s;
    sIt[t][0] = idx3[base + 0]; sIt[t][1] = idx3[base + 1]; sIt[t][2] = idx3[base + 2];
  }
  __syncthreads();
  const float* xb = xc + (size_t)b * 2048 * 128;
#pragma unroll
  for (int p = 0; p < 16; ++p) {
    float v = sWt[p][0] * xb[(size_t)sIt[p][0] * 128 + t]
            + sWt[p][1] * xb[(size_t)sIt[p][1] * 128 + t]
            + sWt[p][2] * xb[(size_t)sIt[p][2] * 128 + t];
    sA[p][t] = f2bf(v);
  }
  for (int e = t; e < 16 * 32; e += 128) {  // cols 128..159 (+zero pad)
    int p = e / 32, c = 128 + (e % 32);
    float v = 0.f;
    if (c < 131) v = x0[((size_t)b * NFULL + q0 + p) * 3 + (c - 128)];
    else if (c < 134) v = pos0[((size_t)b * NFULL + q0 + p) * 3 + (c - 131)];
    sA[p][c] = f2bf(v);
  }
  __syncthreads();
  int col = lane & 15, quad = lane >> 4;

  // ---- layer 1: K=160, N=128 ----
  bf8_t a1[5];
#pragma unroll
  for (int kt = 0; kt < 5; ++kt)
    a1[kt] = *(const bf8_t*)&sA[col][kt * 32 + quad * 8];
  const bf8_t* W1t = (const bf8_t*)u2Wp;
  for (int nt = 2 * wv; nt < 8; nt += 4) {
    float bb0 = u2b[nt * 16 + col], bb1 = u2b[nt * 16 + 16 + col];
    f4_t acc0 = {bb0, bb0, bb0, bb0}, acc1 = {bb1, bb1, bb1, bb1};
#pragma unroll
    for (int kt = 0; kt < 5; ++kt) {
      bf8_t bf0 = W1t[(kt * 8 + nt) * 64 + lane];
      bf8_t bf1 = W1t[(kt * 8 + nt + 1) * 64 + lane];
      acc0 = __builtin_amdgcn_mfma_f32_16x16x32_bf16(a1[kt], bf0, acc0, 0, 0, 0);
      acc1 = __builtin_amdgcn_mfma_f32_16x16x32_bf16(a1[kt], bf1, acc1, 0, 0, 0);
    }
#pragma unroll
    for (int r = 0; r < 4; ++r) {
      sB[quad * 4 + r][nt * 16 + col] = f2bf(fmaxf(acc0[r], 0.f));
      sB[quad * 4 + r][nt * 16 + 16 + col] = f2bf(fmaxf(acc1[r], 0.f));
    }
  }
  __syncthreads();

  // ---- layer 2: K=128, N=128 ----
  bf8_t a2[4];
#pragma unroll
  for (int kt = 0; kt < 4; ++kt)
    a2[kt] = *(const bf8_t*)&sB[col][kt * 32 + quad * 8];
  const bf8_t* W2t = (const bf8_t*)fW1p;
  for (int nt = 2 * wv; nt < 8; nt += 4) {
    float bb0 = fb1[nt * 16 + col], bb1 = fb1[nt * 16 + 16 + col];
    f4_t acc0 = {bb0, bb0, bb0, bb0}, acc1 = {bb1, bb1, bb1, bb1};
#pragma unroll
    for (int kt = 0; kt < 4; ++kt) {
      bf8_t bf0 = W2t[(kt * 8 + nt) * 64 + lane];
      bf8_t bf1 = W2t[(kt * 8 + nt + 1) * 64 + lane];
      acc0 = __builtin_amdgcn_mfma_f32_16x16x32_bf16(a2[kt], bf0, acc0, 0, 0, 0);
      acc1 = __builtin_amdgcn_mfma_f32_16x16x32_bf16(a2[kt], bf1, acc1, 0, 0, 0);
    }
#pragma unroll
    for (int r = 0; r < 4; ++r) {
      sA[quad * 4 + r][nt * 16 + col] = f2bf(fmaxf(acc0[r], 0.f));
      sA[quad * 4 + r][nt * 16 + 16 + col] = f2bf(fmaxf(acc1[r], 0.f));
    }
  }
  __syncthreads();

  // ---- layer 3: K=128, N=128, fp32 out ----
  bf8_t a3[4];
#pragma unroll
  for (int kt = 0; kt < 4; ++kt)
    a3[kt] = *(const bf8_t*)&sA[col][kt * 32 + quad * 8];
  const bf8_t* W3t = (const bf8_t*)fW2p;
  float* ob = out + ((size_t)b * NFULL + q0) * 128;
  for (int nt = 2 * wv; nt < 8; nt += 4) {
    float bb0 = fb2[nt * 16 + col], bb1 = fb2[nt * 16 + 16 + col];
    f4_t acc0 = {bb0, bb0, bb0, bb0}, acc1 = {bb1, bb1, bb1, bb1};
#pragma unroll
    for (int kt = 0; kt < 4; ++kt) {
      bf8_t bf0 = W3t[(kt * 8 + nt) * 64 + lane];
      bf8_t bf1 = W3t[(kt * 8 + nt + 1) * 64 + lane];
      acc0 = __builtin_amdgcn_mfma_f32_16x16x32_bf16(a3[kt], bf0, acc0, 0, 0, 0);
      acc1 = __builtin_amdgcn_mfma_f32_16x16x32_bf16(a3[kt], bf1, acc1, 0, 0, 0);
    }
#pragma unroll
    for (int r = 0; r < 4; ++r) {
      ob[(size_t)(quad * 4 + r) * 128 + nt * 16 + col] = acc0[r];
      ob[(size_t)(quad * 4 + r) * 128 + nt * 16 + 16 + col] = acc1[r];
    }
  }
}

__global__ void copy_kernel(const float* __restrict__ src, float* __restrict__ dst, int n) {
  int i = blockIdx.x * blockDim.x + threadIdx.x;
  if (i < n) dst[i] = src[i];
}

// ------------------------------------------------------------------ launch -
extern "C" void kernel_launch(void* const* d_in, const int* in_sizes, int n_in,
                              void* d_out, int out_size, void* d_ws, size_t ws_size,
                              hipStream_t stream) {
  const float* x    = (const float*)d_in[0];
  const float* pos  = (const float*)d_in[1];
  const float* d0W1 = (const float*)d_in[2];
  const float* d0b1 = (const float*)d_in[3];
  const float* d0W2 = (const float*)d_in[4];
  const float* d0b2 = (const float*)d_in[5];
  const float* d1W1 = (const float*)d_in[6];
  const float* d1b1 = (const float*)d_in[7];
  const float* d1W2 = (const float*)d_in[8];
  const float* d1b2 = (const float*)d_in[9];
  const float* d2W1 = (const float*)d_in[10];
  const float* d2b1 = (const float*)d_in[11];
  const float* d2W2 = (const float*)d_in[12];
  const float* d2b2 = (const float*)d_in[13];
  const float* u0W  = (const float*)d_in[14];
  const float* u0b  = (const float*)d_in[15];
  const float* u1W  = (const float*)d_in[16];
  const float* u1b  = (const float*)d_in[17];
  const float* u2W  = (const float*)d_in[18];
  const float* u2b  = (const float*)d_in[19];
  const float* fW1  = (const float*)d_in[20];
  const float* fb1  = (const float*)d_in[21];
  const float* fW2  = (const float*)d_in[22];
  const float* fb2  = (const float*)d_in[23];

  char* ws = (char*)d_ws;
  float* x1    = (float*)(ws + 0);
  float* x2    = (float*)(ws + 4194304);
  float* x3    = (float*)(ws + 6291456);
  float* up0o  = (float*)(ws + 7340032);
  float* up1o  = (float*)(ws + 9437184);
  int*   idx0  = (int*)  (ws + 13631488);
  int*   idx1  = (int*)  (ws + 14155776);
  int*   idx2  = (int*)  (ws + 14286848);
  float* d2s   = (float*)(ws + 14319616);
  int*   idxu0 = (int*)  (ws + 14843904);
  float* d2u0  = (float*)(ws + 14868480);
  int*   idxu1 = (int*)  (ws + 14893056);
  float* d2u1  = (float*)(ws + 14991360);
  int*   idxu2 = (int*)  (ws + 15089664);
  float* d2u2  = (float*)(ws + 15482880);
  short* d1W1p = (short*)(ws + 15876096);  // 160*256*2  = 81920
  short* d1W2p = (short*)(ws + 15958016);  // 256*256*2  = 131072
  short* d2W1p = (short*)(ws + 16089088);  // 288*512*2  = 294912
  short* d2W2p = (short*)(ws + 16384000);  // 512*512*2  = 524288
  short* d0W1p = (short*)(ws + 16908288);  // 32*128*2   = 8192
  short* d0W2p = (short*)(ws + 16916480);  // 128*128*2  = 32768
  float4* sortedA = (float4*)(ws + 16949248);  // 524288
  int*    csA     = (int*)   (ws + 17473536);  // 65600
  float4* sortedB = (float4*)(ws + 17539136);  // 131072
  int*    csB     = (int*)   (ws + 17670208);  // 27712
  short* u2Wp  = (short*)(ws + 17697920);  // 160*128*2  = 40960
  short* fW1p  = (short*)(ws + 17738880);  // 128*128*2  = 32768
  short* fW2p  = (short*)(ws + 17771648);  // 128*128*2  = 32768 (end 17804416)

  float* out = (float*)d_out;

  // ---- weight packing (bf16 MFMA-B layout) + grid builds ----
  pack_w_kernel<6, 128><<<dim3(1 * 8), 64, 0, stream>>>(d0W1, d0W1p);
  pack_w_kernel<128, 128><<<dim3(4 * 8), 64, 0, stream>>>(d0W2, d0W2p);
  pack_w_kernel<131, 256><<<dim3(5 * 16), 64, 0, stream>>>(d1W1, d1W1p);
  pack_w_kernel<256, 256><<<dim3(8 * 16), 64, 0, stream>>>(d1W2, d1W2p);
  pack_w_kernel<259, 512><<<dim3(9 * 32), 64, 0, stream>>>(d2W1, d2W1p);
  pack_w_kernel<512, 512><<<dim3(16 * 32), 64, 0, stream>>>(d2W2, d2W2p);
  pack_w_kernel<134, 128><<<dim3(5 * 8), 64, 0, stream>>>(u2W, u2Wp);
  pack_w_kernel<128, 128><<<dim3(4 * 8), 64, 0, stream>>>(fW1, fW1p);
  pack_w_kernel<128, 128><<<dim3(4 * 8), 64, 0, stream>>>(fW2, fW2p);
  build_grid_kernel<8192, 16><<<dim3(BATCH), 256, 0, stream>>>(pos, sortedA, csA, 4100);
  build_grid_kernel<2048, 12><<<dim3(BATCH), 256, 0, stream>>>(pos, sortedB, csB, 1732);

  // ---- down path ----
  knn_grid_kernel<16, 16, 4, 16, 2, 8192><<<dim3(512, BATCH), 256, 0, stream>>>(
      pos, sortedA, csA, 4100, 2048, idx0, d2s);
  down_mfma_kernel<6, 3, 128, 32, 1><<<dim3(2048, BATCH), 64, 0, stream>>>(
      pos, x, idx0, d0W1p, d0b1, d0W2p, d0b2, x1, 2048, 8192);
  knn_kernel<16, 16, 4><<<dim3(128, BATCH), 256, 0, stream>>>(pos, 2048, 512, idx1, d2s);
  down_mfma_kernel<131, 128, 256, 160, 1><<<dim3(512, BATCH), 64, 0, stream>>>(
      pos, x1, idx1, d1W1p, d1b1, d1W2p, d1b2, x2, 512, 2048);
  knn_kernel<16, 16, 4><<<dim3(32, BATCH), 256, 0, stream>>>(pos, 512, 128, idx2, d2s);
  down_mfma_kernel<259, 256, 512, 288, 2><<<dim3(128, BATCH), 128, 0, stream>>>(
      pos, x2, idx2, d2W1p, d2b1, d2W2p, d2b2, x3, 128, 512);

  // ---- up path ----
  knn_kernel<4, 3, 4><<<dim3(128, BATCH), 256, 0, stream>>>(pos, 128, 512, idxu0, d2u0);
  up_kernel<512, 256, 256, 8><<<dim3(64, BATCH), 256, 0, stream>>>(
      x3, 128, idxu0, d2u0, x2, u0W, u0b, up0o, 512);
  knn_kernel<4, 3, 4><<<dim3(512, BATCH), 256, 0, stream>>>(pos, 512, 2048, idxu1, d2u1);
  up_kernel<256, 128, 128, 16><<<dim3(128, BATCH), 128, 0, stream>>>(
      up0o, 512, idxu1, d2u1, x1, u1W, u1b, up1o, 2048);
  knn_grid_kernel<4, 3, 4, 12, 1, 2048><<<dim3(2048, BATCH), 256, 0, stream>>>(
      pos, sortedB, csB, 1732, 8192, idxu2, d2u2);
  up2f_mfma_kernel<<<dim3(512, BATCH), 128, 0, stream>>>(
      up1o, idxu2, d2u2, x, pos, u2Wp, u2b, fW1p, fb1, fW2p, fb2, out);

  // ---- second tuple element: pos passthrough ----
  copy_kernel<<<dim3(384), 256, 0, stream>>>(pos, out + (size_t)BATCH * NFULL * 128,
                                             BATCH * NFULL * 3);
}

// Round 11
// 530.430 us; speedup vs baseline: 2.3130x; 1.0815x over previous
//
#include <hip/hip_runtime.h>

#define NFULL 8192
#define BATCH 4

typedef unsigned long long u64;
typedef unsigned int u32;
typedef __attribute__((ext_vector_type(8))) short bf8_t;   // 8 bf16 (4 VGPRs)
typedef __attribute__((ext_vector_type(4))) float f4_t;    // MFMA C/D

__device__ __forceinline__ u32 fbias(float f) {
  u32 u = __float_as_uint(f);
  return (u & 0x80000000u) ? ~u : (u | 0x80000000u);
}
__device__ __forceinline__ float funbias(u32 b) {
  u32 u = (b & 0x80000000u) ? (b & 0x7fffffffu) : ~b;
  return __uint_as_float(u);
}
__device__ __forceinline__ short f2bf(float f) {
  u32 u = __float_as_uint(f);
  u32 r = u + 0x7FFFu + ((u >> 16) & 1u);
  return (short)(r >> 16);
}

// ------------------------------------------------------------ grid build ---
template<int NREF, int GR>
__global__ __launch_bounds__(256) void build_grid_kernel(
    const float* __restrict__ pos, float4* __restrict__ sorted,
    int* __restrict__ cellStart, int csStride) {
  const int NC = GR * GR * GR;
  __shared__ int cnt[NC];
  __shared__ int partial[256];
  int b = blockIdx.x, t = threadIdx.x;
  const float* pb = pos + (size_t)b * NFULL * 3;
  for (int c = t; c < NC; c += 256) cnt[c] = 0;
  __syncthreads();
  for (int p = t; p < NREF; p += 256) {
    float x = pb[p * 3 + 0], y = pb[p * 3 + 1], z = pb[p * 3 + 2];
    int cx = min(max((int)(x * GR), 0), GR - 1);
    int cy = min(max((int)(y * GR), 0), GR - 1);
    int cz = min(max((int)(z * GR), 0), GR - 1);
    atomicAdd(&cnt[(cz * GR + cy) * GR + cx], 1);
  }
  __syncthreads();
  const int chunk = (NC + 255) / 256;
  int s = 0;
  for (int i = 0; i < chunk; ++i) {
    int c = t * chunk + i;
    if (c < NC) s += cnt[c];
  }
  partial[t] = s;
  __syncthreads();
  if (t == 0) {
    int run = 0;
    for (int i = 0; i < 256; ++i) { int v = partial[i]; partial[i] = run; run += v; }
  }
  __syncthreads();
  int run = partial[t];
  for (int i = 0; i < chunk; ++i) {
    int c = t * chunk + i;
    if (c < NC) { int v = cnt[c]; cnt[c] = run; run += v; }
  }
  __syncthreads();
  int* cs = cellStart + b * csStride;
  for (int c = t; c < NC; c += 256) cs[c] = cnt[c];
  if (t == 0) cs[NC] = NREF;
  __syncthreads();
  float4* sb = sorted + (size_t)b * NREF;
  for (int p = t; p < NREF; p += 256) {
    float x = pb[p * 3 + 0], y = pb[p * 3 + 1], z = pb[p * 3 + 2];
    int cx = min(max((int)(x * GR), 0), GR - 1);
    int cy = min(max((int)(y * GR), 0), GR - 1);
    int cz = min(max((int)(z * GR), 0), GR - 1);
    int slot = atomicAdd(&cnt[(cz * GR + cy) * GR + cx], 1);
    sb[slot] = make_float4(x, y, z, __uint_as_float((u32)p));
  }
}

// --------------------------------------------------- grouped insert core ---
// 16-lane group owns one query. Sorted top-SL list distributed one entry per
// lane within the group (slot = gl & (SL-1), replicated if SL < 16). All
// shuffles group/subgroup-scoped via width args. m16 is the group's ballot
// nibble; loop trips = population, masked per group (wave runs the union).
template<int SL>
__device__ __forceinline__ void group_insert(u32 m16, u64 ck, int slot,
                                             u64& val, u64& tau) {
  if (m16) {
    while (m16) {
      int src = __ffs(m16) - 1;
      m16 &= m16 - 1;
      u64 c = __shfl((unsigned long long)ck, src, 16);
      u64 prev = __shfl_up((unsigned long long)val, 1, SL);
      if (slot == 0) prev = 0ull;
      val = (val <= c) ? val : ((prev <= c) ? c : prev);
    }
    tau = __shfl((unsigned long long)val, SL - 1, SL);
  }
}

// ----------------------------------------------------- kNN (grid-pruned) ---
// 4 queries per wave (16-lane groups). Box pass over +/-R cells; each (y,z)
// row is one contiguous segment of the cell-sorted array. EXACTNESS: outside
// points must violate >= 1 box face that is not domain-clipped; bound = min
// over non-clipped faces of dist(q, face), squared. Domain-clipped faces have
// no points beyond them (pos in [0,1)) => infinite margin. If kth-d2 is not
// strictly < bound (incl. NaN sentinel), fall back to full scan skipping box
// members (membership test bitwise-matches the build kernel's classifier).
// Keys (biased-d2<<32 | idx) are unique => exact jax.lax.top_k semantics.
template<int SL, int KOUT, int GR, int R, int NREF>
__global__ __launch_bounds__(256) void knn_grid_kernel(
    const float* __restrict__ pos, const float4* __restrict__ sorted,
    const int* __restrict__ cellStart, int csStride, int Mq,
    int* __restrict__ oidx, float* __restrict__ od2) {
  int b = blockIdx.y;
  int wv = threadIdx.x >> 6, lane = threadIdx.x & 63;
  int g = lane >> 4, gl = lane & 15;
  int q = blockIdx.x * 16 + wv * 4 + g;  // 16 queries/block
  const float* pb = pos + (size_t)b * NFULL * 3;
  const float4* sb = sorted + (size_t)b * NREF;
  const int* cs = cellStart + b * csStride;
  float qx = pb[q * 3 + 0], qy = pb[q * 3 + 1], qz = pb[q * 3 + 2];
  float qq = qx * qx + qy * qy + qz * qz;
  int ix = min(max((int)(qx * GR), 0), GR - 1);
  int iy = min(max((int)(qy * GR), 0), GR - 1);
  int iz = min(max((int)(qz * GR), 0), GR - 1);
  int x0 = max(ix - R, 0), x1 = min(ix + R, GR - 1);
  int y0 = max(iy - R, 0), y1 = min(iy + R, GR - 1);
  int z0 = max(iz - R, 0), z1 = min(iz + R, GR - 1);

  int slot = gl & (SL - 1);
  u64 val = ~0ull, tau = ~0ull;

  for (int zz = z0; zz <= z1; ++zz) {
    for (int yy = y0; yy <= y1; ++yy) {
      int c0 = (zz * GR + yy) * GR + x0;
      int s = cs[c0], e = cs[c0 + (x1 - x0) + 1];
      for (int t0 = s; t0 < e; t0 += 16) {
        int j = t0 + gl;
        u64 ck = ~0ull;
        if (j < e) {
          float4 P = sb[j];
          float rr = P.x * P.x + P.y * P.y + P.z * P.z;
          float d2 = qq + rr - 2.0f * (qx * P.x + qy * P.y + qz * P.z);
          ck = ((u64)fbias(d2) << 32) | (u32)__float_as_uint(P.w);
        }
        u64 full = __ballot(ck < tau);
        u32 m16 = (u32)((full >> (g * 16)) & 0xFFFFull);
        group_insert<SL>(m16, ck, slot, val, tau);
      }
    }
  }

  // per-query exact margin bound (domain-clipped faces => no outside points)
  const float h = 1.0f / GR;
  float m = 1e30f;
  if (x0 > 0)      m = fminf(m, qx - x0 * h);
  if (x1 < GR - 1) m = fminf(m, (x1 + 1) * h - qx);
  if (y0 > 0)      m = fminf(m, qy - y0 * h);
  if (y1 < GR - 1) m = fminf(m, (y1 + 1) * h - qy);
  if (z0 > 0)      m = fminf(m, qz - z0 * h);
  if (z1 < GR - 1) m = fminf(m, (z1 + 1) * h - qz);
  float bound = m * m;
  float tau_d2 = funbias((u32)(tau >> 32));
  if (!(tau_d2 < bound)) {  // group-uniform; rare
    for (int t0 = 0; t0 < NREF; t0 += 16) {
      int j = t0 + gl;
      u64 ck = ~0ull;
      if (j < NREF) {
        float4 P = sb[j];
        int cx = min(max((int)(P.x * GR), 0), GR - 1);
        int cy = min(max((int)(P.y * GR), 0), GR - 1);
        int cz = min(max((int)(P.z * GR), 0), GR - 1);
        bool inbox = (cx >= x0 && cx <= x1 && cy >= y0 && cy <= y1 &&
                      cz >= z0 && cz <= z1);
        if (!inbox) {
          float rr = P.x * P.x + P.y * P.y + P.z * P.z;
          float d2 = qq + rr - 2.0f * (qx * P.x + qy * P.y + qz * P.z);
          ck = ((u64)fbias(d2) << 32) | (u32)__float_as_uint(P.w);
        }
      }
      u64 full = __ballot(ck < tau);
      u32 m16 = (u32)((full >> (g * 16)) & 0xFFFFull);
      group_insert<SL>(m16, ck, slot, val, tau);
    }
  }

  if (gl < KOUT) {
    size_t base = ((size_t)b * Mq + q) * KOUT;
    oidx[base + gl] = (int)(u32)val;
    od2[base + gl] = fmaxf(funbias((u32)(val >> 32)), 0.0f);
  }
}

// -------------------------------------------------------- kNN (brute) ------
// Grouped brute force: 4 queries per wave, 16-lane groups.
template<int SL, int KOUT>
__global__ __launch_bounds__(256) void knn_kernel(
    const float* __restrict__ pos, int Nref, int Mq,
    int* __restrict__ oidx, float* __restrict__ od2) {
  int b = blockIdx.y;
  int wv = threadIdx.x >> 6, lane = threadIdx.x & 63;
  int g = lane >> 4, gl = lane & 15;
  int q = blockIdx.x * 16 + wv * 4 + g;
  const float* pb = pos + (size_t)b * NFULL * 3;
  float qx = pb[q * 3 + 0], qy = pb[q * 3 + 1], qz = pb[q * 3 + 2];
  float qq = qx * qx + qy * qy + qz * qz;

  int slot = gl & (SL - 1);
  u64 val = ~0ull, tau = ~0ull;

  for (int t0 = 0; t0 < Nref; t0 += 16) {  // all Nref multiples of 16
    int j = t0 + gl;
    float rx = pb[j * 3 + 0];
    float ry = pb[j * 3 + 1];
    float rz = pb[j * 3 + 2];
    float rr = rx * rx + ry * ry + rz * rz;
    float d2 = qq + rr - 2.0f * (qx * rx + qy * ry + qz * rz);
    u64 ck = ((u64)fbias(d2) << 32) | (u32)j;
    u64 full = __ballot(ck < tau);
    u32 m16 = (u32)((full >> (g * 16)) & 0xFFFFull);
    group_insert<SL>(m16, ck, slot, val, tau);
  }

  if (gl < KOUT) {
    size_t base = ((size_t)b * Mq + q) * KOUT;
    oidx[base + gl] = (int)(u32)val;
    od2[base + gl] = fmaxf(funbias((u32)(val >> 32)), 0.0f);
  }
}

// -------------------------------------------------- weight packing (bf16) --
template<int KDIM, int N>
__global__ __launch_bounds__(64) void pack_w_kernel(
    const float* __restrict__ W, short* __restrict__ outp) {
  const int NT = N / 16;
  int tile = blockIdx.x;
  int kt = tile / NT, nt = tile % NT;
  int lane = threadIdx.x;
  int n = nt * 16 + (lane & 15);
  int k0 = kt * 32 + (lane >> 4) * 8;
  bf8_t v;
#pragma unroll
  for (int j = 0; j < 8; ++j) {
    int k = k0 + j;
    v[j] = (k < KDIM) ? f2bf(W[(size_t)k * N + n]) : (short)0;
  }
  *(bf8_t*)(outp + ((size_t)tile * 64 + lane) * 8) = v;
}

// ----------------------------------------------------- down MLP (MFMA) -----
template<int FEAT, int CIN, int CHID, int FPAD, int WPB>
__global__ __launch_bounds__(64 * WPB) void down_mfma_kernel(
    const float* __restrict__ pos, const float* __restrict__ xin,
    const int* __restrict__ idx,
    const short* __restrict__ W1p, const float* __restrict__ b1,
    const short* __restrict__ W2p, const float* __restrict__ b2,
    float* __restrict__ out, int n, int nprev) {
  const int KT1 = FPAD / 32, NT1 = CHID / 16;
  const int KT2 = CHID / 32, NT2 = CHID / 16;
  __shared__ short sFeat[16][FPAD];
  __shared__ short sH1[16][CHID];
  __shared__ int sIdx[16];
  __shared__ float sCtr[3];
  int b = blockIdx.y, q = blockIdx.x;
  int lane = threadIdx.x & 63, wv = threadIdx.x >> 6;
  const float* pb = pos + (size_t)b * NFULL * 3;
  const float* xb = xin + (size_t)b * nprev * CIN;
  if (threadIdx.x < 16) sIdx[threadIdx.x] = idx[((size_t)b * n + q) * 16 + threadIdx.x];
  if (threadIdx.x < 3) sCtr[threadIdx.x] = pb[q * 3 + threadIdx.x];
  __syncthreads();
  for (int e = threadIdx.x; e < 16 * FPAD; e += 64 * WPB) {
    int k = e / FPAD, c = e % FPAD;
    float v = 0.f;
    if (c < 3) v = pb[sIdx[k] * 3 + c] - sCtr[c];
    else if (c < FEAT) v = xb[(size_t)sIdx[k] * CIN + (c - 3)];
    sFeat[k][c] = f2bf(v);
  }
  __syncthreads();

  int col = lane & 15, quad = lane >> 4;
  bf8_t afr[KT1];
#pragma unroll
  for (int kt = 0; kt < KT1; ++kt)
    afr[kt] = *(const bf8_t*)&sFeat[col][kt * 32 + quad * 8];
  const bf8_t* W1t = (const bf8_t*)W1p;
  for (int nt = 2 * wv; nt < NT1; nt += 2 * WPB) {
    float bb0 = b1[nt * 16 + col], bb1 = b1[nt * 16 + 16 + col];
    f4_t acc0 = {bb0, bb0, bb0, bb0}, acc1 = {bb1, bb1, bb1, bb1};
#pragma unroll
    for (int kt = 0; kt < KT1; ++kt) {
      bf8_t bf0 = W1t[(kt * NT1 + nt) * 64 + lane];
      bf8_t bf1 = W1t[(kt * NT1 + nt + 1) * 64 + lane];
      acc0 = __builtin_amdgcn_mfma_f32_16x16x32_bf16(afr[kt], bf0, acc0, 0, 0, 0);
      acc1 = __builtin_amdgcn_mfma_f32_16x16x32_bf16(afr[kt], bf1, acc1, 0, 0, 0);
    }
#pragma unroll
    for (int r = 0; r < 4; ++r) {
      sH1[quad * 4 + r][nt * 16 + col] = f2bf(fmaxf(acc0[r], 0.f));
      sH1[quad * 4 + r][nt * 16 + 16 + col] = f2bf(fmaxf(acc1[r], 0.f));
    }
  }
  __syncthreads();

  bf8_t afr2[KT2];
#pragma unroll
  for (int kt = 0; kt < KT2; ++kt)
    afr2[kt] = *(const bf8_t*)&sH1[col][kt * 32 + quad * 8];
  const bf8_t* W2t = (const bf8_t*)W2p;
  float* ob = out + ((size_t)b * n + q) * CHID;
  for (int nt = 2 * wv; nt < NT2; nt += 2 * WPB) {
    float bb0 = b2[nt * 16 + col], bb1 = b2[nt * 16 + 16 + col];
    f4_t acc0 = {bb0, bb0, bb0, bb0}, acc1 = {bb1, bb1, bb1, bb1};
#pragma unroll
    for (int kt = 0; kt < KT2; ++kt) {
      bf8_t bf0 = W2t[(kt * NT2 + nt) * 64 + lane];
      bf8_t bf1 = W2t[(kt * NT2 + nt + 1) * 64 + lane];
      acc0 = __builtin_amdgcn_mfma_f32_16x16x32_bf16(afr2[kt], bf0, acc0, 0, 0, 0);
      acc1 = __builtin_amdgcn_mfma_f32_16x16x32_bf16(afr2[kt], bf1, acc1, 0, 0, 0);
    }
    float m0 = fmaxf(fmaxf(acc0[0], acc0[1]), fmaxf(acc0[2], acc0[3]));
    float m1 = fmaxf(fmaxf(acc1[0], acc1[1]), fmaxf(acc1[2], acc1[3]));
    m0 = fmaxf(m0, __shfl_xor(m0, 16, 64));
    m0 = fmaxf(m0, __shfl_xor(m0, 32, 64));
    m1 = fmaxf(m1, __shfl_xor(m1, 16, 64));
    m1 = fmaxf(m1, __shfl_xor(m1, 32, 64));
    if (lane < 16) {
      ob[nt * 16 + lane] = m0;
      ob[nt * 16 + 16 + lane] = m1;
    }
  }
}

// --------------------------------------------------------------- up MLP ----
template<int CIN, int CPRV, int COUT, int TP>
__global__ __launch_bounds__(COUT) void up_kernel(
    const float* __restrict__ xc, int ncoarse,
    const int* __restrict__ idx3, const float* __restrict__ d23,
    const float* __restrict__ prv, const float* __restrict__ W,
    const float* __restrict__ bvec, float* __restrict__ out, int m) {
  const int CTOT = CIN + CPRV;
  __shared__ float sCat[TP][CTOT];
  __shared__ float sWt[TP][3];
  __shared__ int   sIt[TP][3];
  int b = blockIdx.y, q0 = blockIdx.x * TP, t = threadIdx.x;
  if (t < TP) {
    size_t base = ((size_t)b * m + q0 + t) * 3;
    float d0 = d23[base + 0], d1 = d23[base + 1], d2v = d23[base + 2];
    float w0 = 1.f / (d0 + 1e-8f), w1 = 1.f / (d1 + 1e-8f), w2 = 1.f / (d2v + 1e-8f);
    float s = w0 + w1 + w2;
    sWt[t][0] = w0 / s; sWt[t][1] = w1 / s; sWt[t][2] = w2 / s;
    sIt[t][0] = idx3[base + 0]; sIt[t][1] = idx3[base + 1]; sIt[t][2] = idx3[base + 2];
  }
  __syncthreads();
  const float* xb = xc + (size_t)b * ncoarse * CIN;
  const float* pvb = prv + ((size_t)b * m + q0) * CPRV;
  for (int e = t; e < TP * CIN; e += COUT) {
    int p = e / CIN, c = e % CIN;
    sCat[p][c] = sWt[p][0] * xb[(size_t)sIt[p][0] * CIN + c]
               + sWt[p][1] * xb[(size_t)sIt[p][1] * CIN + c]
               + sWt[p][2] * xb[(size_t)sIt[p][2] * CIN + c];
  }
  for (int e = t; e < TP * CPRV; e += COUT) {
    int p = e / CPRV, c = e % CPRV;
    sCat[p][CIN + c] = pvb[(size_t)p * CPRV + c];
  }
  __syncthreads();
  float acc[TP];
  float bb = bvec[t];
#pragma unroll
  for (int p = 0; p < TP; ++p) acc[p] = bb;
  for (int c4 = 0; c4 < CTOT / 4; ++c4) {
    int c = 4 * c4;
    float w0 = W[(c + 0) * COUT + t];
    float w1 = W[(c + 1) * COUT + t];
    float w2 = W[(c + 2) * COUT + t];
    float w3 = W[(c + 3) * COUT + t];
#pragma unroll
    for (int p = 0; p < TP; ++p) {
      float4 v = *(const float4*)&sCat[p][c];
      acc[p] = fmaf(v.x, w0, acc[p]);
      acc[p] = fmaf(v.y, w1, acc[p]);
      acc[p] = fmaf(v.z, w2, acc[p]);
      acc[p] = fmaf(v.w, w3, acc[p]);
    }
  }
#pragma unroll
  for (int p = 0; p < TP; ++p)
    out[((size_t)b * m + q0 + p) * COUT + t] = fmaxf(acc[p], 0.f);
}

// ------------------------------------- fused up2 + final MLP (bf16 MFMA) ---
__global__ __launch_bounds__(128) void up2f_mfma_kernel(
    const float* __restrict__ xc,
    const int* __restrict__ idx3, const float* __restrict__ d23,
    const float* __restrict__ x0, const float* __restrict__ pos0,
    const short* __restrict__ u2Wp, const float* __restrict__ u2b,
    const short* __restrict__ fW1p, const float* __restrict__ fb1,
    const short* __restrict__ fW2p, const float* __restrict__ fb2,
    float* __restrict__ out) {
  __shared__ short sA[16][160];
  __shared__ short sB[16][128];
  __shared__ float sWt[16][3];
  __shared__ int   sIt[16][3];
  int b = blockIdx.y, q0 = blockIdx.x * 16, t = threadIdx.x;
  int lane = t & 63, wv = t >> 6;
  if (t < 16) {
    size_t base = ((size_t)b * NFULL + q0 + t) * 3;
    float d0 = d23[base + 0], d1 = d23[base + 1], d2v = d23[base + 2];
    float w0 = 1.f / (d0 + 1e-8f), w1 = 1.f / (d1 + 1e-8f), w2 = 1.f / (d2v + 1e-8f);
    float s = w0 + w1 + w2;
    sWt[t][0] = w0 / s; sWt[t][1] = w1 / s; sWt[t][2] = w2 / s;
    sIt[t][0] = idx3[base + 0]; sIt[t][1] = idx3[base + 1]; sIt[t][2] = idx3[base + 2];
  }
  __syncthreads();
  const float* xb = xc + (size_t)b * 2048 * 128;
#pragma unroll
  for (int p = 0; p < 16; ++p) {
    float v = sWt[p][0] * xb[(size_t)sIt[p][0] * 128 + t]
            + sWt[p][1] * xb[(size_t)sIt[p][1] * 128 + t]
            + sWt[p][2] * xb[(size_t)sIt[p][2] * 128 + t];
    sA[p][t] = f2bf(v);
  }
  for (int e = t; e < 16 * 32; e += 128) {
    int p = e / 32, c = 128 + (e % 32);
    float v = 0.f;
    if (c < 131) v = x0[((size_t)b * NFULL + q0 + p) * 3 + (c - 128)];
    else if (c < 134) v = pos0[((size_t)b * NFULL + q0 + p) * 3 + (c - 131)];
    sA[p][c] = f2bf(v);
  }
  __syncthreads();
  int col = lane & 15, quad = lane >> 4;

  bf8_t a1[5];
#pragma unroll
  for (int kt = 0; kt < 5; ++kt)
    a1[kt] = *(const bf8_t*)&sA[col][kt * 32 + quad * 8];
  const bf8_t* W1t = (const bf8_t*)u2Wp;
  for (int nt = 2 * wv; nt < 8; nt += 4) {
    float bb0 = u2b[nt * 16 + col], bb1 = u2b[nt * 16 + 16 + col];
    f4_t acc0 = {bb0, bb0, bb0, bb0}, acc1 = {bb1, bb1, bb1, bb1};
#pragma unroll
    for (int kt = 0; kt < 5; ++kt) {
      bf8_t bf0 = W1t[(kt * 8 + nt) * 64 + lane];
      bf8_t bf1 = W1t[(kt * 8 + nt + 1) * 64 + lane];
      acc0 = __builtin_amdgcn_mfma_f32_16x16x32_bf16(a1[kt], bf0, acc0, 0, 0, 0);
      acc1 = __builtin_amdgcn_mfma_f32_16x16x32_bf16(a1[kt], bf1, acc1, 0, 0, 0);
    }
#pragma unroll
    for (int r = 0; r < 4; ++r) {
      sB[quad * 4 + r][nt * 16 + col] = f2bf(fmaxf(acc0[r], 0.f));
      sB[quad * 4 + r][nt * 16 + 16 + col] = f2bf(fmaxf(acc1[r], 0.f));
    }
  }
  __syncthreads();

  bf8_t a2[4];
#pragma unroll
  for (int kt = 0; kt < 4; ++kt)
    a2[kt] = *(const bf8_t*)&sB[col][kt * 32 + quad * 8];
  const bf8_t* W2t = (const bf8_t*)fW1p;
  for (int nt = 2 * wv; nt < 8; nt += 4) {
    float bb0 = fb1[nt * 16 + col], bb1 = fb1[nt * 16 + 16 + col];
    f4_t acc0 = {bb0, bb0, bb0, bb0}, acc1 = {bb1, bb1, bb1, bb1};
#pragma unroll
    for (int kt = 0; kt < 4; ++kt) {
      bf8_t bf0 = W2t[(kt * 8 + nt) * 64 + lane];
      bf8_t bf1 = W2t[(kt * 8 + nt + 1) * 64 + lane];
      acc0 = __builtin_amdgcn_mfma_f32_16x16x32_bf16(a2[kt], bf0, acc0, 0, 0, 0);
      acc1 = __builtin_amdgcn_mfma_f32_16x16x32_bf16(a2[kt], bf1, acc1, 0, 0, 0);
    }
#pragma unroll
    for (int r = 0; r < 4; ++r) {
      sA[quad * 4 + r][nt * 16 + col] = f2bf(fmaxf(acc0[r], 0.f));
      sA[quad * 4 + r][nt * 16 + 16 + col] = f2bf(fmaxf(acc1[r], 0.f));
    }
  }
  __syncthreads();

  bf8_t a3[4];
#pragma unroll
  for (int kt = 0; kt < 4; ++kt)
    a3[kt] = *(const bf8_t*)&sA[col][kt * 32 + quad * 8];
  const bf8_t* W3t = (const bf8_t*)fW2p;
  float* ob = out + ((size_t)b * NFULL + q0) * 128;
  for (int nt = 2 * wv; nt < 8; nt += 4) {
    float bb0 = fb2[nt * 16 + col], bb1 = fb2[nt * 16 + 16 + col];
    f4_t acc0 = {bb0, bb0, bb0, bb0}, acc1 = {bb1, bb1, bb1, bb1};
#pragma unroll
    for (int kt = 0; kt < 4; ++kt) {
      bf8_t bf0 = W3t[(kt * 8 + nt) * 64 + lane];
      bf8_t bf1 = W3t[(kt * 8 + nt + 1) * 64 + lane];
      acc0 = __builtin_amdgcn_mfma_f32_16x16x32_bf16(a3[kt], bf0, acc0, 0, 0, 0);
      acc1 = __builtin_amdgcn_mfma_f32_16x16x32_bf16(a3[kt], bf1, acc1, 0, 0, 0);
    }
#pragma unroll
    for (int r = 0; r < 4; ++r) {
      ob[(size_t)(quad * 4 + r) * 128 + nt * 16 + col] = acc0[r];
      ob[(size_t)(quad * 4 + r) * 128 + nt * 16 + 16 + col] = acc1[r];
    }
  }
}

__global__ void copy_kernel(const float* __restrict__ src, float* __restrict__ dst, int n) {
  int i = blockIdx.x * blockDim.x + threadIdx.x;
  if (i < n) dst[i] = src[i];
}

// ------------------------------------------------------------------ launch -
extern "C" void kernel_launch(void* const* d_in, const int* in_sizes, int n_in,
                              void* d_out, int out_size, void* d_ws, size_t ws_size,
                              hipStream_t stream) {
  const float* x    = (const float*)d_in[0];
  const float* pos  = (const float*)d_in[1];
  const float* d0W1 = (const float*)d_in[2];
  const float* d0b1 = (const float*)d_in[3];
  const float* d0W2 = (const float*)d_in[4];
  const float* d0b2 = (const float*)d_in[5];
  const float* d1W1 = (const float*)d_in[6];
  const float* d1b1 = (const float*)d_in[7];
  const float* d1W2 = (const float*)d_in[8];
  const float* d1b2 = (const float*)d_in[9];
  const float* d2W1 = (const float*)d_in[10];
  const float* d2b1 = (const float*)d_in[11];
  const float* d2W2 = (const float*)d_in[12];
  const float* d2b2 = (const float*)d_in[13];
  const float* u0W  = (const float*)d_in[14];
  const float* u0b  = (const float*)d_in[15];
  const float* u1W  = (const float*)d_in[16];
  const float* u1b  = (const float*)d_in[17];
  const float* u2W  = (const float*)d_in[18];
  const float* u2b  = (const float*)d_in[19];
  const float* fW1  = (const float*)d_in[20];
  const float* fb1  = (const float*)d_in[21];
  const float* fW2  = (const float*)d_in[22];
  const float* fb2  = (const float*)d_in[23];

  char* ws = (char*)d_ws;
  float* x1    = (float*)(ws + 0);
  float* x2    = (float*)(ws + 4194304);
  float* x3    = (float*)(ws + 6291456);
  float* up0o  = (float*)(ws + 7340032);
  float* up1o  = (float*)(ws + 9437184);
  int*   idx0  = (int*)  (ws + 13631488);
  int*   idx1  = (int*)  (ws + 14155776);
  int*   idx2  = (int*)  (ws + 14286848);
  float* d2s   = (float*)(ws + 14319616);
  int*   idxu0 = (int*)  (ws + 14843904);
  float* d2u0  = (float*)(ws + 14868480);
  int*   idxu1 = (int*)  (ws + 14893056);
  float* d2u1  = (float*)(ws + 14991360);
  int*   idxu2 = (int*)  (ws + 15089664);
  float* d2u2  = (float*)(ws + 15482880);
  short* d1W1p = (short*)(ws + 15876096);
  short* d1W2p = (short*)(ws + 15958016);
  short* d2W1p = (short*)(ws + 16089088);
  short* d2W2p = (short*)(ws + 16384000);
  short* d0W1p = (short*)(ws + 16908288);
  short* d0W2p = (short*)(ws + 16916480);
  float4* sortedA = (float4*)(ws + 16949248);  // 4*8192*16 = 524288
  int*    csA     = (int*)   (ws + 17473536);  // 4*4097*4  = 65552
  float4* sortedB = (float4*)(ws + 17539136);  // 4*2048*16 = 131072
  int*    csB     = (int*)   (ws + 17670208);  // 4*513*4   = 8208
  short* u2Wp  = (short*)(ws + 17697920);
  short* fW1p  = (short*)(ws + 17738880);
  short* fW2p  = (short*)(ws + 17771648);

  float* out = (float*)d_out;

  // ---- weight packing + grid builds ----
  pack_w_kernel<6, 128><<<dim3(1 * 8), 64, 0, stream>>>(d0W1, d0W1p);
  pack_w_kernel<128, 128><<<dim3(4 * 8), 64, 0, stream>>>(d0W2, d0W2p);
  pack_w_kernel<131, 256><<<dim3(5 * 16), 64, 0, stream>>>(d1W1, d1W1p);
  pack_w_kernel<256, 256><<<dim3(8 * 16), 64, 0, stream>>>(d1W2, d1W2p);
  pack_w_kernel<259, 512><<<dim3(9 * 32), 64, 0, stream>>>(d2W1, d2W1p);
  pack_w_kernel<512, 512><<<dim3(16 * 32), 64, 0, stream>>>(d2W2, d2W2p);
  pack_w_kernel<134, 128><<<dim3(5 * 8), 64, 0, stream>>>(u2W, u2Wp);
  pack_w_kernel<128, 128><<<dim3(4 * 8), 64, 0, stream>>>(fW1, fW1p);
  pack_w_kernel<128, 128><<<dim3(4 * 8), 64, 0, stream>>>(fW2, fW2p);
  build_grid_kernel<8192, 16><<<dim3(BATCH), 256, 0, stream>>>(pos, sortedA, csA, 4097);
  build_grid_kernel<2048, 8><<<dim3(BATCH), 256, 0, stream>>>(pos, sortedB, csB, 513);

  // ---- down path ----
  knn_grid_kernel<16, 16, 16, 2, 8192><<<dim3(128, BATCH), 256, 0, stream>>>(
      pos, sortedA, csA, 4097, 2048, idx0, d2s);
  down_mfma_kernel<6, 3, 128, 32, 1><<<dim3(2048, BATCH), 64, 0, stream>>>(
      pos, x, idx0, d0W1p, d0b1, d0W2p, d0b2, x1, 2048, 8192);
  knn_grid_kernel<16, 16, 8, 2, 2048><<<dim3(32, BATCH), 256, 0, stream>>>(
      pos, sortedB, csB, 513, 512, idx1, d2s);
  down_mfma_kernel<131, 128, 256, 160, 1><<<dim3(512, BATCH), 64, 0, stream>>>(
      pos, x1, idx1, d1W1p, d1b1, d1W2p, d1b2, x2, 512, 2048);
  knn_kernel<16, 16><<<dim3(8, BATCH), 256, 0, stream>>>(pos, 512, 128, idx2, d2s);
  down_mfma_kernel<259, 256, 512, 288, 2><<<dim3(128, BATCH), 128, 0, stream>>>(
      pos, x2, idx2, d2W1p, d2b1, d2W2p, d2b2, x3, 128, 512);

  // ---- up path ----
  knn_kernel<4, 3><<<dim3(32, BATCH), 256, 0, stream>>>(pos, 128, 512, idxu0, d2u0);
  up_kernel<512, 256, 256, 8><<<dim3(64, BATCH), 256, 0, stream>>>(
      x3, 128, idxu0, d2u0, x2, u0W, u0b, up0o, 512);
  knn_kernel<4, 3><<<dim3(128, BATCH), 256, 0, stream>>>(pos, 512, 2048, idxu1, d2u1);
  up_kernel<256, 128, 128, 16><<<dim3(128, BATCH), 128, 0, stream>>>(
      up0o, 512, idxu1, d2u1, x1, u1W, u1b, up1o, 2048);
  knn_grid_kernel<4, 3, 8, 1, 2048><<<dim3(512, BATCH), 256, 0, stream>>>(
      pos, sortedB, csB, 513, 8192, idxu2, d2u2);
  up2f_mfma_kernel<<<dim3(512, BATCH), 128, 0, stream>>>(
      up1o, idxu2, d2u2, x, pos, u2Wp, u2b, fW1p, fb1, fW2p, fb2, out);

  // ---- second tuple element: pos passthrough ----
  copy_kernel<<<dim3(384), 256, 0, stream>>>(pos, out + (size_t)BATCH * NFULL * 128,
                                             BATCH * NFULL * 3);
}

// Round 12
// 491.974 us; speedup vs baseline: 2.4938x; 1.0782x over previous
//
#include <hip/hip_runtime.h>

#define NFULL 8192
#define BATCH 4

typedef unsigned long long u64;
typedef unsigned int u32;
typedef __attribute__((ext_vector_type(8))) short bf8_t;   // 8 bf16 (4 VGPRs)
typedef __attribute__((ext_vector_type(4))) float f4_t;    // MFMA C/D

__device__ __forceinline__ u32 fbias(float f) {
  u32 u = __float_as_uint(f);
  return (u & 0x80000000u) ? ~u : (u | 0x80000000u);
}
__device__ __forceinline__ float funbias(u32 b) {
  u32 u = (b & 0x80000000u) ? (b & 0x7fffffffu) : ~b;
  return __uint_as_float(u);
}
__device__ __forceinline__ short f2bf(float f) {
  u32 u = __float_as_uint(f);
  u32 r = u + 0x7FFFu + ((u >> 16) & 1u);
  return (short)(r >> 16);
}

// ------------------------------------------------ fused grid build (both) --
// grid (BATCH, 2): y=0 builds the 16^3/8192 grid, y=1 the 8^3/2048 grid.
// Classification (int)(x*GR) clamped — bitwise-identical to query kernels.
__global__ __launch_bounds__(256) void build_grids_kernel(
    const float* __restrict__ pos, float4* __restrict__ sortedA,
    int* __restrict__ csA, float4* __restrict__ sortedB, int* __restrict__ csB) {
  __shared__ int cnt[4096];
  __shared__ int partial[256];
  int which = blockIdx.y, b = blockIdx.x, t = threadIdx.x;
  int NREF = which ? 2048 : 8192;
  int GR = which ? 8 : 16;
  int NC = GR * GR * GR;
  float4* sorted = (which ? sortedB : sortedA) + (size_t)b * NREF;
  int* cs = (which ? csB : csA) + b * (which ? 513 : 4097);
  const float* pb = pos + (size_t)b * NFULL * 3;
  for (int c = t; c < NC; c += 256) cnt[c] = 0;
  __syncthreads();
  for (int p = t; p < NREF; p += 256) {
    float x = pb[p * 3 + 0], y = pb[p * 3 + 1], z = pb[p * 3 + 2];
    int cx = min(max((int)(x * GR), 0), GR - 1);
    int cy = min(max((int)(y * GR), 0), GR - 1);
    int cz = min(max((int)(z * GR), 0), GR - 1);
    atomicAdd(&cnt[(cz * GR + cy) * GR + cx], 1);
  }
  __syncthreads();
  int chunk = (NC + 255) / 256;
  int s = 0;
  for (int i = 0; i < chunk; ++i) {
    int c = t * chunk + i;
    if (c < NC) s += cnt[c];
  }
  partial[t] = s;
  __syncthreads();
  if (t == 0) {
    int run = 0;
    for (int i = 0; i < 256; ++i) { int v = partial[i]; partial[i] = run; run += v; }
  }
  __syncthreads();
  int run = partial[t];
  for (int i = 0; i < chunk; ++i) {
    int c = t * chunk + i;
    if (c < NC) { int v = cnt[c]; cnt[c] = run; run += v; }
  }
  __syncthreads();
  for (int c = t; c < NC; c += 256) cs[c] = cnt[c];
  if (t == 0) cs[NC] = NREF;
  __syncthreads();
  for (int p = t; p < NREF; p += 256) {
    float x = pb[p * 3 + 0], y = pb[p * 3 + 1], z = pb[p * 3 + 2];
    int cx = min(max((int)(x * GR), 0), GR - 1);
    int cy = min(max((int)(y * GR), 0), GR - 1);
    int cz = min(max((int)(z * GR), 0), GR - 1);
    int slot = atomicAdd(&cnt[(cz * GR + cy) * GR + cx], 1);
    sorted[slot] = make_float4(x, y, z, __uint_as_float((u32)p));
  }
}

// --------------------------------------------------- grouped insert core ---
template<int SL>
__device__ __forceinline__ void group_insert(u32 m16, u64 ck, int slot,
                                             u64& val, u64& tau) {
  if (m16) {
    while (m16) {
      int src = __ffs(m16) - 1;
      m16 &= m16 - 1;
      u64 c = __shfl((unsigned long long)ck, src, 16);
      u64 prev = __shfl_up((unsigned long long)val, 1, SL);
      if (slot == 0) prev = 0ull;
      val = (val <= c) ? val : ((prev <= c) ? c : prev);
    }
    tau = __shfl((unsigned long long)val, SL - 1, SL);
  }
}

// -------------------- shared: box computation + margin-bound + fallback ----
// (exactness argument unchanged from R11: per-face margin; domain-clipped
// faces have no points beyond them; strict < vs exact kth; unique u64 keys)

// --------------------------------------- kNN grid, FLAT (NROW <= 16) -------
// R12: parallel cs prefetch (1 round), 16-wide prefix scan, flattened virtual
// candidate index with 4-step shfl binary search. Loads independent across
// rounds => pipelined; only ballot+insert remains serial.
template<int SL, int KOUT, int GR, int R, int NREF>
__global__ __launch_bounds__(256) void knn_grid_flat_kernel(
    const float* __restrict__ pos, const float4* __restrict__ sorted,
    const int* __restrict__ cellStart, int csStride, int Mq,
    int* __restrict__ oidx, float* __restrict__ od2) {
  int b = blockIdx.y;
  int wv = threadIdx.x >> 6, lane = threadIdx.x & 63;
  int g = lane >> 4, gl = lane & 15;
  int q = blockIdx.x * 16 + wv * 4 + g;
  const float* pb = pos + (size_t)b * NFULL * 3;
  const float4* sb = sorted + (size_t)b * NREF;
  const int* cs = cellStart + b * csStride;
  float qx = pb[q * 3 + 0], qy = pb[q * 3 + 1], qz = pb[q * 3 + 2];
  float qq = qx * qx + qy * qy + qz * qz;
  int ix = min(max((int)(qx * GR), 0), GR - 1);
  int iy = min(max((int)(qy * GR), 0), GR - 1);
  int iz = min(max((int)(qz * GR), 0), GR - 1);
  int x0 = max(ix - R, 0), x1 = min(ix + R, GR - 1);
  int y0 = max(iy - R, 0), y1 = min(iy + R, GR - 1);
  int z0 = max(iz - R, 0), z1 = min(iz + R, GR - 1);

  int ny = y1 - y0 + 1;
  int nrow = (z1 - z0 + 1) * ny;  // <= 9 for R=1
  int s_i = 0, len_i = 0;
  if (gl < nrow) {
    int zz = z0 + gl / ny, yy = y0 + gl % ny;
    int c0 = (zz * GR + yy) * GR + x0;
    s_i = cs[c0];
    len_i = cs[c0 + (x1 - x0) + 1] - s_i;
  }
  int p_i = len_i;
#pragma unroll
  for (int st = 1; st < 16; st <<= 1) {
    int o = __shfl_up(p_i, st, 16);
    if (gl >= st) p_i += o;
  }
  int T = __shfl(p_i, 15, 16);
  p_i -= len_i;              // exclusive prefix
  int d_i = s_i - p_i;       // sorted index = v + d_row
  if (gl >= nrow) p_i = 0x7fffffff;

  int slot = gl & (SL - 1);
  u64 val = ~0ull, tau = ~0ull;

  for (int v0 = 0; v0 < T; v0 += 16) {  // T group-uniform
    int v = v0 + gl;
    // binary search: last r with p_r <= v (p_0 = 0 <= v)
    int r = 0;
#pragma unroll
    for (int st = 8; st >= 1; st >>= 1) {
      int pc = __shfl(p_i, r + st, 16);
      if (v >= pc) r += st;
    }
    int addr = v + __shfl(d_i, r, 16);
    u64 ck = ~0ull;
    if (v < T) {
      float4 P = sb[addr];
      float rr = P.x * P.x + P.y * P.y + P.z * P.z;
      float d2 = qq + rr - 2.0f * (qx * P.x + qy * P.y + qz * P.z);
      ck = ((u64)fbias(d2) << 32) | (u32)__float_as_uint(P.w);
    }
    u64 full = __ballot(ck < tau);
    u32 m16 = (u32)((full >> (g * 16)) & 0xFFFFull);
    group_insert<SL>(m16, ck, slot, val, tau);
  }

  const float h = 1.0f / GR;
  float m = 1e30f;
  if (x0 > 0)      m = fminf(m, qx - x0 * h);
  if (x1 < GR - 1) m = fminf(m, (x1 + 1) * h - qx);
  if (y0 > 0)      m = fminf(m, qy - y0 * h);
  if (y1 < GR - 1) m = fminf(m, (y1 + 1) * h - qy);
  if (z0 > 0)      m = fminf(m, qz - z0 * h);
  if (z1 < GR - 1) m = fminf(m, (z1 + 1) * h - qz);
  float bound = m * m;
  float tau_d2 = funbias((u32)(tau >> 32));
  if (!(tau_d2 < bound)) {  // group-uniform; rare
    for (int t0 = 0; t0 < NREF; t0 += 16) {
      int j = t0 + gl;
      u64 ck = ~0ull;
      if (j < NREF) {
        float4 P = sb[j];
        int cx = min(max((int)(P.x * GR), 0), GR - 1);
        int cy = min(max((int)(P.y * GR), 0), GR - 1);
        int cz = min(max((int)(P.z * GR), 0), GR - 1);
        bool inbox = (cx >= x0 && cx <= x1 && cy >= y0 && cy <= y1 &&
                      cz >= z0 && cz <= z1);
        if (!inbox) {
          float rr = P.x * P.x + P.y * P.y + P.z * P.z;
          float d2 = qq + rr - 2.0f * (qx * P.x + qy * P.y + qz * P.z);
          ck = ((u64)fbias(d2) << 32) | (u32)__float_as_uint(P.w);
        }
      }
      u64 full = __ballot(ck < tau);
      u32 m16 = (u32)((full >> (g * 16)) & 0xFFFFull);
      group_insert<SL>(m16, ck, slot, val, tau);
    }
  }

  if (gl < KOUT) {
    size_t base = ((size_t)b * Mq + q) * KOUT;
    oidx[base + gl] = (int)(u32)val;
    od2[base + gl] = fmaxf(funbias((u32)(val >> 32)), 0.0f);
  }
}

// --------------------------------------- kNN grid, ROWS (NROW <= 32) -------
// R12: all row (s,e) pairs prefetched in parallel (2 regs/lane), row loop
// reads them via shfl — no dependent cs loads inside the loop.
template<int SL, int KOUT, int GR, int R, int NREF>
__global__ __launch_bounds__(256) void knn_grid_rows_kernel(
    const float* __restrict__ pos, const float4* __restrict__ sorted,
    const int* __restrict__ cellStart, int csStride, int Mq,
    int* __restrict__ oidx, float* __restrict__ od2) {
  int b = blockIdx.y;
  int wv = threadIdx.x >> 6, lane = threadIdx.x & 63;
  int g = lane >> 4, gl = lane & 15;
  int q = blockIdx.x * 16 + wv * 4 + g;
  const float* pb = pos + (size_t)b * NFULL * 3;
  const float4* sb = sorted + (size_t)b * NREF;
  const int* cs = cellStart + b * csStride;
  float qx = pb[q * 3 + 0], qy = pb[q * 3 + 1], qz = pb[q * 3 + 2];
  float qq = qx * qx + qy * qy + qz * qz;
  int ix = min(max((int)(qx * GR), 0), GR - 1);
  int iy = min(max((int)(qy * GR), 0), GR - 1);
  int iz = min(max((int)(qz * GR), 0), GR - 1);
  int x0 = max(ix - R, 0), x1 = min(ix + R, GR - 1);
  int y0 = max(iy - R, 0), y1 = min(iy + R, GR - 1);
  int z0 = max(iz - R, 0), z1 = min(iz + R, GR - 1);

  int ny = y1 - y0 + 1;
  int nrow = (z1 - z0 + 1) * ny;  // <= 25 for R=2
  int sLo = 0, eLo = 0, sHi = 0, eHi = 0;
  if (gl < nrow) {
    int zz = z0 + gl / ny, yy = y0 + gl % ny;
    int c0 = (zz * GR + yy) * GR + x0;
    sLo = cs[c0]; eLo = cs[c0 + (x1 - x0) + 1];
  }
  {
    int i2 = gl + 16;
    if (i2 < nrow) {
      int zz = z0 + i2 / ny, yy = y0 + i2 % ny;
      int c0 = (zz * GR + yy) * GR + x0;
      sHi = cs[c0]; eHi = cs[c0 + (x1 - x0) + 1];
    }
  }

  int slot = gl & (SL - 1);
  u64 val = ~0ull, tau = ~0ull;

  for (int r = 0; r < nrow; ++r) {  // r group-uniform
    int sa = __shfl(sLo, r & 15, 16);
    int sb2 = __shfl(sHi, r & 15, 16);
    int ea = __shfl(eLo, r & 15, 16);
    int eb = __shfl(eHi, r & 15, 16);
    int s = (r < 16) ? sa : sb2;
    int e = (r < 16) ? ea : eb;
    for (int t0 = s; t0 < e; t0 += 16) {
      int j = t0 + gl;
      u64 ck = ~0ull;
      if (j < e) {
        float4 P = sb[j];
        float rr = P.x * P.x + P.y * P.y + P.z * P.z;
        float d2 = qq + rr - 2.0f * (qx * P.x + qy * P.y + qz * P.z);
        ck = ((u64)fbias(d2) << 32) | (u32)__float_as_uint(P.w);
      }
      u64 full = __ballot(ck < tau);
      u32 m16 = (u32)((full >> (g * 16)) & 0xFFFFull);
      group_insert<SL>(m16, ck, slot, val, tau);
    }
  }

  const float h = 1.0f / GR;
  float m = 1e30f;
  if (x0 > 0)      m = fminf(m, qx - x0 * h);
  if (x1 < GR - 1) m = fminf(m, (x1 + 1) * h - qx);
  if (y0 > 0)      m = fminf(m, qy - y0 * h);
  if (y1 < GR - 1) m = fminf(m, (y1 + 1) * h - qy);
  if (z0 > 0)      m = fminf(m, qz - z0 * h);
  if (z1 < GR - 1) m = fminf(m, (z1 + 1) * h - qz);
  float bound = m * m;
  float tau_d2 = funbias((u32)(tau >> 32));
  if (!(tau_d2 < bound)) {
    for (int t0 = 0; t0 < NREF; t0 += 16) {
      int j = t0 + gl;
      u64 ck = ~0ull;
      if (j < NREF) {
        float4 P = sb[j];
        int cx = min(max((int)(P.x * GR), 0), GR - 1);
        int cy = min(max((int)(P.y * GR), 0), GR - 1);
        int cz = min(max((int)(P.z * GR), 0), GR - 1);
        bool inbox = (cx >= x0 && cx <= x1 && cy >= y0 && cy <= y1 &&
                      cz >= z0 && cz <= z1);
        if (!inbox) {
          float rr = P.x * P.x + P.y * P.y + P.z * P.z;
          float d2 = qq + rr - 2.0f * (qx * P.x + qy * P.y + qz * P.z);
          ck = ((u64)fbias(d2) << 32) | (u32)__float_as_uint(P.w);
        }
      }
      u64 full = __ballot(ck < tau);
      u32 m16 = (u32)((full >> (g * 16)) & 0xFFFFull);
      group_insert<SL>(m16, ck, slot, val, tau);
    }
  }

  if (gl < KOUT) {
    size_t base = ((size_t)b * Mq + q) * KOUT;
    oidx[base + gl] = (int)(u32)val;
    od2[base + gl] = fmaxf(funbias((u32)(val >> 32)), 0.0f);
  }
}

// -------------------------------------------------------- kNN (brute) ------
template<int SL, int KOUT>
__global__ __launch_bounds__(256) void knn_kernel(
    const float* __restrict__ pos, int Nref, int Mq,
    int* __restrict__ oidx, float* __restrict__ od2) {
  int b = blockIdx.y;
  int wv = threadIdx.x >> 6, lane = threadIdx.x & 63;
  int g = lane >> 4, gl = lane & 15;
  int q = blockIdx.x * 16 + wv * 4 + g;
  const float* pb = pos + (size_t)b * NFULL * 3;
  float qx = pb[q * 3 + 0], qy = pb[q * 3 + 1], qz = pb[q * 3 + 2];
  float qq = qx * qx + qy * qy + qz * qz;

  int slot = gl & (SL - 1);
  u64 val = ~0ull, tau = ~0ull;

  for (int t0 = 0; t0 < Nref; t0 += 16) {
    int j = t0 + gl;
    float rx = pb[j * 3 + 0];
    float ry = pb[j * 3 + 1];
    float rz = pb[j * 3 + 2];
    float rr = rx * rx + ry * ry + rz * rz;
    float d2 = qq + rr - 2.0f * (qx * rx + qy * ry + qz * rz);
    u64 ck = ((u64)fbias(d2) << 32) | (u32)j;
    u64 full = __ballot(ck < tau);
    u32 m16 = (u32)((full >> (g * 16)) & 0xFFFFull);
    group_insert<SL>(m16, ck, slot, val, tau);
  }

  if (gl < KOUT) {
    size_t base = ((size_t)b * Mq + q) * KOUT;
    oidx[base + gl] = (int)(u32)val;
    od2[base + gl] = fmaxf(funbias((u32)(val >> 32)), 0.0f);
  }
}

// ----------------------------------- fused weight packing + pos copy -------
__device__ __forceinline__ void pack_tile_rt(const float* __restrict__ W,
                                             short* __restrict__ outp,
                                             int KDIM, int N, int tile, int lane) {
  int NT = N >> 4;
  int kt = tile / NT, nt = tile - kt * NT;
  int n = nt * 16 + (lane & 15);
  int k0 = kt * 32 + (lane >> 4) * 8;
  bf8_t v;
#pragma unroll
  for (int j = 0; j < 8; ++j) {
    int k = k0 + j;
    v[j] = (k < KDIM) ? f2bf(W[(size_t)k * N + n]) : (short)0;
  }
  *(bf8_t*)(outp + ((size_t)tile * 64 + lane) * 8) = v;
}

__global__ __launch_bounds__(64) void pack_copy_all_kernel(
    const float* d0W1, short* d0W1p, const float* d0W2, short* d0W2p,
    const float* d1W1, short* d1W1p, const float* d1W2, short* d1W2p,
    const float* d2W1, short* d2W1p, const float* d2W2, short* d2W2p,
    const float* u2W, short* u2Wp, const float* fW1, short* fW1p,
    const float* fW2, short* fW2p,
    const float* pos, float* posOut) {
  int blk = blockIdx.x, lane = threadIdx.x;
  if      (blk < 8)    pack_tile_rt(d0W1, d0W1p, 6, 128, blk, lane);
  else if (blk < 40)   pack_tile_rt(d0W2, d0W2p, 128, 128, blk - 8, lane);
  else if (blk < 120)  pack_tile_rt(d1W1, d1W1p, 131, 256, blk - 40, lane);
  else if (blk < 248)  pack_tile_rt(d1W2, d1W2p, 256, 256, blk - 120, lane);
  else if (blk < 536)  pack_tile_rt(d2W1, d2W1p, 259, 512, blk - 248, lane);
  else if (blk < 1048) pack_tile_rt(d2W2, d2W2p, 512, 512, blk - 536, lane);
  else if (blk < 1088) pack_tile_rt(u2W, u2Wp, 134, 128, blk - 1048, lane);
  else if (blk < 1120) pack_tile_rt(fW1, fW1p, 128, 128, blk - 1088, lane);
  else if (blk < 1152) pack_tile_rt(fW2, fW2p, 128, 128, blk - 1120, lane);
  else {
    int base = (blk - 1152) * 256;  // 384 blocks x 256 = 98304 = BATCH*NFULL*3
#pragma unroll
    for (int j = 0; j < 4; ++j) {
      int i = base + lane + j * 64;
      posOut[i] = pos[i];
    }
  }
}

// ----------------------------------------------------- down MLP (MFMA) -----
template<int FEAT, int CIN, int CHID, int FPAD, int WPB>
__global__ __launch_bounds__(64 * WPB) void down_mfma_kernel(
    const float* __restrict__ pos, const float* __restrict__ xin,
    const int* __restrict__ idx,
    const short* __restrict__ W1p, const float* __restrict__ b1,
    const short* __restrict__ W2p, const float* __restrict__ b2,
    float* __restrict__ out, int n, int nprev) {
  const int KT1 = FPAD / 32, NT1 = CHID / 16;
  const int KT2 = CHID / 32, NT2 = CHID / 16;
  __shared__ short sFeat[16][FPAD];
  __shared__ short sH1[16][CHID];
  __shared__ int sIdx[16];
  __shared__ float sCtr[3];
  int b = blockIdx.y, q = blockIdx.x;
  int lane = threadIdx.x & 63, wv = threadIdx.x >> 6;
  const float* pb = pos + (size_t)b * NFULL * 3;
  const float* xb = xin + (size_t)b * nprev * CIN;
  if (threadIdx.x < 16) sIdx[threadIdx.x] = idx[((size_t)b * n + q) * 16 + threadIdx.x];
  if (threadIdx.x < 3) sCtr[threadIdx.x] = pb[q * 3 + threadIdx.x];
  __syncthreads();
  for (int e = threadIdx.x; e < 16 * FPAD; e += 64 * WPB) {
    int k = e / FPAD, c = e % FPAD;
    float v = 0.f;
    if (c < 3) v = pb[sIdx[k] * 3 + c] - sCtr[c];
    else if (c < FEAT) v = xb[(size_t)sIdx[k] * CIN + (c - 3)];
    sFeat[k][c] = f2bf(v);
  }
  __syncthreads();

  int col = lane & 15, quad = lane >> 4;
  bf8_t afr[KT1];
#pragma unroll
  for (int kt = 0; kt < KT1; ++kt)
    afr[kt] = *(const bf8_t*)&sFeat[col][kt * 32 + quad * 8];
  const bf8_t* W1t = (const bf8_t*)W1p;
  for (int nt = 2 * wv; nt < NT1; nt += 2 * WPB) {
    float bb0 = b1[nt * 16 + col], bb1 = b1[nt * 16 + 16 + col];
    f4_t acc0 = {bb0, bb0, bb0, bb0}, acc1 = {bb1, bb1, bb1, bb1};
#pragma unroll
    for (int kt = 0; kt < KT1; ++kt) {
      bf8_t bf0 = W1t[(kt * NT1 + nt) * 64 + lane];
      bf8_t bf1 = W1t[(kt * NT1 + nt + 1) * 64 + lane];
      acc0 = __builtin_amdgcn_mfma_f32_16x16x32_bf16(afr[kt], bf0, acc0, 0, 0, 0);
      acc1 = __builtin_amdgcn_mfma_f32_16x16x32_bf16(afr[kt], bf1, acc1, 0, 0, 0);
    }
#pragma unroll
    for (int r = 0; r < 4; ++r) {
      sH1[quad * 4 + r][nt * 16 + col] = f2bf(fmaxf(acc0[r], 0.f));
      sH1[quad * 4 + r][nt * 16 + 16 + col] = f2bf(fmaxf(acc1[r], 0.f));
    }
  }
  __syncthreads();

  bf8_t afr2[KT2];
#pragma unroll
  for (int kt = 0; kt < KT2; ++kt)
    afr2[kt] = *(const bf8_t*)&sH1[col][kt * 32 + quad * 8];
  const bf8_t* W2t = (const bf8_t*)W2p;
  float* ob = out + ((size_t)b * n + q) * CHID;
  for (int nt = 2 * wv; nt < NT2; nt += 2 * WPB) {
    float bb0 = b2[nt * 16 + col], bb1 = b2[nt * 16 + 16 + col];
    f4_t acc0 = {bb0, bb0, bb0, bb0}, acc1 = {bb1, bb1, bb1, bb1};
#pragma unroll
    for (int kt = 0; kt < KT2; ++kt) {
      bf8_t bf0 = W2t[(kt * NT2 + nt) * 64 + lane];
      bf8_t bf1 = W2t[(kt * NT2 + nt + 1) * 64 + lane];
      acc0 = __builtin_amdgcn_mfma_f32_16x16x32_bf16(afr2[kt], bf0, acc0, 0, 0, 0);
      acc1 = __builtin_amdgcn_mfma_f32_16x16x32_bf16(afr2[kt], bf1, acc1, 0, 0, 0);
    }
    float m0 = fmaxf(fmaxf(acc0[0], acc0[1]), fmaxf(acc0[2], acc0[3]));
    float m1 = fmaxf(fmaxf(acc1[0], acc1[1]), fmaxf(acc1[2], acc1[3]));
    m0 = fmaxf(m0, __shfl_xor(m0, 16, 64));
    m0 = fmaxf(m0, __shfl_xor(m0, 32, 64));
    m1 = fmaxf(m1, __shfl_xor(m1, 16, 64));
    m1 = fmaxf(m1, __shfl_xor(m1, 32, 64));
    if (lane < 16) {
      ob[nt * 16 + lane] = m0;
      ob[nt * 16 + 16 + lane] = m1;
    }
  }
}

// --------------------------------------------------------------- up MLP ----
template<int CIN, int CPRV, int COUT, int TP>
__global__ __launch_bounds__(COUT) void up_kernel(
    const float* __restrict__ xc, int ncoarse,
    const int* __restrict__ idx3, const float* __restrict__ d23,
    const float* __restrict__ prv, const float* __restrict__ W,
    const float* __restrict__ bvec, float* __restrict__ out, int m) {
  const int CTOT = CIN + CPRV;
  __shared__ float sCat[TP][CTOT];
  __shared__ float sWt[TP][3];
  __shared__ int   sIt[TP][3];
  int b = blockIdx.y, q0 = blockIdx.x * TP, t = threadIdx.x;
  if (t < TP) {
    size_t base = ((size_t)b * m + q0 + t) * 3;
    float d0 = d23[base + 0], d1 = d23[base + 1], d2v = d23[base + 2];
    float w0 = 1.f / (d0 + 1e-8f), w1 = 1.f / (d1 + 1e-8f), w2 = 1.f / (d2v + 1e-8f);
    float s = w0 + w1 + w2;
    sWt[t][0] = w0 / s; sWt[t][1] = w1 / s; sWt[t][2] = w2 / s;
    sIt[t][0] = idx3[base + 0]; sIt[t][1] = idx3[base + 1]; sIt[t][2] = idx3[base + 2];
  }
  __syncthreads();
  const float* xb = xc + (size_t)b * ncoarse * CIN;
  const float* pvb = prv + ((size_t)b * m + q0) * CPRV;
  for (int e = t; e < TP * CIN; e += COUT) {
    int p = e / CIN, c = e % CIN;
    sCat[p][c] = sWt[p][0] * xb[(size_t)sIt[p][0] * CIN + c]
               + sWt[p][1] * xb[(size_t)sIt[p][1] * CIN + c]
               + sWt[p][2] * xb[(size_t)sIt[p][2] * CIN + c];
  }
  for (int e = t; e < TP * CPRV; e += COUT) {
    int p = e / CPRV, c = e % CPRV;
    sCat[p][CIN + c] = pvb[(size_t)p * CPRV + c];
  }
  __syncthreads();
  float acc[TP];
  float bb = bvec[t];
#pragma unroll
  for (int p = 0; p < TP; ++p) acc[p] = bb;
  for (int c4 = 0; c4 < CTOT / 4; ++c4) {
    int c = 4 * c4;
    float w0 = W[(c + 0) * COUT + t];
    float w1 = W[(c + 1) * COUT + t];
    float w2 = W[(c + 2) * COUT + t];
    float w3 = W[(c + 3) * COUT + t];
#pragma unroll
    for (int p = 0; p < TP; ++p) {
      float4 v = *(const float4*)&sCat[p][c];
      acc[p] = fmaf(v.x, w0, acc[p]);
      acc[p] = fmaf(v.y, w1, acc[p]);
      acc[p] = fmaf(v.z, w2, acc[p]);
      acc[p] = fmaf(v.w, w3, acc[p]);
    }
  }
#pragma unroll
  for (int p = 0; p < TP; ++p)
    out[((size_t)b * m + q0 + p) * COUT + t] = fmaxf(acc[p], 0.f);
}

// ------------------------------------- fused up2 + final MLP (bf16 MFMA) ---
__global__ __launch_bounds__(128) void up2f_mfma_kernel(
    const float* __restrict__ xc,
    const int* __restrict__ idx3, const float* __restrict__ d23,
    const float* __restrict__ x0, const float* __restrict__ pos0,
    const short* __restrict__ u2Wp, const float* __restrict__ u2b,
    const short* __restrict__ fW1p, const float* __restrict__ fb1,
    const short* __restrict__ fW2p, const float* __restrict__ fb2,
    float* __restrict__ out) {
  __shared__ short sA[16][160];
  __shared__ short sB[16][128];
  __shared__ float sWt[16][3];
  __shared__ int   sIt[16][3];
  int b = blockIdx.y, q0 = blockIdx.x * 16, t = threadIdx.x;
  int lane = t & 63, wv = t >> 6;
  if (t < 16) {
    size_t base = ((size_t)b * NFULL + q0 + t) * 3;
    float d0 = d23[base + 0], d1 = d23[base + 1], d2v = d23[base + 2];
    float w0 = 1.f / (d0 + 1e-8f), w1 = 1.f / (d1 + 1e-8f), w2 = 1.f / (d2v + 1e-8f);
    float s = w0 + w1 + w2;
    sWt[t][0] = w0 / s; sWt[t][1] = w1 / s; sWt[t][2] = w2 / s;
    sIt[t][0] = idx3[base + 0]; sIt[t][1] = idx3[base + 1]; sIt[t][2] = idx3[base + 2];
  }
  __syncthreads();
  const float* xb = xc + (size_t)b * 2048 * 128;
#pragma unroll
  for (int p = 0; p < 16; ++p) {
    float v = sWt[p][0] * xb[(size_t)sIt[p][0] * 128 + t]
            + sWt[p][1] * xb[(size_t)sIt[p][1] * 128 + t]
            + sWt[p][2] * xb[(size_t)sIt[p][2] * 128 + t];
    sA[p][t] = f2bf(v);
  }
  for (int e = t; e < 16 * 32; e += 128) {
    int p = e / 32, c = 128 + (e % 32);
    float v = 0.f;
    if (c < 131) v = x0[((size_t)b * NFULL + q0 + p) * 3 + (c - 128)];
    else if (c < 134) v = pos0[((size_t)b * NFULL + q0 + p) * 3 + (c - 131)];
    sA[p][c] = f2bf(v);
  }
  __syncthreads();
  int col = lane & 15, quad = lane >> 4;

  bf8_t a1[5];
#pragma unroll
  for (int kt = 0; kt < 5; ++kt)
    a1[kt] = *(const bf8_t*)&sA[col][kt * 32 + quad * 8];
  const bf8_t* W1t = (const bf8_t*)u2Wp;
  for (int nt = 2 * wv; nt < 8; nt += 4) {
    float bb0 = u2b[nt * 16 + col], bb1 = u2b[nt * 16 + 16 + col];
    f4_t acc0 = {bb0, bb0, bb0, bb0}, acc1 = {bb1, bb1, bb1, bb1};
#pragma unroll
    for (int kt = 0; kt < 5; ++kt) {
      bf8_t bf0 = W1t[(kt * 8 + nt) * 64 + lane];
      bf8_t bf1 = W1t[(kt * 8 + nt + 1) * 64 + lane];
      acc0 = __builtin_amdgcn_mfma_f32_16x16x32_bf16(a1[kt], bf0, acc0, 0, 0, 0);
      acc1 = __builtin_amdgcn_mfma_f32_16x16x32_bf16(a1[kt], bf1, acc1, 0, 0, 0);
    }
#pragma unroll
    for (int r = 0; r < 4; ++r) {
      sB[quad * 4 + r][nt * 16 + col] = f2bf(fmaxf(acc0[r], 0.f));
      sB[quad * 4 + r][nt * 16 + 16 + col] = f2bf(fmaxf(acc1[r], 0.f));
    }
  }
  __syncthreads();

  bf8_t a2[4];
#pragma unroll
  for (int kt = 0; kt < 4; ++kt)
    a2[kt] = *(const bf8_t*)&sB[col][kt * 32 + quad * 8];
  const bf8_t* W2t = (const bf8_t*)fW1p;
  for (int nt = 2 * wv; nt < 8; nt += 4) {
    float bb0 = fb1[nt * 16 + col], bb1 = fb1[nt * 16 + 16 + col];
    f4_t acc0 = {bb0, bb0, bb0, bb0}, acc1 = {bb1, bb1, bb1, bb1};
#pragma unroll
    for (int kt = 0; kt < 4; ++kt) {
      bf8_t bf0 = W2t[(kt * 8 + nt) * 64 + lane];
      bf8_t bf1 = W2t[(kt * 8 + nt + 1) * 64 + lane];
      acc0 = __builtin_amdgcn_mfma_f32_16x16x32_bf16(a2[kt], bf0, acc0, 0, 0, 0);
      acc1 = __builtin_amdgcn_mfma_f32_16x16x32_bf16(a2[kt], bf1, acc1, 0, 0, 0);
    }
#pragma unroll
    for (int r = 0; r < 4; ++r) {
      sA[quad * 4 + r][nt * 16 + col] = f2bf(fmaxf(acc0[r], 0.f));
      sA[quad * 4 + r][nt * 16 + 16 + col] = f2bf(fmaxf(acc1[r], 0.f));
    }
  }
  __syncthreads();

  bf8_t a3[4];
#pragma unroll
  for (int kt = 0; kt < 4; ++kt)
    a3[kt] = *(const bf8_t*)&sA[col][kt * 32 + quad * 8];
  const bf8_t* W3t = (const bf8_t*)fW2p;
  float* ob = out + ((size_t)b * NFULL + q0) * 128;
  for (int nt = 2 * wv; nt < 8; nt += 4) {
    float bb0 = fb2[nt * 16 + col], bb1 = fb2[nt * 16 + 16 + col];
    f4_t acc0 = {bb0, bb0, bb0, bb0}, acc1 = {bb1, bb1, bb1, bb1};
#pragma unroll
    for (int kt = 0; kt < 4; ++kt) {
      bf8_t bf0 = W3t[(kt * 8 + nt) * 64 + lane];
      bf8_t bf1 = W3t[(kt * 8 + nt + 1) * 64 + lane];
      acc0 = __builtin_amdgcn_mfma_f32_16x16x32_bf16(a3[kt], bf0, acc0, 0, 0, 0);
      acc1 = __builtin_amdgcn_mfma_f32_16x16x32_bf16(a3[kt], bf1, acc1, 0, 0, 0);
    }
#pragma unroll
    for (int r = 0; r < 4; ++r) {
      ob[(size_t)(quad * 4 + r) * 128 + nt * 16 + col] = acc0[r];
      ob[(size_t)(quad * 4 + r) * 128 + nt * 16 + 16 + col] = acc1[r];
    }
  }
}

// ------------------------------------------------------------------ launch -
extern "C" void kernel_launch(void* const* d_in, const int* in_sizes, int n_in,
                              void* d_out, int out_size, void* d_ws, size_t ws_size,
                              hipStream_t stream) {
  const float* x    = (const float*)d_in[0];
  const float* pos  = (const float*)d_in[1];
  const float* d0W1 = (const float*)d_in[2];
  const float* d0b1 = (const float*)d_in[3];
  const float* d0W2 = (const float*)d_in[4];
  const float* d0b2 = (const float*)d_in[5];
  const float* d1W1 = (const float*)d_in[6];
  const float* d1b1 = (const float*)d_in[7];
  const float* d1W2 = (const float*)d_in[8];
  const float* d1b2 = (const float*)d_in[9];
  const float* d2W1 = (const float*)d_in[10];
  const float* d2b1 = (const float*)d_in[11];
  const float* d2W2 = (const float*)d_in[12];
  const float* d2b2 = (const float*)d_in[13];
  const float* u0W  = (const float*)d_in[14];
  const float* u0b  = (const float*)d_in[15];
  const float* u1W  = (const float*)d_in[16];
  const float* u1b  = (const float*)d_in[17];
  const float* u2W  = (const float*)d_in[18];
  const float* u2b  = (const float*)d_in[19];
  const float* fW1  = (const float*)d_in[20];
  const float* fb1  = (const float*)d_in[21];
  const float* fW2  = (const float*)d_in[22];
  const float* fb2  = (const float*)d_in[23];

  char* ws = (char*)d_ws;
  float* x1    = (float*)(ws + 0);
  float* x2    = (float*)(ws + 4194304);
  float* x3    = (float*)(ws + 6291456);
  float* up0o  = (float*)(ws + 7340032);
  float* up1o  = (float*)(ws + 9437184);
  int*   idx0  = (int*)  (ws + 13631488);
  int*   idx1  = (int*)  (ws + 14155776);
  int*   idx2  = (int*)  (ws + 14286848);
  float* d2s   = (float*)(ws + 14319616);
  int*   idxu0 = (int*)  (ws + 14843904);
  float* d2u0  = (float*)(ws + 14868480);
  int*   idxu1 = (int*)  (ws + 14893056);
  float* d2u1  = (float*)(ws + 14991360);
  int*   idxu2 = (int*)  (ws + 15089664);
  float* d2u2  = (float*)(ws + 15482880);
  short* d1W1p = (short*)(ws + 15876096);
  short* d1W2p = (short*)(ws + 15958016);
  short* d2W1p = (short*)(ws + 16089088);
  short* d2W2p = (short*)(ws + 16384000);
  short* d0W1p = (short*)(ws + 16908288);
  short* d0W2p = (short*)(ws + 16916480);
  float4* sortedA = (float4*)(ws + 16949248);  // 4*8192*16 = 524288
  int*    csA     = (int*)   (ws + 17473536);  // 4*4097*4  = 65552
  float4* sortedB = (float4*)(ws + 17539136);  // 4*2048*16 = 131072
  int*    csB     = (int*)   (ws + 17670208);  // 4*513*4   = 8208
  short* u2Wp  = (short*)(ws + 17697920);
  short* fW1p  = (short*)(ws + 17738880);
  short* fW2p  = (short*)(ws + 17771648);

  float* out = (float*)d_out;

  // ---- fused packing + pos passthrough; fused grid builds ----
  pack_copy_all_kernel<<<dim3(1536), 64, 0, stream>>>(
      d0W1, d0W1p, d0W2, d0W2p, d1W1, d1W1p, d1W2, d1W2p,
      d2W1, d2W1p, d2W2, d2W2p, u2W, u2Wp, fW1, fW1p, fW2, fW2p,
      pos, out + (size_t)BATCH * NFULL * 128);
  build_grids_kernel<<<dim3(BATCH, 2), 256, 0, stream>>>(pos, sortedA, csA, sortedB, csB);

  // ---- down path ----
  knn_grid_rows_kernel<16, 16, 16, 2, 8192><<<dim3(128, BATCH), 256, 0, stream>>>(
      pos, sortedA, csA, 4097, 2048, idx0, d2s);
  down_mfma_kernel<6, 3, 128, 32, 1><<<dim3(2048, BATCH), 64, 0, stream>>>(
      pos, x, idx0, d0W1p, d0b1, d0W2p, d0b2, x1, 2048, 8192);
  knn_grid_rows_kernel<16, 16, 8, 2, 2048><<<dim3(32, BATCH), 256, 0, stream>>>(
      pos, sortedB, csB, 513, 512, idx1, d2s);
  down_mfma_kernel<131, 128, 256, 160, 1><<<dim3(512, BATCH), 64, 0, stream>>>(
      pos, x1, idx1, d1W1p, d1b1, d1W2p, d1b2, x2, 512, 2048);
  knn_kernel<16, 16><<<dim3(8, BATCH), 256, 0, stream>>>(pos, 512, 128, idx2, d2s);
  down_mfma_kernel<259, 256, 512, 288, 2><<<dim3(128, BATCH), 128, 0, stream>>>(
      pos, x2, idx2, d2W1p, d2b1, d2W2p, d2b2, x3, 128, 512);

  // ---- up path ----
  knn_kernel<4, 3><<<dim3(32, BATCH), 256, 0, stream>>>(pos, 128, 512, idxu0, d2u0);
  up_kernel<512, 256, 256, 8><<<dim3(64, BATCH), 256, 0, stream>>>(
      x3, 128, idxu0, d2u0, x2, u0W, u0b, up0o, 512);
  knn_kernel<4, 3><<<dim3(128, BATCH), 256, 0, stream>>>(pos, 512, 2048, idxu1, d2u1);
  up_kernel<256, 128, 128, 16><<<dim3(128, BATCH), 128, 0, stream>>>(
      up0o, 512, idxu1, d2u1, x1, u1W, u1b, up1o, 2048);
  knn_grid_flat_kernel<4, 3, 8, 1, 2048><<<dim3(512, BATCH), 256, 0, stream>>>(
      pos, sortedB, csB, 513, 8192, idxu2, d2u2);
  up2f_mfma_kernel<<<dim3(512, BATCH), 128, 0, stream>>>(
      up1o, idxu2, d2u2, x, pos, u2Wp, u2b, fW1p, fb1, fW2p, fb2, out);
}